// Round 1
// 462.345 us; speedup vs baseline: 1.0533x; 1.0533x over previous
//
#include <hip/hip_runtime.h>
#include <cstdint>
#include <cstddef>

#define NN 50000
#define NE 800000
#define GB 196        // coarse buckets = ceil(NN/256)
#define TILE1 4096    // edges per part1 block
#define CAP 8192      // max edges per bucket in part2 LDS (mean 4082)

typedef __attribute__((ext_vector_type(8))) short short8;
typedef __attribute__((ext_vector_type(4))) float floatx4;
typedef __attribute__((ext_vector_type(2))) float floatx2;

__device__ __forceinline__ float lrelu_f(float x){ return x >= 0.f ? x : 0.2f*x; }
__device__ __forceinline__ float elu_f(float x){ return x > 0.f ? x : __expf(x) - 1.f; }

__device__ __forceinline__ unsigned short f2bf(float f){
  unsigned int u = __float_as_uint(f);
  u += 0x7FFFu + ((u >> 16) & 1u);
  return (unsigned short)(u >> 16);
}
__device__ __forceinline__ float bf2f(unsigned int us){
  return __uint_as_float(us << 16);
}
__device__ __forceinline__ float4 bf4_load(const unsigned short* p){
  uint2 q = *(const uint2*)p;
  return make_float4(bf2f(q.x & 0xffffu), bf2f(q.x >> 16),
                     bf2f(q.y & 0xffffu), bf2f(q.y >> 16));
}
__device__ __forceinline__ uint2 bf4_pack(float4 o){
  uint2 p;
  p.x = (unsigned)f2bf(o.x) | ((unsigned)f2bf(o.y) << 16);
  p.y = (unsigned)f2bf(o.z) | ((unsigned)f2bf(o.w) << 16);
  return p;
}
__device__ __forceinline__ void split_bf(float a, unsigned short& h, unsigned short& l){
  h = f2bf(a);
  l = f2bf(a - bf2f(h));
}

// packed-FP32 helpers (CDNA VOP3P: 2 f32 FMAs / instr)
__device__ __forceinline__ void pk_fma(floatx2& acc, floatx2 a, floatx2 b){
  asm("v_pk_fma_f32 %0, %1, %2, %0" : "+v"(acc) : "v"(a), "v"(b));
}
__device__ __forceinline__ void pk_add(floatx2& acc, floatx2 a){
  asm("v_pk_add_f32 %0, %0, %1" : "+v"(acc) : "v"(a));
}
// build f32 pair from the LOW bf16 of two dwords (1 shift each)
__device__ __forceinline__ floatx2 pair_lo(unsigned a, unsigned b){
  floatx2 r;
  r.x = __uint_as_float(a << 16);
  r.y = __uint_as_float(b << 16);
  return r;
}
// build f32 pair from the HIGH bf16 of two dwords (1 and each)
__device__ __forceinline__ floatx2 pair_hi(unsigned a, unsigned b){
  floatx2 r;
  r.x = __uint_as_float(a & 0xffff0000u);
  r.y = __uint_as_float(b & 0xffff0000u);
  return r;
}

// ---------------- two-level bucket sort of edges by dst ----------------
__global__ __launch_bounds__(256) void ghist_kernel(const int* __restrict__ e0,
                                                    const int* __restrict__ e1,
                                                    int* __restrict__ ghist){
  const int ty = blockIdx.y;
  const int* e = ty ? e1 : e0;
  __shared__ int h[GB];
  for (int j=threadIdx.x; j<GB; j+=256) h[j]=0;
  __syncthreads();
  for (int i = blockIdx.x*256 + threadIdx.x; i < NE; i += 256*256)
    atomicAdd(&h[e[NE+i]>>8], 1);
  __syncthreads();
  for (int j=threadIdx.x; j<GB; j+=256) if (h[j]) atomicAdd(&ghist[ty*200+j], h[j]);
}

__global__ __launch_bounds__(256) void gscan_kernel(const int* __restrict__ ghist,
                                                    int* __restrict__ gbase,
                                                    int* __restrict__ gcur){
  __shared__ int wb[4];
  const int t = threadIdx.x, wv = t>>6, l = t&63;
  for (int ty=0; ty<2; ++ty){
    int v = (t < GB) ? ghist[ty*200+t] : 0;
    int sum = v;
    #pragma unroll
    for (int off=1; off<64; off<<=1){
      int x = __shfl_up(sum, off, 64);
      if (l >= off) sum += x;
    }
    if (l == 63) wb[wv] = sum;
    __syncthreads();
    int wbase = 0;
    #pragma unroll
    for (int w=0; w<4; ++w) if (w < wv) wbase += wb[w];
    int excl = wbase + sum - v;
    if (t <= GB) gbase[ty*200+t] = excl;
    if (t <  GB) gcur [ty*200+t] = excl;
    __syncthreads();
  }
}

// partition with LDS staging: global writes are contiguous per-bucket runs
__global__ __launch_bounds__(256) void part1_kernel(const int* __restrict__ e0,
                                                    const int* __restrict__ e1,
                                                    int* __restrict__ gcur,
                                                    int2* __restrict__ p0,
                                                    int2* __restrict__ p1){
  const int ty = blockIdx.y;
  const int* e = ty ? e1 : e0;
  int2* pairs = ty ? p1 : p0;
  __shared__ int cnt[256];
  __shared__ int lstart[256];
  __shared__ int lcur[256];
  __shared__ int curg[GB];
  __shared__ int lsrc[TILE1];
  __shared__ int ldst[TILE1];
  __shared__ int wb[4];
  const int t = threadIdx.x;
  cnt[t] = 0;
  __syncthreads();
  int dreg[16], sreg[16];
  const int base = blockIdx.x*TILE1;
  const int ntile = min(TILE1, NE - base);
  #pragma unroll
  for (int it=0; it<16; ++it){
    int i = base + it*256 + t;
    int d = -1, s = 0;
    if (i < NE){ d = e[NE+i]; s = e[i]; atomicAdd(&cnt[d>>8], 1); }
    dreg[it] = d; sreg[it] = s;
  }
  __syncthreads();
  int c = cnt[t], sum = c;
  #pragma unroll
  for (int off=1; off<64; off<<=1){
    int x = __shfl_up(sum, off, 64);
    if ((t&63) >= off) sum += x;
  }
  if ((t&63) == 63) wb[t>>6] = sum;
  __syncthreads();
  int wbase = 0;
  #pragma unroll
  for (int w=0; w<4; ++w) if (w < (t>>6)) wbase += wb[w];
  int excl = wbase + sum - c;
  lstart[t] = excl;
  lcur[t] = excl;
  if (t < GB && c > 0) curg[t] = atomicAdd(&gcur[ty*200+t], c);
  __syncthreads();
  #pragma unroll
  for (int it=0; it<16; ++it){
    int d = dreg[it];
    if (d >= 0){
      int pos = atomicAdd(&lcur[d>>8], 1);
      lsrc[pos] = sreg[it];
      ldst[pos] = d;
    }
  }
  __syncthreads();
  for (int i=t; i<ntile; i+=256){
    int d = ldst[i];
    int j = d>>8;
    pairs[curg[j] + (i - lstart[j])] = make_int2(lsrc[i], d);
  }
}

// per-bucket LDS bin by dst + CSR offsets + fused layer-0 softmax weights (bf16).
struct Part2Job {
  const int2* pairs; const int* gbase;
  const float* als; const float* ald;   // [NN,4]
  int* ssrc; int* offs; unsigned short* coef;  // coef: [E,4] bf16
};
__global__ __launch_bounds__(256) void part2_kernel(Part2Job j0, Part2Job j1){
  const Part2Job jb = blockIdx.y ? j1 : j0;
  const int b = blockIdx.x;
  const int t = threadIdx.x;
  __shared__ int lcnt[256];
  __shared__ int lcur[256];
  __shared__ int wb[4];
  __shared__ int sorted_src[CAP];
  __shared__ unsigned char sorted_dl[CAP];
  const int gb0 = jb.gbase[b], gb1 = jb.gbase[b+1];
  const int n = gb1 - gb0;
  lcnt[t] = 0;
  __syncthreads();
  for (int i=t; i<n; i+=256)
    atomicAdd(&lcnt[jb.pairs[gb0+i].y - (b<<8)], 1);
  __syncthreads();
  int c = lcnt[t], sum = c;
  #pragma unroll
  for (int off=1; off<64; off<<=1){
    int x = __shfl_up(sum, off, 64);
    if ((t&63) >= off) sum += x;
  }
  if ((t&63) == 63) wb[t>>6] = sum;
  __syncthreads();
  int wbase = 0;
  #pragma unroll
  for (int w=0; w<4; ++w) if (w < (t>>6)) wbase += wb[w];
  int excl = wbase + sum - c;
  lcur[t] = excl;
  int g = (b<<8) + t;
  if (g <= NN) jb.offs[g] = gb0 + excl;
  __syncthreads();
  for (int i=t; i<n; i+=256){
    int2 pr = jb.pairs[gb0+i];
    int dl = pr.y - (b<<8);
    int pos = atomicAdd(&lcur[dl], 1);
    sorted_src[pos] = pr.x;
    sorted_dl[pos] = (unsigned char)dl;
  }
  __syncthreads();
  const float4* als4 = (const float4*)jb.als;
  const float4* ald4 = (const float4*)jb.ald;
  for (int i=t; i<n; i+=256){
    int s  = sorted_src[i];
    int dl = sorted_dl[i];
    float4 a  = als4[s];
    float4 ad = ald4[(b<<8)+dl];
    // no max-shift: |alpha| small at this model scale; softmax shift-invariant.
    float4 w;
    w.x = __expf(lrelu_f(a.x+ad.x));
    w.y = __expf(lrelu_f(a.y+ad.y));
    w.z = __expf(lrelu_f(a.z+ad.z));
    w.w = __expf(lrelu_f(a.w+ad.w));
    ((uint2*)jb.coef)[gb0+i] = bf4_pack(w);
    jb.ssrc[gb0+i] = s;
  }
}

// ---------------- MFMA GEMM: C = act(A[M,K] @ W[K,N] (+bias)) ----------------
// LG: logit-fused variant — GEMM N=48; cols 0..31 -> bf16 C (stride 32),
// col 32 -> fp32 outA[m], col 33 -> fp32 outB[m].
struct MgJob {
  const void* A; const float* W; const float* bias;
  void* C; float* outA; float* outB;
};
template<int NT, bool ELU, bool BF16OUT, bool BF16A, bool LG>
__global__ __launch_bounds__(256) void mgemm_kernel(MgJob j0, MgJob j1,
                                                    int M, int K, int N)
{
  const MgJob jb = blockIdx.z ? j1 : j0;
  constexpr int TN = NT*16;
  __shared__ __align__(16) unsigned short Ah[64*72];
  __shared__ __align__(16) unsigned short Al[BF16A ? 8 : 64*72];
  __shared__ __align__(16) unsigned short Bh[TN*72];
  __shared__ __align__(16) unsigned short Bl[TN*72];
  const int t = threadIdx.x;
  const int m0 = blockIdx.x*64;
  const int n0 = blockIdx.y*TN;
  const int wv = t>>6, l = t&63;
  const int lr = l&15, lq = l>>4;
  floatx4 acc[NT];
  #pragma unroll
  for (int i=0;i<NT;i++) acc[i] = (floatx4){0.f,0.f,0.f,0.f};

  for (int kt=0; kt<K; kt+=64){
    if constexpr (BF16A){
      const unsigned short* A = (const unsigned short*)jb.A;
      #pragma unroll
      for (int i=0;i<2;i++){
        int li = t + i*256;
        int r = li >> 3, c8 = (li & 7)*8;
        short8 v = {0,0,0,0,0,0,0,0};
        if (m0 + r < M) v = *(const short8*)(A + (size_t)(m0+r)*K + kt + c8);
        *(short8*)&Ah[r*72 + c8] = v;
      }
    } else {
      const float* A = (const float*)jb.A;
      #pragma unroll
      for (int i=0;i<4;i++){
        int li = t + i*256;
        int r = li >> 4, c4 = (li & 15)*4;
        float4 v = make_float4(0.f,0.f,0.f,0.f);
        if (m0 + r < M) v = *(const float4*)(A + (size_t)(m0+r)*K + kt + c4);
        unsigned short h0,h1,h2,h3,g0,g1,g2,g3;
        split_bf(v.x,h0,g0); split_bf(v.y,h1,g1);
        split_bf(v.z,h2,g2); split_bf(v.w,h3,g3);
        uint2 ph = { (unsigned)h0 | ((unsigned)h1<<16), (unsigned)h2 | ((unsigned)h3<<16) };
        uint2 pl = { (unsigned)g0 | ((unsigned)g1<<16), (unsigned)g2 | ((unsigned)g3<<16) };
        *(uint2*)&Ah[r*72 + c4] = ph;
        *(uint2*)&Al[r*72 + c4] = pl;
      }
    }
    #pragma unroll
    for (int i=0;i<NT;i++){
      int li = t + i*256;
      int k  = li / (TN/4);
      int n4 = (li % (TN/4))*4;
      float4 v = *(const float4*)(jb.W + (size_t)(kt+k)*N + n0 + n4);
      unsigned short h, g;
      split_bf(v.x,h,g); Bh[(n4+0)*72+k]=h; Bl[(n4+0)*72+k]=g;
      split_bf(v.y,h,g); Bh[(n4+1)*72+k]=h; Bl[(n4+1)*72+k]=g;
      split_bf(v.z,h,g); Bh[(n4+2)*72+k]=h; Bl[(n4+2)*72+k]=g;
      split_bf(v.w,h,g); Bh[(n4+3)*72+k]=h; Bl[(n4+3)*72+k]=g;
    }
    __syncthreads();
    #pragma unroll
    for (int ks=0; ks<2; ks++){
      const int koff = ks*32 + lq*8;
      short8 a_h = *(const short8*)&Ah[(wv*16+lr)*72 + koff];
      short8 a_l;
      if constexpr (!BF16A) a_l = *(const short8*)&Al[(wv*16+lr)*72 + koff];
      #pragma unroll
      for (int nt=0; nt<NT; nt++){
        short8 b_h = *(const short8*)&Bh[(nt*16+lr)*72 + koff];
        short8 b_l = *(const short8*)&Bl[(nt*16+lr)*72 + koff];
        acc[nt] = __builtin_amdgcn_mfma_f32_16x16x32_bf16(a_h, b_h, acc[nt], 0,0,0);
        acc[nt] = __builtin_amdgcn_mfma_f32_16x16x32_bf16(a_h, b_l, acc[nt], 0,0,0);
        if constexpr (!BF16A)
          acc[nt] = __builtin_amdgcn_mfma_f32_16x16x32_bf16(a_l, b_h, acc[nt], 0,0,0);
      }
    }
    __syncthreads();
  }
  #pragma unroll
  for (int nt=0; nt<NT; nt++){
    int n = n0 + nt*16 + lr;
    float bv = jb.bias ? jb.bias[n] : 0.f;
    #pragma unroll
    for (int r=0;r<4;r++){
      int m = m0 + wv*16 + lq*4 + r;
      if (m < M){
        float o = acc[nt][r] + bv;
        if (ELU) o = elu_f(o);
        if constexpr (LG){
          if (n < 32)       ((unsigned short*)jb.C)[(size_t)m*32 + n] = f2bf(o);
          else if (n == 32) jb.outA[m] = o;
          else if (n == 33) jb.outB[m] = o;
        } else {
          if (BF16OUT) ((unsigned short*)jb.C)[(size_t)m*N + n] = f2bf(o);
          else         ((float*)jb.C)[(size_t)m*N + n] = o;
        }
      }
    }
  }
}

// ---------------- per-head block GEMM: hi1[m, h*64+n] = elu((agg_h @ Ws_h)/den + b) ----
struct HgJob {
  const unsigned short* A; const float* W; const float* den;  // den [M,4]
  const float* bias; unsigned short* out;                      // out bf16 [M,256]
};
__global__ __launch_bounds__(256) void hgemm_kernel(HgJob j0, HgJob j1){
  const HgJob jb = blockIdx.z ? j1 : j0;
  const int head = blockIdx.y;
  const int m0 = blockIdx.x*64;
  __shared__ __align__(16) unsigned short Ah[64*72];
  __shared__ __align__(16) unsigned short Bh[64*72];
  __shared__ __align__(16) unsigned short Bl[64*72];
  const int t = threadIdx.x;
  const int wv = t>>6, l = t&63;
  const int lr = l&15, lq = l>>4;
  floatx4 acc[4];
  #pragma unroll
  for (int i=0;i<4;i++) acc[i] = (floatx4){0.f,0.f,0.f,0.f};
  #pragma unroll
  for (int i=0;i<2;i++){
    int li = t + i*256;
    int r = li >> 3, c8 = (li & 7)*8;
    short8 v = {0,0,0,0,0,0,0,0};
    if (m0 + r < NN) v = *(const short8*)(jb.A + (size_t)(m0+r)*256 + head*64 + c8);
    *(short8*)&Ah[r*72 + c8] = v;
  }
  #pragma unroll
  for (int i=0;i<4;i++){
    int li = t + i*256;
    int k  = li >> 4;
    int n4 = (li & 15)*4;
    float4 v = *(const float4*)(jb.W + (size_t)k*256 + head*64 + n4);
    unsigned short h, g;
    split_bf(v.x,h,g); Bh[(n4+0)*72+k]=h; Bl[(n4+0)*72+k]=g;
    split_bf(v.y,h,g); Bh[(n4+1)*72+k]=h; Bl[(n4+1)*72+k]=g;
    split_bf(v.z,h,g); Bh[(n4+2)*72+k]=h; Bl[(n4+2)*72+k]=g;
    split_bf(v.w,h,g); Bh[(n4+3)*72+k]=h; Bl[(n4+3)*72+k]=g;
  }
  __syncthreads();
  #pragma unroll
  for (int ks=0; ks<2; ks++){
    const int koff = ks*32 + lq*8;
    short8 a_h = *(const short8*)&Ah[(wv*16+lr)*72 + koff];
    #pragma unroll
    for (int nt=0; nt<4; nt++){
      short8 b_h = *(const short8*)&Bh[(nt*16+lr)*72 + koff];
      short8 b_l = *(const short8*)&Bl[(nt*16+lr)*72 + koff];
      acc[nt] = __builtin_amdgcn_mfma_f32_16x16x32_bf16(a_h, b_h, acc[nt], 0,0,0);
      acc[nt] = __builtin_amdgcn_mfma_f32_16x16x32_bf16(a_h, b_l, acc[nt], 0,0,0);
    }
  }
  float inv[4];
  #pragma unroll
  for (int r=0;r<4;r++){
    int m = m0 + wv*16 + lq*4 + r;
    inv[r] = (m < NN) ? 1.f/(jb.den[(size_t)m*4 + head] + 1e-16f) : 0.f;
  }
  #pragma unroll
  for (int nt=0; nt<4; nt++){
    int col = head*64 + nt*16 + lr;
    float bv = jb.bias[col];
    #pragma unroll
    for (int r=0;r<4;r++){
      int m = m0 + wv*16 + lq*4 + r;
      if (m < NN)
        jb.out[(size_t)m*256 + col] = f2bf(elu_f(acc[nt][r]*inv[r] + bv));
    }
  }
}

// ---------------- collapse attention vectors ----------------
struct CollapseJob { const float* W; const float* a; float* out; int K,H,C; };
struct CollapseArgs { CollapseJob j[8]; };
__global__ void collapse_kernel(CollapseArgs args){
  CollapseJob jb = args.j[blockIdx.x];
  int t = threadIdx.x;
  if (t < jb.K * jb.H){
    int k = t / jb.H, h = t % jb.H;
    const float* wr = jb.W + (size_t)k * (jb.H*jb.C) + h*jb.C;
    const float* ar = jb.a + h*jb.C;
    float s = 0.f;
    for (int c=0;c<jb.C;c++) s += wr[c]*ar[c];
    jb.out[h*jb.K + k] = s;   // layout [H,K]
  }
}

// build combined layer-1 weight [256 x 48]: cols 0..31 Ws, 32 cwS, 33 cwD, rest 0
__global__ __launch_bounds__(256) void prep1_kernel(
    const float* __restrict__ WsA, const float* __restrict__ cwSA, const float* __restrict__ cwDA,
    const float* __restrict__ WsB, const float* __restrict__ cwSB, const float* __restrict__ cwDB,
    float* __restrict__ WcA, float* __restrict__ WcB){
  const float* Ws  = blockIdx.x ? WsB  : WsA;
  const float* cwS = blockIdx.x ? cwSB : cwSA;
  const float* cwD = blockIdx.x ? cwDB : cwDA;
  float* Wc = blockIdx.x ? WcB : WcA;
  const int k = threadIdx.x;   // 256 rows
  #pragma unroll
  for (int n=0;n<32;n++) Wc[(size_t)k*48 + n] = Ws[(size_t)k*32 + n];
  Wc[(size_t)k*48 + 32] = cwS[k];
  Wc[(size_t)k*48 + 33] = cwD[k];
  #pragma unroll
  for (int n=34;n<48;n++) Wc[(size_t)k*48 + n] = 0.f;
}

// ---------------- fused dual matvec over bf16 X (layer 0 logits) ----------------
struct Mv2Job { const unsigned short* X; const float* cwA; const float* cwB;
                float* outA; float* outB; };
template<int K, int H>
__global__ __launch_bounds__(256) void matvec2_kernel(Mv2Job j0, Mv2Job j1){
  Mv2Job jb = blockIdx.y ? j1 : j0;
  __shared__ float cwa[K*H];
  __shared__ float cwb[K*H];
  for (int i=threadIdx.x; i<K*H; i+=256){ cwa[i] = jb.cwA[i]; cwb[i] = jb.cwB[i]; }
  __syncthreads();
  const int wid = threadIdx.x>>6, lane = threadIdx.x&63;
  const int node = blockIdx.x*4 + wid;
  if (node >= NN) return;
  float pa[H], pb[H];
  #pragma unroll
  for (int h=0;h<H;h++){ pa[h]=0.f; pb[h]=0.f; }
  #pragma unroll
  for (int kk=0; kk<K/64; kk++){
    float x = bf2f(jb.X[(size_t)node*K + kk*64 + lane]);
    #pragma unroll
    for (int h=0;h<H;h++){
      pa[h] += x*cwa[h*K + kk*64 + lane];
      pb[h] += x*cwb[h*K + kk*64 + lane];
    }
  }
  #pragma unroll
  for (int off=32; off>0; off>>=1){
    #pragma unroll
    for (int h=0;h<H;h++){
      pa[h] += __shfl_xor(pa[h], off, 64);
      pb[h] += __shfl_xor(pb[h], off, 64);
    }
  }
  if (lane==0){
    #pragma unroll
    for (int h=0;h<H;h++){
      jb.outA[(size_t)node*H + h] = pa[h];
      jb.outB[(size_t)node*H + h] = pb[h];
    }
  }
}

// ---------------- layer-0 pre-aggregation over hu/hi rows ----------------
struct AggPJob {
  const int* offs; const int* ssrc;
  const unsigned short* x;     // bf16 [NN,64]
  const unsigned short* coef;  // bf16 [E,4]
  unsigned short* agg;         // bf16 [NN,256]
  float* den;                  // fp32 [NN,4]
};
__global__ __launch_bounds__(256) void aggpre_kernel(AggPJob ja, AggPJob jbb){
  const AggPJob jb = blockIdx.y ? jbb : ja;
  const int wid = threadIdx.x>>6, lane = threadIdx.x&63;
  const int dst = blockIdx.x*4 + wid;
  if (dst >= NN) return;
  const int b0 = jb.offs[dst], b1 = jb.offs[dst+1];
  const int g  = lane >> 4;        // edge slot 0..3
  const int c4 = (lane & 15)*4;    // channel base
  // packed accumulators: .x accumulates edge e, .y accumulates edge e+4
  floatx2 accp[4][4];
  floatx2 denp[4];
  #pragma unroll
  for (int h=0;h<4;h++){
    denp[h] = (floatx2){0.f,0.f};
    #pragma unroll
    for (int c=0;c<4;c++) accp[h][c] = (floatx2){0.f,0.f};
  }
  int e = b0 + g;
  // unroll 2 paired into v_pk_fma_f32: 2 MACs/instr (kernel is VALU-issue bound)
  for (; e+4 < b1; e += 8){
    int s0 = jb.ssrc[e];
    int s1 = jb.ssrc[e+4];
    uint2 q0 = *(const uint2*)(jb.x + ((size_t)s0<<6) + c4);
    uint2 q1 = *(const uint2*)(jb.x + ((size_t)s1<<6) + c4);
    uint2 w0 = *(const uint2*)(jb.coef + (size_t)e*4);
    uint2 w1 = *(const uint2*)(jb.coef + (size_t)(e+4)*4);
    floatx2 xp[4], wp[4];
    xp[0] = pair_lo(q0.x, q1.x); xp[1] = pair_hi(q0.x, q1.x);
    xp[2] = pair_lo(q0.y, q1.y); xp[3] = pair_hi(q0.y, q1.y);
    wp[0] = pair_lo(w0.x, w1.x); wp[1] = pair_hi(w0.x, w1.x);
    wp[2] = pair_lo(w0.y, w1.y); wp[3] = pair_hi(w0.y, w1.y);
    #pragma unroll
    for (int h=0;h<4;h++){
      pk_add(denp[h], wp[h]);
      #pragma unroll
      for (int c=0;c<4;c++) pk_fma(accp[h][c], wp[h], xp[c]);
    }
  }
  float acc[4][4];
  float den[4];
  #pragma unroll
  for (int h=0;h<4;h++){
    den[h] = denp[h].x + denp[h].y;
    #pragma unroll
    for (int c=0;c<4;c++) acc[h][c] = accp[h][c].x + accp[h][c].y;
  }
  if (e < b1){
    int s = jb.ssrc[e];
    float4 xv = bf4_load(jb.x + ((size_t)s<<6) + c4);
    float4 wv = bf4_load(jb.coef + (size_t)e*4);
    acc[0][0]+=wv.x*xv.x; acc[0][1]+=wv.x*xv.y; acc[0][2]+=wv.x*xv.z; acc[0][3]+=wv.x*xv.w;
    acc[1][0]+=wv.y*xv.x; acc[1][1]+=wv.y*xv.y; acc[1][2]+=wv.y*xv.z; acc[1][3]+=wv.y*xv.w;
    acc[2][0]+=wv.z*xv.x; acc[2][1]+=wv.z*xv.y; acc[2][2]+=wv.z*xv.z; acc[2][3]+=wv.z*xv.w;
    acc[3][0]+=wv.w*xv.x; acc[3][1]+=wv.w*xv.y; acc[3][2]+=wv.w*xv.z; acc[3][3]+=wv.w*xv.w;
    den[0]+=wv.x; den[1]+=wv.y; den[2]+=wv.z; den[3]+=wv.w;
  }
  #pragma unroll
  for (int off=16; off<=32; off<<=1){
    #pragma unroll
    for (int h=0;h<4;h++){
      acc[h][0] += __shfl_xor(acc[h][0], off, 64);
      acc[h][1] += __shfl_xor(acc[h][1], off, 64);
      acc[h][2] += __shfl_xor(acc[h][2], off, 64);
      acc[h][3] += __shfl_xor(acc[h][3], off, 64);
      den[h]    += __shfl_xor(den[h],    off, 64);
    }
  }
  if (lane < 16){
    #pragma unroll
    for (int h=0;h<4;h++){
      float4 o = make_float4(acc[h][0], acc[h][1], acc[h][2], acc[h][3]);
      *(uint2*)(jb.agg + (size_t)dst*256 + h*64 + c4) = bf4_pack(o);
    }
    if (lane == 0)
      *(float4*)(jb.den + (size_t)dst*4) = make_float4(den[0],den[1],den[2],den[3]);
  }
}

// ---------------- layer-1 aggregation (softmax weight fused inline) ----------------
struct Agg1Job {
  const int* offs; const int* ssrc;
  const unsigned short* hs;   // bf16 [NN,32]
  const float* als; const float* ald;  // layer-1 logits
  const float* bias; float* out;
};
__global__ __launch_bounds__(256) void agg1_kernel(Agg1Job ja, Agg1Job jbb){
  const Agg1Job jb = blockIdx.y ? jbb : ja;
  const int wid = threadIdx.x>>6, lane = threadIdx.x&63;
  const int dst = blockIdx.x*4 + wid;
  if (dst >= NN) return;
  const int b0 = jb.offs[dst], b1 = jb.offs[dst+1];
  const float ad = jb.ald[dst];
  const int slot = lane>>3, c4 = (lane&7)*4;
  float4 acc = make_float4(0.f,0.f,0.f,0.f);
  float den = 0.f;
  int e = b0 + slot;
  for (; e+8 < b1; e += 16){
    int s0 = jb.ssrc[e], s1 = jb.ssrc[e+8];
    float a0 = jb.als[s0];
    float a1 = jb.als[s1];
    float4 v0 = bf4_load(jb.hs + ((size_t)s0<<5) + c4);
    float4 v1 = bf4_load(jb.hs + ((size_t)s1<<5) + c4);
    float w0 = __expf(lrelu_f(a0 + ad));
    float w1 = __expf(lrelu_f(a1 + ad));
    acc.x += w0*v0.x + w1*v1.x;
    acc.y += w0*v0.y + w1*v1.y;
    acc.z += w0*v0.z + w1*v1.z;
    acc.w += w0*v0.w + w1*v1.w;
    den += w0 + w1;
  }
  if (e < b1){
    int s = jb.ssrc[e];
    float w = __expf(lrelu_f(jb.als[s] + ad));
    float4 v = bf4_load(jb.hs + ((size_t)s<<5) + c4);
    acc.x += w*v.x; acc.y += w*v.y; acc.z += w*v.z; acc.w += w*v.w;
    den += w;
  }
  #pragma unroll
  for (int off=32; off>=8; off>>=1){
    acc.x += __shfl_xor(acc.x, off, 64);
    acc.y += __shfl_xor(acc.y, off, 64);
    acc.z += __shfl_xor(acc.z, off, 64);
    acc.w += __shfl_xor(acc.w, off, 64);
    den   += __shfl_xor(den,   off, 64);
  }
  if (lane < 8){
    const float inv = 1.f/(den + 1e-16f);
    float4 b = *(const float4*)(jb.bias + c4);
    float4 o = make_float4(acc.x*inv+b.x, acc.y*inv+b.y, acc.z*inv+b.z, acc.w*inv+b.w);
    *(float4*)(jb.out + (size_t)dst*32 + c4) = o;
  }
}

// ---------------- host glue ----------------
extern "C" void kernel_launch(void* const* d_in, const int* in_sizes, int n_in,
                              void* d_out, int out_size, void* d_ws, size_t ws_size,
                              hipStream_t stream)
{
  (void)in_sizes; (void)n_in; (void)out_size; (void)ws_size;
  const float* x_user   = (const float*)d_in[0];
  const float* x_item   = (const float*)d_in[1];
  const int*   e_u2i    = (const int*)  d_in[2];
  const int*   e_i2u    = (const int*)  d_in[3];
  const float* p_user_w = (const float*)d_in[4];
  const float* p_user_b = (const float*)d_in[5];
  const float* p_item_w = (const float*)d_in[6];
  const float* p_item_b = (const float*)d_in[7];
  const float* l0_u2i_ws=(const float*)d_in[8];
  const float* l0_u2i_wd=(const float*)d_in[9];
  const float* l0_u2i_as=(const float*)d_in[10];
  const float* l0_u2i_ad=(const float*)d_in[11];
  const float* l0_u2i_b =(const float*)d_in[12];
  const float* l0_i2u_ws=(const float*)d_in[13];
  const float* l0_i2u_wd=(const float*)d_in[14];
  const float* l0_i2u_as=(const float*)d_in[15];
  const float* l0_i2u_ad=(const float*)d_in[16];
  const float* l0_i2u_b =(const float*)d_in[17];
  const float* l1_u2i_ws=(const float*)d_in[18];
  const float* l1_u2i_wd=(const float*)d_in[19];
  const float* l1_u2i_as=(const float*)d_in[20];
  const float* l1_u2i_ad=(const float*)d_in[21];
  const float* l1_u2i_b =(const float*)d_in[22];
  const float* l1_i2u_ws=(const float*)d_in[23];
  const float* l1_i2u_wd=(const float*)d_in[24];
  const float* l1_i2u_as=(const float*)d_in[25];
  const float* l1_i2u_ad=(const float*)d_in[26];
  const float* l1_i2u_b =(const float*)d_in[27];

  char* base = (char*)d_ws;
  size_t off = 0;
  auto alloc = [&](size_t bytes)->void*{
    void* p = base + off;
    off += (bytes + 255) & ~(size_t)255;
    return p;
  };
  int* offs_u2i = (int*)alloc((size_t)(NN+1)*sizeof(int));
  int* offs_i2u = (int*)alloc((size_t)(NN+1)*sizeof(int));
  int* ssrc_u2i = (int*)alloc((size_t)NE*sizeof(int));
  int* ssrc_i2u = (int*)alloc((size_t)NE*sizeof(int));
  int* ghist    = (int*)alloc((size_t)2*200*sizeof(int));
  int* gbase    = (int*)alloc((size_t)2*200*sizeof(int));
  int* gcur     = (int*)alloc((size_t)2*200*sizeof(int));
  unsigned short* coef0_u2i = (unsigned short*)alloc((size_t)NE*4*sizeof(unsigned short));
  unsigned short* coef0_i2u = (unsigned short*)alloc((size_t)NE*4*sizeof(unsigned short));
  unsigned short* hu = (unsigned short*)alloc((size_t)NN*64*sizeof(unsigned short));
  unsigned short* hi = (unsigned short*)alloc((size_t)NN*64*sizeof(unsigned short));
  unsigned short* agg_u2i = (unsigned short*)alloc((size_t)NN*256*sizeof(unsigned short));
  unsigned short* agg_i2u = (unsigned short*)alloc((size_t)NN*256*sizeof(unsigned short));
  float* den_u2i = (float*)alloc((size_t)NN*4*sizeof(float));
  float* den_i2u = (float*)alloc((size_t)NN*4*sizeof(float));
  unsigned short* hu1 = (unsigned short*)alloc((size_t)NN*256*sizeof(unsigned short));
  unsigned short* hi1 = (unsigned short*)alloc((size_t)NN*256*sizeof(unsigned short));
  unsigned short* hs1_u2i = (unsigned short*)alloc((size_t)NN*32*sizeof(unsigned short));
  unsigned short* hs1_i2u = (unsigned short*)alloc((size_t)NN*32*sizeof(unsigned short));
  float* als0_u2i = (float*)alloc((size_t)NN*4*sizeof(float));
  float* ald0_u2i = (float*)alloc((size_t)NN*4*sizeof(float));
  float* als0_i2u = (float*)alloc((size_t)NN*4*sizeof(float));
  float* ald0_i2u = (float*)alloc((size_t)NN*4*sizeof(float));
  float* als1_u2i = (float*)alloc((size_t)NN*sizeof(float));
  float* ald1_u2i = (float*)alloc((size_t)NN*sizeof(float));
  float* als1_i2u = (float*)alloc((size_t)NN*sizeof(float));
  float* ald1_i2u = (float*)alloc((size_t)NN*sizeof(float));
  float* cw0s_u2i = (float*)alloc(256*sizeof(float));
  float* cw0d_u2i = (float*)alloc(256*sizeof(float));
  float* cw0s_i2u = (float*)alloc(256*sizeof(float));
  float* cw0d_i2u = (float*)alloc(256*sizeof(float));
  float* cw1s_u2i = (float*)alloc(256*sizeof(float));
  float* cw1d_u2i = (float*)alloc(256*sizeof(float));
  float* cw1s_i2u = (float*)alloc(256*sizeof(float));
  float* cw1d_i2u = (float*)alloc(256*sizeof(float));
  float* Wc_u2i   = (float*)alloc((size_t)256*48*sizeof(float));
  float* Wc_i2u   = (float*)alloc((size_t)256*48*sizeof(float));
  // pairs scratch aliases hu1/hi1: consumed by part2 before hgemm writes them
  int2* pairs_u2i = (int2*)hu1;
  int2* pairs_i2u = pairs_u2i + NE;

  const int GM = (NN + 63)/64;

  // ---- bucket sort stage A ----
  hipMemsetAsync(ghist, 0, (size_t)2*200*sizeof(int), stream);
  ghist_kernel<<<dim3(256,2), 256, 0, stream>>>(e_u2i, e_i2u, ghist);
  gscan_kernel<<<1, 256, 0, stream>>>(ghist, gbase, gcur);
  part1_kernel<<<dim3((NE+TILE1-1)/TILE1,2), 256, 0, stream>>>(
      e_u2i, e_i2u, gcur, pairs_u2i, pairs_i2u);

  // ---- input projections (+bias +ELU) -> bf16 (merged dual launch) ----
  mgemm_kernel<4,true,true,false,false><<<dim3(GM,1,2), 256, 0, stream>>>(
      MgJob{x_user, p_user_w, p_user_b, hu, nullptr, nullptr},
      MgJob{x_item, p_item_w, p_item_b, hi, nullptr, nullptr}, NN, 128, 64);

  // ---- collapse attention vectors ----
  CollapseArgs ca;
  ca.j[0] = {l0_u2i_ws, l0_u2i_as, cw0s_u2i, 64, 4, 64};
  ca.j[1] = {l0_u2i_wd, l0_u2i_ad, cw0d_u2i, 64, 4, 64};
  ca.j[2] = {l0_i2u_ws, l0_i2u_as, cw0s_i2u, 64, 4, 64};
  ca.j[3] = {l0_i2u_wd, l0_i2u_ad, cw0d_i2u, 64, 4, 64};
  ca.j[4] = {l1_u2i_ws, l1_u2i_as, cw1s_u2i, 256, 1, 32};
  ca.j[5] = {l1_u2i_wd, l1_u2i_ad, cw1d_u2i, 256, 1, 32};
  ca.j[6] = {l1_i2u_ws, l1_i2u_as, cw1s_i2u, 256, 1, 32};
  ca.j[7] = {l1_i2u_wd, l1_i2u_ad, cw1d_i2u, 256, 1, 32};
  collapse_kernel<<<8, 256, 0, stream>>>(ca);

  // ---- combined layer-1 weights (Ws | cwS | cwD) ----
  prep1_kernel<<<2, 256, 0, stream>>>(
      l1_u2i_ws, cw1s_u2i, cw1d_i2u,
      l1_i2u_ws, cw1s_i2u, cw1d_u2i,
      Wc_u2i, Wc_i2u);

  // ---- layer 0 logits ----
  matvec2_kernel<64,4><<<dim3(NN/4,2), 256, 0, stream>>>(
      Mv2Job{hu, cw0s_u2i, cw0d_i2u, als0_u2i, ald0_i2u},
      Mv2Job{hi, cw0s_i2u, cw0d_u2i, als0_i2u, ald0_u2i});

  // ---- bucket sort stage B ----
  part2_kernel<<<dim3(GB,2), 256, 0, stream>>>(
      Part2Job{pairs_u2i, gbase,       als0_u2i, ald0_u2i, ssrc_u2i, offs_u2i, coef0_u2i},
      Part2Job{pairs_i2u, gbase + 200, als0_i2u, ald0_i2u, ssrc_i2u, offs_i2u, coef0_i2u});

  // ---- layer 0: pre-aggregate hu/hi rows (128 B gathers, packed-fp32 MACs) ----
  aggpre_kernel<<<dim3(NN/4,2), 256, 0, stream>>>(
      AggPJob{offs_u2i, ssrc_u2i, hu, coef0_u2i, agg_u2i, den_u2i},
      AggPJob{offs_i2u, ssrc_i2u, hi, coef0_i2u, agg_i2u, den_i2u});

  // ---- layer 0: per-head GEMM + den-divide + bias + ELU -> hi1/hu1 bf16 ----
  hgemm_kernel<<<dim3(GM,4,2), 256, 0, stream>>>(
      HgJob{agg_u2i, l0_u2i_ws, den_u2i, l0_u2i_b, hi1},
      HgJob{agg_i2u, l0_i2u_ws, den_i2u, l0_i2u_b, hu1});

  // ---- layer 1: feature GEMMs with fused logit columns (merged dual launch) ----
  // hu1 @ Wc_u2i -> hs1_u2i (cols 0..31), als1_u2i (col 32), ald1_i2u (col 33)
  mgemm_kernel<3,false,true,true,true><<<dim3(GM,1,2), 256, 0, stream>>>(
      MgJob{hu1, Wc_u2i, nullptr, hs1_u2i, als1_u2i, ald1_i2u},
      MgJob{hi1, Wc_i2u, nullptr, hs1_i2u, als1_i2u, ald1_u2i}, NN, 256, 48);

  // ---- layer 1: aggregate (+bias), softmax weights computed inline ----
  float* hu2 = (float*)d_out;                  // first tuple element (users, i2u dst)
  float* hi2 = (float*)d_out + (size_t)NN*32;  // second tuple element (items, u2i dst)
  agg1_kernel<<<dim3(NN/4,2), 256, 0, stream>>>(
      Agg1Job{offs_u2i, ssrc_u2i, hs1_u2i, als1_u2i, ald1_u2i, l1_u2i_b, hi2},
      Agg1Job{offs_i2u, ssrc_i2u, hs1_i2u, als1_i2u, ald1_i2u, l1_i2u_b, hu2});
}

// Round 3
// 407.237 us; speedup vs baseline: 1.1958x; 1.1353x over previous
//
#include <hip/hip_runtime.h>
#include <cstdint>
#include <cstddef>

#define NN 50000
#define NE 800000
#define GB 196        // coarse buckets = ceil(NN/256)
#define TILE1 4096    // edges per part1 block
#define CAP 8192      // max edges per bucket in part2 LDS (mean 4082)

typedef __attribute__((ext_vector_type(8))) short short8;
typedef __attribute__((ext_vector_type(4))) float floatx4;

__device__ __forceinline__ float lrelu_f(float x){ return x >= 0.f ? x : 0.2f*x; }
__device__ __forceinline__ float elu_f(float x){ return x > 0.f ? x : __expf(x) - 1.f; }

__device__ __forceinline__ unsigned short f2bf(float f){
  unsigned int u = __float_as_uint(f);
  u += 0x7FFFu + ((u >> 16) & 1u);
  return (unsigned short)(u >> 16);
}
__device__ __forceinline__ float bf2f(unsigned int us){
  return __uint_as_float(us << 16);
}
__device__ __forceinline__ float4 bf4_load(const unsigned short* p){
  uint2 q = *(const uint2*)p;
  return make_float4(bf2f(q.x & 0xffffu), bf2f(q.x >> 16),
                     bf2f(q.y & 0xffffu), bf2f(q.y >> 16));
}
__device__ __forceinline__ uint2 bf4_pack(float4 o){
  uint2 p;
  p.x = (unsigned)f2bf(o.x) | ((unsigned)f2bf(o.y) << 16);
  p.y = (unsigned)f2bf(o.z) | ((unsigned)f2bf(o.w) << 16);
  return p;
}
__device__ __forceinline__ void split_bf(float a, unsigned short& h, unsigned short& l){
  h = f2bf(a);
  l = f2bf(a - bf2f(h));
}

// ---------------- two-level bucket sort of edges by dst ----------------
__global__ __launch_bounds__(256) void ghist_kernel(const int* __restrict__ e0,
                                                    const int* __restrict__ e1,
                                                    int* __restrict__ ghist){
  const int ty = blockIdx.y;
  const int* e = ty ? e1 : e0;
  __shared__ int h[GB];
  for (int j=threadIdx.x; j<GB; j+=256) h[j]=0;
  __syncthreads();
  for (int i = blockIdx.x*256 + threadIdx.x; i < NE; i += 256*256)
    atomicAdd(&h[e[NE+i]>>8], 1);
  __syncthreads();
  for (int j=threadIdx.x; j<GB; j+=256) if (h[j]) atomicAdd(&ghist[ty*200+j], h[j]);
}

__global__ __launch_bounds__(256) void gscan_kernel(const int* __restrict__ ghist,
                                                    int* __restrict__ gbase,
                                                    int* __restrict__ gcur){
  __shared__ int wb[4];
  const int t = threadIdx.x, wv = t>>6, l = t&63;
  for (int ty=0; ty<2; ++ty){
    int v = (t < GB) ? ghist[ty*200+t] : 0;
    int sum = v;
    #pragma unroll
    for (int off=1; off<64; off<<=1){
      int x = __shfl_up(sum, off, 64);
      if (l >= off) sum += x;
    }
    if (l == 63) wb[wv] = sum;
    __syncthreads();
    int wbase = 0;
    #pragma unroll
    for (int w=0; w<4; ++w) if (w < wv) wbase += wb[w];
    int excl = wbase + sum - v;
    if (t <= GB) gbase[ty*200+t] = excl;
    if (t <  GB) gcur [ty*200+t] = excl;
    __syncthreads();
  }
}

// partition with LDS staging: global writes are contiguous per-bucket runs
__global__ __launch_bounds__(256) void part1_kernel(const int* __restrict__ e0,
                                                    const int* __restrict__ e1,
                                                    int* __restrict__ gcur,
                                                    int2* __restrict__ p0,
                                                    int2* __restrict__ p1){
  const int ty = blockIdx.y;
  const int* e = ty ? e1 : e0;
  int2* pairs = ty ? p1 : p0;
  __shared__ int cnt[256];
  __shared__ int lstart[256];
  __shared__ int lcur[256];
  __shared__ int curg[GB];
  __shared__ int lsrc[TILE1];
  __shared__ int ldst[TILE1];
  __shared__ int wb[4];
  const int t = threadIdx.x;
  cnt[t] = 0;
  __syncthreads();
  int dreg[16], sreg[16];
  const int base = blockIdx.x*TILE1;
  const int ntile = min(TILE1, NE - base);
  #pragma unroll
  for (int it=0; it<16; ++it){
    int i = base + it*256 + t;
    int d = -1, s = 0;
    if (i < NE){ d = e[NE+i]; s = e[i]; atomicAdd(&cnt[d>>8], 1); }
    dreg[it] = d; sreg[it] = s;
  }
  __syncthreads();
  int c = cnt[t], sum = c;
  #pragma unroll
  for (int off=1; off<64; off<<=1){
    int x = __shfl_up(sum, off, 64);
    if ((t&63) >= off) sum += x;
  }
  if ((t&63) == 63) wb[t>>6] = sum;
  __syncthreads();
  int wbase = 0;
  #pragma unroll
  for (int w=0; w<4; ++w) if (w < (t>>6)) wbase += wb[w];
  int excl = wbase + sum - c;
  lstart[t] = excl;
  lcur[t] = excl;
  if (t < GB && c > 0) curg[t] = atomicAdd(&gcur[ty*200+t], c);
  __syncthreads();
  #pragma unroll
  for (int it=0; it<16; ++it){
    int d = dreg[it];
    if (d >= 0){
      int pos = atomicAdd(&lcur[d>>8], 1);
      lsrc[pos] = sreg[it];
      ldst[pos] = d;
    }
  }
  __syncthreads();
  for (int i=t; i<ntile; i+=256){
    int d = ldst[i];
    int j = d>>8;
    pairs[curg[j] + (i - lstart[j])] = make_int2(lsrc[i], d);
  }
}

// per-bucket LDS bin by dst + CSR offsets + fused layer-0 softmax weights (bf16).
struct Part2Job {
  const int2* pairs; const int* gbase;
  const float* als; const float* ald;   // [NN,4]
  int* ssrc; int* offs; unsigned short* coef;  // coef: [E,4] bf16
};
__global__ __launch_bounds__(256) void part2_kernel(Part2Job j0, Part2Job j1){
  const Part2Job jb = blockIdx.y ? j1 : j0;
  const int b = blockIdx.x;
  const int t = threadIdx.x;
  __shared__ int lcnt[256];
  __shared__ int lcur[256];
  __shared__ int wb[4];
  __shared__ int sorted_src[CAP];
  __shared__ unsigned char sorted_dl[CAP];
  const int gb0 = jb.gbase[b], gb1 = jb.gbase[b+1];
  const int n = gb1 - gb0;
  lcnt[t] = 0;
  __syncthreads();
  for (int i=t; i<n; i+=256)
    atomicAdd(&lcnt[jb.pairs[gb0+i].y - (b<<8)], 1);
  __syncthreads();
  int c = lcnt[t], sum = c;
  #pragma unroll
  for (int off=1; off<64; off<<=1){
    int x = __shfl_up(sum, off, 64);
    if ((t&63) >= off) sum += x;
  }
  if ((t&63) == 63) wb[t>>6] = sum;
  __syncthreads();
  int wbase = 0;
  #pragma unroll
  for (int w=0; w<4; ++w) if (w < (t>>6)) wbase += wb[w];
  int excl = wbase + sum - c;
  lcur[t] = excl;
  int g = (b<<8) + t;
  if (g <= NN) jb.offs[g] = gb0 + excl;
  __syncthreads();
  for (int i=t; i<n; i+=256){
    int2 pr = jb.pairs[gb0+i];
    int dl = pr.y - (b<<8);
    int pos = atomicAdd(&lcur[dl], 1);
    sorted_src[pos] = pr.x;
    sorted_dl[pos] = (unsigned char)dl;
  }
  __syncthreads();
  const float4* als4 = (const float4*)jb.als;
  const float4* ald4 = (const float4*)jb.ald;
  for (int i=t; i<n; i+=256){
    int s  = sorted_src[i];
    int dl = sorted_dl[i];
    float4 a  = als4[s];
    float4 ad = ald4[(b<<8)+dl];
    // no max-shift: |alpha| small at this model scale; softmax shift-invariant.
    float4 w;
    w.x = __expf(lrelu_f(a.x+ad.x));
    w.y = __expf(lrelu_f(a.y+ad.y));
    w.z = __expf(lrelu_f(a.z+ad.z));
    w.w = __expf(lrelu_f(a.w+ad.w));
    ((uint2*)jb.coef)[gb0+i] = bf4_pack(w);
    jb.ssrc[gb0+i] = s;
  }
}

// ---------------- MFMA GEMM: C = act(A[M,K] @ W[K,N] (+bias)) ----------------
// LG: logit-fused variant — GEMM N=48; cols 0..31 -> bf16 C (stride 32),
// col 32 -> fp32 outA[m], col 33 -> fp32 outB[m].
// LOGIT: proj variant (N=64) — additionally computes per-row dual logit dot
// products against cwS/cwD (layout [4][64]) -> outA[m*4+h], outB[m*4+h].
struct MgJob {
  const void* A; const float* W; const float* bias;
  void* C; float* outA; float* outB;
  const float* cwS; const float* cwD;
};
template<int NT, bool ELU, bool BF16OUT, bool BF16A, bool LG, bool LOGIT>
__global__ __launch_bounds__(256) void mgemm_kernel(MgJob j0, MgJob j1,
                                                    int M, int K, int N)
{
  const MgJob jb = blockIdx.z ? j1 : j0;
  constexpr int TN = NT*16;
  __shared__ __align__(16) unsigned short Ah[64*72];
  __shared__ __align__(16) unsigned short Al[BF16A ? 8 : 64*72];
  __shared__ __align__(16) unsigned short Bh[TN*72];
  __shared__ __align__(16) unsigned short Bl[TN*72];
  __shared__ float CwS[LOGIT ? 256 : 1];
  __shared__ float CwD[LOGIT ? 256 : 1];
  const int t = threadIdx.x;
  const int m0 = blockIdx.x*64;
  const int n0 = blockIdx.y*TN;
  const int wv = t>>6, l = t&63;
  const int lr = l&15, lq = l>>4;
  if constexpr (LOGIT){ CwS[t] = jb.cwS[t]; CwD[t] = jb.cwD[t]; }
  floatx4 acc[NT];
  #pragma unroll
  for (int i=0;i<NT;i++) acc[i] = (floatx4){0.f,0.f,0.f,0.f};

  for (int kt=0; kt<K; kt+=64){
    if constexpr (BF16A){
      const unsigned short* A = (const unsigned short*)jb.A;
      #pragma unroll
      for (int i=0;i<2;i++){
        int li = t + i*256;
        int r = li >> 3, c8 = (li & 7)*8;
        short8 v = {0,0,0,0,0,0,0,0};
        if (m0 + r < M) v = *(const short8*)(A + (size_t)(m0+r)*K + kt + c8);
        *(short8*)&Ah[r*72 + c8] = v;
      }
    } else {
      const float* A = (const float*)jb.A;
      #pragma unroll
      for (int i=0;i<4;i++){
        int li = t + i*256;
        int r = li >> 4, c4 = (li & 15)*4;
        float4 v = make_float4(0.f,0.f,0.f,0.f);
        if (m0 + r < M) v = *(const float4*)(A + (size_t)(m0+r)*K + kt + c4);
        unsigned short h0,h1,h2,h3,g0,g1,g2,g3;
        split_bf(v.x,h0,g0); split_bf(v.y,h1,g1);
        split_bf(v.z,h2,g2); split_bf(v.w,h3,g3);
        uint2 ph = { (unsigned)h0 | ((unsigned)h1<<16), (unsigned)h2 | ((unsigned)h3<<16) };
        uint2 pl = { (unsigned)g0 | ((unsigned)g1<<16), (unsigned)g2 | ((unsigned)g3<<16) };
        *(uint2*)&Ah[r*72 + c4] = ph;
        *(uint2*)&Al[r*72 + c4] = pl;
      }
    }
    #pragma unroll
    for (int i=0;i<NT;i++){
      int li = t + i*256;
      int k  = li / (TN/4);
      int n4 = (li % (TN/4))*4;
      float4 v = *(const float4*)(jb.W + (size_t)(kt+k)*N + n0 + n4);
      unsigned short h, g;
      split_bf(v.x,h,g); Bh[(n4+0)*72+k]=h; Bl[(n4+0)*72+k]=g;
      split_bf(v.y,h,g); Bh[(n4+1)*72+k]=h; Bl[(n4+1)*72+k]=g;
      split_bf(v.z,h,g); Bh[(n4+2)*72+k]=h; Bl[(n4+2)*72+k]=g;
      split_bf(v.w,h,g); Bh[(n4+3)*72+k]=h; Bl[(n4+3)*72+k]=g;
    }
    __syncthreads();
    #pragma unroll
    for (int ks=0; ks<2; ks++){
      const int koff = ks*32 + lq*8;
      short8 a_h = *(const short8*)&Ah[(wv*16+lr)*72 + koff];
      short8 a_l;
      if constexpr (!BF16A) a_l = *(const short8*)&Al[(wv*16+lr)*72 + koff];
      #pragma unroll
      for (int nt=0; nt<NT; nt++){
        short8 b_h = *(const short8*)&Bh[(nt*16+lr)*72 + koff];
        short8 b_l = *(const short8*)&Bl[(nt*16+lr)*72 + koff];
        acc[nt] = __builtin_amdgcn_mfma_f32_16x16x32_bf16(a_h, b_h, acc[nt], 0,0,0);
        acc[nt] = __builtin_amdgcn_mfma_f32_16x16x32_bf16(a_h, b_l, acc[nt], 0,0,0);
        if constexpr (!BF16A)
          acc[nt] = __builtin_amdgcn_mfma_f32_16x16x32_bf16(a_l, b_h, acc[nt], 0,0,0);
      }
    }
    __syncthreads();
  }
  float ls[LOGIT ? 4 : 1][LOGIT ? 4 : 1];   // [r][h]
  float ld_[LOGIT ? 4 : 1][LOGIT ? 4 : 1];
  if constexpr (LOGIT){
    #pragma unroll
    for (int r=0;r<4;r++)
      #pragma unroll
      for (int h=0;h<4;h++){ ls[r][h]=0.f; ld_[r][h]=0.f; }
  }
  #pragma unroll
  for (int nt=0; nt<NT; nt++){
    int n = n0 + nt*16 + lr;
    float bv = jb.bias ? jb.bias[n] : 0.f;
    #pragma unroll
    for (int r=0;r<4;r++){
      int m = m0 + wv*16 + lq*4 + r;
      if (m < M){
        float o = acc[nt][r] + bv;
        if (ELU) o = elu_f(o);
        if constexpr (LG){
          if (n < 32)       ((unsigned short*)jb.C)[(size_t)m*32 + n] = f2bf(o);
          else if (n == 32) jb.outA[m] = o;
          else if (n == 33) jb.outB[m] = o;
        } else {
          if (BF16OUT) ((unsigned short*)jb.C)[(size_t)m*N + n] = f2bf(o);
          else         ((float*)jb.C)[(size_t)m*N + n] = o;
        }
        if constexpr (LOGIT){
          #pragma unroll
          for (int h=0;h<4;h++){
            ls[r][h]  = fmaf(o, CwS[h*64 + n], ls[r][h]);
            ld_[r][h] = fmaf(o, CwD[h*64 + n], ld_[r][h]);
          }
        }
      }
    }
  }
  if constexpr (LOGIT){
    // reduce over the 16 lr-lanes (channels), then lane lr==0 writes 4 rows x 4 heads
    #pragma unroll
    for (int r=0;r<4;r++)
      #pragma unroll
      for (int h=0;h<4;h++){
        float a = ls[r][h], d = ld_[r][h];
        #pragma unroll
        for (int off=1; off<16; off<<=1){
          a += __shfl_xor(a, off, 64);
          d += __shfl_xor(d, off, 64);
        }
        ls[r][h]=a; ld_[r][h]=d;
      }
    if (lr == 0){
      #pragma unroll
      for (int r=0;r<4;r++){
        int m = m0 + wv*16 + lq*4 + r;
        if (m < M){
          #pragma unroll
          for (int h=0;h<4;h++){
            jb.outA[(size_t)m*4 + h] = ls[r][h];
            jb.outB[(size_t)m*4 + h] = ld_[r][h];
          }
        }
      }
    }
  }
}

// ---------------- per-head block GEMM: hi1[m, h*64+n] = elu((agg_h @ Ws_h)/den + b) ----
struct HgJob {
  const unsigned short* A; const float* W; const float* den;  // den [M,4]
  const float* bias; unsigned short* out;                      // out bf16 [M,256]
};
__global__ __launch_bounds__(256) void hgemm_kernel(HgJob j0, HgJob j1){
  const HgJob jb = blockIdx.z ? j1 : j0;
  const int head = blockIdx.y;
  const int m0 = blockIdx.x*64;
  __shared__ __align__(16) unsigned short Ah[64*72];
  __shared__ __align__(16) unsigned short Bh[64*72];
  __shared__ __align__(16) unsigned short Bl[64*72];
  const int t = threadIdx.x;
  const int wv = t>>6, l = t&63;
  const int lr = l&15, lq = l>>4;
  floatx4 acc[4];
  #pragma unroll
  for (int i=0;i<4;i++) acc[i] = (floatx4){0.f,0.f,0.f,0.f};
  #pragma unroll
  for (int i=0;i<2;i++){
    int li = t + i*256;
    int r = li >> 3, c8 = (li & 7)*8;
    short8 v = {0,0,0,0,0,0,0,0};
    if (m0 + r < NN) v = *(const short8*)(jb.A + (size_t)(m0+r)*256 + head*64 + c8);
    *(short8*)&Ah[r*72 + c8] = v;
  }
  #pragma unroll
  for (int i=0;i<4;i++){
    int li = t + i*256;
    int k  = li >> 4;
    int n4 = (li & 15)*4;
    float4 v = *(const float4*)(jb.W + (size_t)k*256 + head*64 + n4);
    unsigned short h, g;
    split_bf(v.x,h,g); Bh[(n4+0)*72+k]=h; Bl[(n4+0)*72+k]=g;
    split_bf(v.y,h,g); Bh[(n4+1)*72+k]=h; Bl[(n4+1)*72+k]=g;
    split_bf(v.z,h,g); Bh[(n4+2)*72+k]=h; Bl[(n4+2)*72+k]=g;
    split_bf(v.w,h,g); Bh[(n4+3)*72+k]=h; Bl[(n4+3)*72+k]=g;
  }
  __syncthreads();
  #pragma unroll
  for (int ks=0; ks<2; ks++){
    const int koff = ks*32 + lq*8;
    short8 a_h = *(const short8*)&Ah[(wv*16+lr)*72 + koff];
    #pragma unroll
    for (int nt=0; nt<4; nt++){
      short8 b_h = *(const short8*)&Bh[(nt*16+lr)*72 + koff];
      short8 b_l = *(const short8*)&Bl[(nt*16+lr)*72 + koff];
      acc[nt] = __builtin_amdgcn_mfma_f32_16x16x32_bf16(a_h, b_h, acc[nt], 0,0,0);
      acc[nt] = __builtin_amdgcn_mfma_f32_16x16x32_bf16(a_h, b_l, acc[nt], 0,0,0);
    }
  }
  float inv[4];
  #pragma unroll
  for (int r=0;r<4;r++){
    int m = m0 + wv*16 + lq*4 + r;
    inv[r] = (m < NN) ? 1.f/(jb.den[(size_t)m*4 + head] + 1e-16f) : 0.f;
  }
  #pragma unroll
  for (int nt=0; nt<4; nt++){
    int col = head*64 + nt*16 + lr;
    float bv = jb.bias[col];
    #pragma unroll
    for (int r=0;r<4;r++){
      int m = m0 + wv*16 + lq*4 + r;
      if (m < NN)
        jb.out[(size_t)m*256 + col] = f2bf(elu_f(acc[nt][r]*inv[r] + bv));
    }
  }
}

// ---------------- collapse attention vectors ----------------
struct CollapseJob { const float* W; const float* a; float* out; int K,H,C; };
struct CollapseArgs { CollapseJob j[8]; };
__global__ void collapse_kernel(CollapseArgs args){
  CollapseJob jb = args.j[blockIdx.x];
  int t = threadIdx.x;
  if (t < jb.K * jb.H){
    int k = t / jb.H, h = t % jb.H;
    const float* wr = jb.W + (size_t)k * (jb.H*jb.C) + h*jb.C;
    const float* ar = jb.a + h*jb.C;
    float s = 0.f;
    for (int c=0;c<jb.C;c++) s += wr[c]*ar[c];
    jb.out[h*jb.K + k] = s;   // layout [H,K]
  }
}

// build combined layer-1 weight [256 x 48]: cols 0..31 Ws, 32 cwS, 33 cwD, rest 0
__global__ __launch_bounds__(256) void prep1_kernel(
    const float* __restrict__ WsA, const float* __restrict__ cwSA, const float* __restrict__ cwDA,
    const float* __restrict__ WsB, const float* __restrict__ cwSB, const float* __restrict__ cwDB,
    float* __restrict__ WcA, float* __restrict__ WcB){
  const float* Ws  = blockIdx.x ? WsB  : WsA;
  const float* cwS = blockIdx.x ? cwSB : cwSA;
  const float* cwD = blockIdx.x ? cwDB : cwDA;
  float* Wc = blockIdx.x ? WcB : WcA;
  const int k = threadIdx.x;   // 256 rows
  #pragma unroll
  for (int n=0;n<32;n++) Wc[(size_t)k*48 + n] = Ws[(size_t)k*32 + n];
  Wc[(size_t)k*48 + 32] = cwS[k];
  Wc[(size_t)k*48 + 33] = cwD[k];
  #pragma unroll
  for (int n=34;n<48;n++) Wc[(size_t)k*48 + n] = 0.f;
}

// ---------------- layer-0 pre-aggregation over hu/hi rows ----------------
struct AggPJob {
  const int* offs; const int* ssrc;
  const unsigned short* x;     // bf16 [NN,64]
  const unsigned short* coef;  // bf16 [E,4]
  unsigned short* agg;         // bf16 [NN,256]
  float* den;                  // fp32 [NN,4]
};
__global__ __launch_bounds__(256) void aggpre_kernel(AggPJob ja, AggPJob jbb){
  const AggPJob jb = blockIdx.y ? jbb : ja;
  const int wid = threadIdx.x>>6, lane = threadIdx.x&63;
  const int dst = blockIdx.x*4 + wid;
  if (dst >= NN) return;
  const int b0 = jb.offs[dst], b1 = jb.offs[dst+1];
  const int g  = lane >> 4;        // edge slot 0..3
  const int c4 = (lane & 15)*4;    // channel base
  float acc[4][4];
  float den[4] = {0.f,0.f,0.f,0.f};
  #pragma unroll
  for (int h=0;h<4;h++){ acc[h][0]=0.f; acc[h][1]=0.f; acc[h][2]=0.f; acc[h][3]=0.f; }
  int e = b0 + g;
  // unroll 2: issue both gathers before the FMA block (memory-level parallelism)
  for (; e+4 < b1; e += 8){
    int s0 = jb.ssrc[e];
    int s1 = jb.ssrc[e+4];
    float4 xv0 = bf4_load(jb.x + ((size_t)s0<<6) + c4);
    float4 xv1 = bf4_load(jb.x + ((size_t)s1<<6) + c4);
    float4 wv0 = bf4_load(jb.coef + (size_t)e*4);
    float4 wv1 = bf4_load(jb.coef + (size_t)(e+4)*4);
    acc[0][0]+=wv0.x*xv0.x+wv1.x*xv1.x; acc[0][1]+=wv0.x*xv0.y+wv1.x*xv1.y;
    acc[0][2]+=wv0.x*xv0.z+wv1.x*xv1.z; acc[0][3]+=wv0.x*xv0.w+wv1.x*xv1.w;
    acc[1][0]+=wv0.y*xv0.x+wv1.y*xv1.x; acc[1][1]+=wv0.y*xv0.y+wv1.y*xv1.y;
    acc[1][2]+=wv0.y*xv0.z+wv1.y*xv1.z; acc[1][3]+=wv0.y*xv0.w+wv1.y*xv1.w;
    acc[2][0]+=wv0.z*xv0.x+wv1.z*xv1.x; acc[2][1]+=wv0.z*xv0.y+wv1.z*xv1.y;
    acc[2][2]+=wv0.z*xv0.z+wv1.z*xv1.z; acc[2][3]+=wv0.z*xv0.w+wv1.z*xv1.w;
    acc[3][0]+=wv0.w*xv0.x+wv1.w*xv1.x; acc[3][1]+=wv0.w*xv0.y+wv1.w*xv1.y;
    acc[3][2]+=wv0.w*xv0.z+wv1.w*xv1.z; acc[3][3]+=wv0.w*xv0.w+wv1.w*xv1.w;
    den[0]+=wv0.x+wv1.x; den[1]+=wv0.y+wv1.y; den[2]+=wv0.z+wv1.z; den[3]+=wv0.w+wv1.w;
  }
  if (e < b1){
    int s = jb.ssrc[e];
    float4 xv = bf4_load(jb.x + ((size_t)s<<6) + c4);
    float4 wv = bf4_load(jb.coef + (size_t)e*4);
    acc[0][0]+=wv.x*xv.x; acc[0][1]+=wv.x*xv.y; acc[0][2]+=wv.x*xv.z; acc[0][3]+=wv.x*xv.w;
    acc[1][0]+=wv.y*xv.x; acc[1][1]+=wv.y*xv.y; acc[1][2]+=wv.y*xv.z; acc[1][3]+=wv.y*xv.w;
    acc[2][0]+=wv.z*xv.x; acc[2][1]+=wv.z*xv.y; acc[2][2]+=wv.z*xv.z; acc[2][3]+=wv.z*xv.w;
    acc[3][0]+=wv.w*xv.x; acc[3][1]+=wv.w*xv.y; acc[3][2]+=wv.w*xv.z; acc[3][3]+=wv.w*xv.w;
    den[0]+=wv.x; den[1]+=wv.y; den[2]+=wv.z; den[3]+=wv.w;
  }
  #pragma unroll
  for (int off=16; off<=32; off<<=1){
    #pragma unroll
    for (int h=0;h<4;h++){
      acc[h][0] += __shfl_xor(acc[h][0], off, 64);
      acc[h][1] += __shfl_xor(acc[h][1], off, 64);
      acc[h][2] += __shfl_xor(acc[h][2], off, 64);
      acc[h][3] += __shfl_xor(acc[h][3], off, 64);
      den[h]    += __shfl_xor(den[h],    off, 64);
    }
  }
  if (lane < 16){
    #pragma unroll
    for (int h=0;h<4;h++){
      float4 o = make_float4(acc[h][0], acc[h][1], acc[h][2], acc[h][3]);
      *(uint2*)(jb.agg + (size_t)dst*256 + h*64 + c4) = bf4_pack(o);
    }
    if (lane == 0)
      *(float4*)(jb.den + (size_t)dst*4) = make_float4(den[0],den[1],den[2],den[3]);
  }
}

// ---------------- layer-1 aggregation (softmax weight fused inline) ----------------
struct Agg1Job {
  const int* offs; const int* ssrc;
  const unsigned short* hs;   // bf16 [NN,32]
  const float* als; const float* ald;  // layer-1 logits
  const float* bias; float* out;
};
__global__ __launch_bounds__(256) void agg1_kernel(Agg1Job ja, Agg1Job jbb){
  const Agg1Job jb = blockIdx.y ? jbb : ja;
  const int wid = threadIdx.x>>6, lane = threadIdx.x&63;
  const int dst = blockIdx.x*4 + wid;
  if (dst >= NN) return;
  const int b0 = jb.offs[dst], b1 = jb.offs[dst+1];
  const float ad = jb.ald[dst];
  const int slot = lane>>3, c4 = (lane&7)*4;
  float4 acc = make_float4(0.f,0.f,0.f,0.f);
  float den = 0.f;
  int e = b0 + slot;
  for (; e+8 < b1; e += 16){
    int s0 = jb.ssrc[e], s1 = jb.ssrc[e+8];
    float a0 = jb.als[s0];
    float a1 = jb.als[s1];
    float4 v0 = bf4_load(jb.hs + ((size_t)s0<<5) + c4);
    float4 v1 = bf4_load(jb.hs + ((size_t)s1<<5) + c4);
    float w0 = __expf(lrelu_f(a0 + ad));
    float w1 = __expf(lrelu_f(a1 + ad));
    acc.x += w0*v0.x + w1*v1.x;
    acc.y += w0*v0.y + w1*v1.y;
    acc.z += w0*v0.z + w1*v1.z;
    acc.w += w0*v0.w + w1*v1.w;
    den += w0 + w1;
  }
  if (e < b1){
    int s = jb.ssrc[e];
    float w = __expf(lrelu_f(jb.als[s] + ad));
    float4 v = bf4_load(jb.hs + ((size_t)s<<5) + c4);
    acc.x += w*v.x; acc.y += w*v.y; acc.z += w*v.z; acc.w += w*v.w;
    den += w;
  }
  #pragma unroll
  for (int off=32; off>=8; off>>=1){
    acc.x += __shfl_xor(acc.x, off, 64);
    acc.y += __shfl_xor(acc.y, off, 64);
    acc.z += __shfl_xor(acc.z, off, 64);
    acc.w += __shfl_xor(acc.w, off, 64);
    den   += __shfl_xor(den,   off, 64);
  }
  if (lane < 8){
    const float inv = 1.f/(den + 1e-16f);
    float4 b = *(const float4*)(jb.bias + c4);
    float4 o = make_float4(acc.x*inv+b.x, acc.y*inv+b.y, acc.z*inv+b.z, acc.w*inv+b.w);
    *(float4*)(jb.out + (size_t)dst*32 + c4) = o;
  }
}

// ---------------- host glue ----------------
extern "C" void kernel_launch(void* const* d_in, const int* in_sizes, int n_in,
                              void* d_out, int out_size, void* d_ws, size_t ws_size,
                              hipStream_t stream)
{
  (void)in_sizes; (void)n_in; (void)out_size; (void)ws_size;
  const float* x_user   = (const float*)d_in[0];
  const float* x_item   = (const float*)d_in[1];
  const int*   e_u2i    = (const int*)  d_in[2];
  const int*   e_i2u    = (const int*)  d_in[3];
  const float* p_user_w = (const float*)d_in[4];
  const float* p_user_b = (const float*)d_in[5];
  const float* p_item_w = (const float*)d_in[6];
  const float* p_item_b = (const float*)d_in[7];
  const float* l0_u2i_ws=(const float*)d_in[8];
  const float* l0_u2i_wd=(const float*)d_in[9];
  const float* l0_u2i_as=(const float*)d_in[10];
  const float* l0_u2i_ad=(const float*)d_in[11];
  const float* l0_u2i_b =(const float*)d_in[12];
  const float* l0_i2u_ws=(const float*)d_in[13];
  const float* l0_i2u_wd=(const float*)d_in[14];
  const float* l0_i2u_as=(const float*)d_in[15];
  const float* l0_i2u_ad=(const float*)d_in[16];
  const float* l0_i2u_b =(const float*)d_in[17];
  const float* l1_u2i_ws=(const float*)d_in[18];
  const float* l1_u2i_wd=(const float*)d_in[19];
  const float* l1_u2i_as=(const float*)d_in[20];
  const float* l1_u2i_ad=(const float*)d_in[21];
  const float* l1_u2i_b =(const float*)d_in[22];
  const float* l1_i2u_ws=(const float*)d_in[23];
  const float* l1_i2u_wd=(const float*)d_in[24];
  const float* l1_i2u_as=(const float*)d_in[25];
  const float* l1_i2u_ad=(const float*)d_in[26];
  const float* l1_i2u_b =(const float*)d_in[27];

  char* base = (char*)d_ws;
  size_t off = 0;
  auto alloc = [&](size_t bytes)->void*{
    void* p = base + off;
    off += (bytes + 255) & ~(size_t)255;
    return p;
  };
  int* offs_u2i = (int*)alloc((size_t)(NN+1)*sizeof(int));
  int* offs_i2u = (int*)alloc((size_t)(NN+1)*sizeof(int));
  int* ssrc_u2i = (int*)alloc((size_t)NE*sizeof(int));
  int* ssrc_i2u = (int*)alloc((size_t)NE*sizeof(int));
  int* ghist    = (int*)alloc((size_t)2*200*sizeof(int));
  int* gbase    = (int*)alloc((size_t)2*200*sizeof(int));
  int* gcur     = (int*)alloc((size_t)2*200*sizeof(int));
  unsigned short* coef0_u2i = (unsigned short*)alloc((size_t)NE*4*sizeof(unsigned short));
  unsigned short* coef0_i2u = (unsigned short*)alloc((size_t)NE*4*sizeof(unsigned short));
  unsigned short* hu = (unsigned short*)alloc((size_t)NN*64*sizeof(unsigned short));
  unsigned short* hi = (unsigned short*)alloc((size_t)NN*64*sizeof(unsigned short));
  unsigned short* agg_u2i = (unsigned short*)alloc((size_t)NN*256*sizeof(unsigned short));
  unsigned short* agg_i2u = (unsigned short*)alloc((size_t)NN*256*sizeof(unsigned short));
  float* den_u2i = (float*)alloc((size_t)NN*4*sizeof(float));
  float* den_i2u = (float*)alloc((size_t)NN*4*sizeof(float));
  unsigned short* hu1 = (unsigned short*)alloc((size_t)NN*256*sizeof(unsigned short));
  unsigned short* hi1 = (unsigned short*)alloc((size_t)NN*256*sizeof(unsigned short));
  unsigned short* hs1_u2i = (unsigned short*)alloc((size_t)NN*32*sizeof(unsigned short));
  unsigned short* hs1_i2u = (unsigned short*)alloc((size_t)NN*32*sizeof(unsigned short));
  float* als0_u2i = (float*)alloc((size_t)NN*4*sizeof(float));
  float* ald0_u2i = (float*)alloc((size_t)NN*4*sizeof(float));
  float* als0_i2u = (float*)alloc((size_t)NN*4*sizeof(float));
  float* ald0_i2u = (float*)alloc((size_t)NN*4*sizeof(float));
  float* als1_u2i = (float*)alloc((size_t)NN*sizeof(float));
  float* ald1_u2i = (float*)alloc((size_t)NN*sizeof(float));
  float* als1_i2u = (float*)alloc((size_t)NN*sizeof(float));
  float* ald1_i2u = (float*)alloc((size_t)NN*sizeof(float));
  float* cw0s_u2i = (float*)alloc(256*sizeof(float));
  float* cw0d_u2i = (float*)alloc(256*sizeof(float));
  float* cw0s_i2u = (float*)alloc(256*sizeof(float));
  float* cw0d_i2u = (float*)alloc(256*sizeof(float));
  float* cw1s_u2i = (float*)alloc(256*sizeof(float));
  float* cw1d_u2i = (float*)alloc(256*sizeof(float));
  float* cw1s_i2u = (float*)alloc(256*sizeof(float));
  float* cw1d_i2u = (float*)alloc(256*sizeof(float));
  float* Wc_u2i   = (float*)alloc((size_t)256*48*sizeof(float));
  float* Wc_i2u   = (float*)alloc((size_t)256*48*sizeof(float));
  // pairs scratch aliases hu1/hi1: consumed by part2 before hgemm writes them
  int2* pairs_u2i = (int2*)hu1;
  int2* pairs_i2u = pairs_u2i + NE;

  const int GM = (NN + 63)/64;

  // ---- bucket sort stage A ----
  hipMemsetAsync(ghist, 0, (size_t)2*200*sizeof(int), stream);
  ghist_kernel<<<dim3(256,2), 256, 0, stream>>>(e_u2i, e_i2u, ghist);
  gscan_kernel<<<1, 256, 0, stream>>>(ghist, gbase, gcur);
  part1_kernel<<<dim3((NE+TILE1-1)/TILE1,2), 256, 0, stream>>>(
      e_u2i, e_i2u, gcur, pairs_u2i, pairs_i2u);

  // ---- collapse attention vectors (needed by proj's fused logits) ----
  CollapseArgs ca;
  ca.j[0] = {l0_u2i_ws, l0_u2i_as, cw0s_u2i, 64, 4, 64};
  ca.j[1] = {l0_u2i_wd, l0_u2i_ad, cw0d_u2i, 64, 4, 64};
  ca.j[2] = {l0_i2u_ws, l0_i2u_as, cw0s_i2u, 64, 4, 64};
  ca.j[3] = {l0_i2u_wd, l0_i2u_ad, cw0d_i2u, 64, 4, 64};
  ca.j[4] = {l1_u2i_ws, l1_u2i_as, cw1s_u2i, 256, 1, 32};
  ca.j[5] = {l1_u2i_wd, l1_u2i_ad, cw1d_u2i, 256, 1, 32};
  ca.j[6] = {l1_i2u_ws, l1_i2u_as, cw1s_i2u, 256, 1, 32};
  ca.j[7] = {l1_i2u_wd, l1_i2u_ad, cw1d_i2u, 256, 1, 32};
  collapse_kernel<<<8, 256, 0, stream>>>(ca);

  // ---- input projections (+bias +ELU) -> bf16, with fused layer-0 logits ----
  // hu row -> als0_u2i (S-side of u2i) and ald0_i2u (D-side of i2u); vice versa.
  mgemm_kernel<4,true,true,false,false,true><<<dim3(GM,1,2), 256, 0, stream>>>(
      MgJob{x_user, p_user_w, p_user_b, hu, als0_u2i, ald0_i2u, cw0s_u2i, cw0d_i2u},
      MgJob{x_item, p_item_w, p_item_b, hi, als0_i2u, ald0_u2i, cw0s_i2u, cw0d_u2i},
      NN, 128, 64);

  // ---- combined layer-1 weights (Ws | cwS | cwD) ----
  prep1_kernel<<<2, 256, 0, stream>>>(
      l1_u2i_ws, cw1s_u2i, cw1d_i2u,
      l1_i2u_ws, cw1s_i2u, cw1d_u2i,
      Wc_u2i, Wc_i2u);

  // ---- bucket sort stage B ----
  part2_kernel<<<dim3(GB,2), 256, 0, stream>>>(
      Part2Job{pairs_u2i, gbase,       als0_u2i, ald0_u2i, ssrc_u2i, offs_u2i, coef0_u2i},
      Part2Job{pairs_i2u, gbase + 200, als0_i2u, ald0_i2u, ssrc_i2u, offs_i2u, coef0_i2u});

  // ---- layer 0: pre-aggregate hu/hi rows (128 B gathers, unroll-2) ----
  aggpre_kernel<<<dim3(NN/4,2), 256, 0, stream>>>(
      AggPJob{offs_u2i, ssrc_u2i, hu, coef0_u2i, agg_u2i, den_u2i},
      AggPJob{offs_i2u, ssrc_i2u, hi, coef0_i2u, agg_i2u, den_i2u});

  // ---- layer 0: per-head GEMM + den-divide + bias + ELU -> hi1/hu1 bf16 ----
  hgemm_kernel<<<dim3(GM,4,2), 256, 0, stream>>>(
      HgJob{agg_u2i, l0_u2i_ws, den_u2i, l0_u2i_b, hi1},
      HgJob{agg_i2u, l0_i2u_ws, den_i2u, l0_i2u_b, hu1});

  // ---- layer 1: feature GEMMs with fused logit columns (merged dual launch) ----
  // hu1 @ Wc_u2i -> hs1_u2i (cols 0..31), als1_u2i (col 32), ald1_i2u (col 33)
  mgemm_kernel<3,false,true,true,true,false><<<dim3(GM,1,2), 256, 0, stream>>>(
      MgJob{hu1, Wc_u2i, nullptr, hs1_u2i, als1_u2i, ald1_i2u, nullptr, nullptr},
      MgJob{hi1, Wc_i2u, nullptr, hs1_i2u, als1_i2u, ald1_u2i, nullptr, nullptr},
      NN, 256, 48);

  // ---- layer 1: aggregate (+bias), softmax weights computed inline ----
  float* hu2 = (float*)d_out;                  // first tuple element (users, i2u dst)
  float* hi2 = (float*)d_out + (size_t)NN*32;  // second tuple element (items, u2i dst)
  agg1_kernel<<<dim3(NN/4,2), 256, 0, stream>>>(
      Agg1Job{offs_u2i, ssrc_u2i, hs1_u2i, als1_u2i, ald1_u2i, l1_u2i_b, hi2},
      Agg1Job{offs_i2u, ssrc_i2u, hs1_i2u, als1_i2u, ald1_i2u, l1_i2u_b, hu2});
}

// Round 4
// 406.380 us; speedup vs baseline: 1.1983x; 1.0021x over previous
//
#include <hip/hip_runtime.h>
#include <cstdint>
#include <cstddef>

#define NN 50000
#define NE 800000
#define GB 196        // coarse buckets = ceil(NN/256)
#define TILE1 4096    // edges per part1 block
#define CAP 8192      // max edges per bucket in part2 LDS (mean 4082)

typedef __attribute__((ext_vector_type(8))) short short8;
typedef __attribute__((ext_vector_type(4))) float floatx4;

__device__ __forceinline__ float lrelu_f(float x){ return x >= 0.f ? x : 0.2f*x; }
__device__ __forceinline__ float elu_f(float x){ return x > 0.f ? x : __expf(x) - 1.f; }

__device__ __forceinline__ unsigned short f2bf(float f){
  unsigned int u = __float_as_uint(f);
  u += 0x7FFFu + ((u >> 16) & 1u);
  return (unsigned short)(u >> 16);
}
__device__ __forceinline__ float bf2f(unsigned int us){
  return __uint_as_float(us << 16);
}
__device__ __forceinline__ float4 bf4_load(const unsigned short* p){
  uint2 q = *(const uint2*)p;
  return make_float4(bf2f(q.x & 0xffffu), bf2f(q.x >> 16),
                     bf2f(q.y & 0xffffu), bf2f(q.y >> 16));
}
__device__ __forceinline__ uint2 bf4_pack(float4 o){
  uint2 p;
  p.x = (unsigned)f2bf(o.x) | ((unsigned)f2bf(o.y) << 16);
  p.y = (unsigned)f2bf(o.z) | ((unsigned)f2bf(o.w) << 16);
  return p;
}
__device__ __forceinline__ void split_bf(float a, unsigned short& h, unsigned short& l){
  h = f2bf(a);
  l = f2bf(a - bf2f(h));
}

// v_dot2_f32_bf16: acc += a.bf16[0]*b.bf16[0] + a.bf16[1]*b.bf16[1]
// single-dword operands + tied f32 accumulator => no mov/regpair overhead
__device__ __forceinline__ float dot2bf(float acc, unsigned a, unsigned b){
  asm("v_dot2_f32_bf16 %0, %1, %2, %0" : "+v"(acc) : "v"(a), "v"(b));
  return acc;
}

// ---------------- two-level bucket sort of edges by dst ----------------
__global__ __launch_bounds__(256) void ghist_kernel(const int* __restrict__ e0,
                                                    const int* __restrict__ e1,
                                                    int* __restrict__ ghist){
  const int ty = blockIdx.y;
  const int* e = ty ? e1 : e0;
  __shared__ int h[GB];
  for (int j=threadIdx.x; j<GB; j+=256) h[j]=0;
  __syncthreads();
  for (int i = blockIdx.x*256 + threadIdx.x; i < NE; i += 256*256)
    atomicAdd(&h[e[NE+i]>>8], 1);
  __syncthreads();
  for (int j=threadIdx.x; j<GB; j+=256) if (h[j]) atomicAdd(&ghist[ty*200+j], h[j]);
}

__global__ __launch_bounds__(256) void gscan_kernel(const int* __restrict__ ghist,
                                                    int* __restrict__ gbase,
                                                    int* __restrict__ gcur){
  __shared__ int wb[4];
  const int t = threadIdx.x, wv = t>>6, l = t&63;
  for (int ty=0; ty<2; ++ty){
    int v = (t < GB) ? ghist[ty*200+t] : 0;
    int sum = v;
    #pragma unroll
    for (int off=1; off<64; off<<=1){
      int x = __shfl_up(sum, off, 64);
      if (l >= off) sum += x;
    }
    if (l == 63) wb[wv] = sum;
    __syncthreads();
    int wbase = 0;
    #pragma unroll
    for (int w=0; w<4; ++w) if (w < wv) wbase += wb[w];
    int excl = wbase + sum - v;
    if (t <= GB) gbase[ty*200+t] = excl;
    if (t <  GB) gcur [ty*200+t] = excl;
    __syncthreads();
  }
}

// partition with LDS staging: global writes are contiguous per-bucket runs
__global__ __launch_bounds__(256) void part1_kernel(const int* __restrict__ e0,
                                                    const int* __restrict__ e1,
                                                    int* __restrict__ gcur,
                                                    int2* __restrict__ p0,
                                                    int2* __restrict__ p1){
  const int ty = blockIdx.y;
  const int* e = ty ? e1 : e0;
  int2* pairs = ty ? p1 : p0;
  __shared__ int cnt[256];
  __shared__ int lstart[256];
  __shared__ int lcur[256];
  __shared__ int curg[GB];
  __shared__ int lsrc[TILE1];
  __shared__ int ldst[TILE1];
  __shared__ int wb[4];
  const int t = threadIdx.x;
  cnt[t] = 0;
  __syncthreads();
  int dreg[16], sreg[16];
  const int base = blockIdx.x*TILE1;
  const int ntile = min(TILE1, NE - base);
  #pragma unroll
  for (int it=0; it<16; ++it){
    int i = base + it*256 + t;
    int d = -1, s = 0;
    if (i < NE){ d = e[NE+i]; s = e[i]; atomicAdd(&cnt[d>>8], 1); }
    dreg[it] = d; sreg[it] = s;
  }
  __syncthreads();
  int c = cnt[t], sum = c;
  #pragma unroll
  for (int off=1; off<64; off<<=1){
    int x = __shfl_up(sum, off, 64);
    if ((t&63) >= off) sum += x;
  }
  if ((t&63) == 63) wb[t>>6] = sum;
  __syncthreads();
  int wbase = 0;
  #pragma unroll
  for (int w=0; w<4; ++w) if (w < (t>>6)) wbase += wb[w];
  int excl = wbase + sum - c;
  lstart[t] = excl;
  lcur[t] = excl;
  if (t < GB && c > 0) curg[t] = atomicAdd(&gcur[ty*200+t], c);
  __syncthreads();
  #pragma unroll
  for (int it=0; it<16; ++it){
    int d = dreg[it];
    if (d >= 0){
      int pos = atomicAdd(&lcur[d>>8], 1);
      lsrc[pos] = sreg[it];
      ldst[pos] = d;
    }
  }
  __syncthreads();
  for (int i=t; i<ntile; i+=256){
    int d = ldst[i];
    int j = d>>8;
    pairs[curg[j] + (i - lstart[j])] = make_int2(lsrc[i], d);
  }
}

// per-bucket LDS bin by dst + CSR offsets + fused layer-0 softmax weights (bf16).
struct Part2Job {
  const int2* pairs; const int* gbase;
  const float* als; const float* ald;   // [NN,4]
  int* ssrc; int* offs; unsigned short* coef;  // coef: [E,4] bf16
};
__global__ __launch_bounds__(256) void part2_kernel(Part2Job j0, Part2Job j1){
  const Part2Job jb = blockIdx.y ? j1 : j0;
  const int b = blockIdx.x;
  const int t = threadIdx.x;
  __shared__ int lcnt[256];
  __shared__ int lcur[256];
  __shared__ int wb[4];
  __shared__ int sorted_src[CAP];
  __shared__ unsigned char sorted_dl[CAP];
  const int gb0 = jb.gbase[b], gb1 = jb.gbase[b+1];
  const int n = gb1 - gb0;
  lcnt[t] = 0;
  __syncthreads();
  for (int i=t; i<n; i+=256)
    atomicAdd(&lcnt[jb.pairs[gb0+i].y - (b<<8)], 1);
  __syncthreads();
  int c = lcnt[t], sum = c;
  #pragma unroll
  for (int off=1; off<64; off<<=1){
    int x = __shfl_up(sum, off, 64);
    if ((t&63) >= off) sum += x;
  }
  if ((t&63) == 63) wb[t>>6] = sum;
  __syncthreads();
  int wbase = 0;
  #pragma unroll
  for (int w=0; w<4; ++w) if (w < (t>>6)) wbase += wb[w];
  int excl = wbase + sum - c;
  lcur[t] = excl;
  int g = (b<<8) + t;
  if (g <= NN) jb.offs[g] = gb0 + excl;
  __syncthreads();
  for (int i=t; i<n; i+=256){
    int2 pr = jb.pairs[gb0+i];
    int dl = pr.y - (b<<8);
    int pos = atomicAdd(&lcur[dl], 1);
    sorted_src[pos] = pr.x;
    sorted_dl[pos] = (unsigned char)dl;
  }
  __syncthreads();
  const float4* als4 = (const float4*)jb.als;
  const float4* ald4 = (const float4*)jb.ald;
  for (int i=t; i<n; i+=256){
    int s  = sorted_src[i];
    int dl = sorted_dl[i];
    float4 a  = als4[s];
    float4 ad = ald4[(b<<8)+dl];
    // no max-shift: |alpha| small at this model scale; softmax shift-invariant.
    float4 w;
    w.x = __expf(lrelu_f(a.x+ad.x));
    w.y = __expf(lrelu_f(a.y+ad.y));
    w.z = __expf(lrelu_f(a.z+ad.z));
    w.w = __expf(lrelu_f(a.w+ad.w));
    ((uint2*)jb.coef)[gb0+i] = bf4_pack(w);
    jb.ssrc[gb0+i] = s;
  }
}

// ---------------- MFMA GEMM: C = act(A[M,K] @ W[K,N] (+bias)) ----------------
// LG: logit-fused variant — GEMM N=48; cols 0..31 -> bf16 C (stride 32),
// col 32 -> fp32 outA[m], col 33 -> fp32 outB[m].
// LOGIT: proj variant (N=64) — additionally computes per-row dual logit dot
// products against cwS/cwD (layout [4][64]) -> outA[m*4+h], outB[m*4+h].
struct MgJob {
  const void* A; const float* W; const float* bias;
  void* C; float* outA; float* outB;
  const float* cwS; const float* cwD;
};
template<int NT, bool ELU, bool BF16OUT, bool BF16A, bool LG, bool LOGIT>
__global__ __launch_bounds__(256) void mgemm_kernel(MgJob j0, MgJob j1,
                                                    int M, int K, int N)
{
  const MgJob jb = blockIdx.z ? j1 : j0;
  constexpr int TN = NT*16;
  __shared__ __align__(16) unsigned short Ah[64*72];
  __shared__ __align__(16) unsigned short Al[BF16A ? 8 : 64*72];
  __shared__ __align__(16) unsigned short Bh[TN*72];
  __shared__ __align__(16) unsigned short Bl[TN*72];
  __shared__ float CwS[LOGIT ? 256 : 1];
  __shared__ float CwD[LOGIT ? 256 : 1];
  const int t = threadIdx.x;
  const int m0 = blockIdx.x*64;
  const int n0 = blockIdx.y*TN;
  const int wv = t>>6, l = t&63;
  const int lr = l&15, lq = l>>4;
  if constexpr (LOGIT){ CwS[t] = jb.cwS[t]; CwD[t] = jb.cwD[t]; }
  floatx4 acc[NT];
  #pragma unroll
  for (int i=0;i<NT;i++) acc[i] = (floatx4){0.f,0.f,0.f,0.f};

  for (int kt=0; kt<K; kt+=64){
    if constexpr (BF16A){
      const unsigned short* A = (const unsigned short*)jb.A;
      #pragma unroll
      for (int i=0;i<2;i++){
        int li = t + i*256;
        int r = li >> 3, c8 = (li & 7)*8;
        short8 v = {0,0,0,0,0,0,0,0};
        if (m0 + r < M) v = *(const short8*)(A + (size_t)(m0+r)*K + kt + c8);
        *(short8*)&Ah[r*72 + c8] = v;
      }
    } else {
      const float* A = (const float*)jb.A;
      #pragma unroll
      for (int i=0;i<4;i++){
        int li = t + i*256;
        int r = li >> 4, c4 = (li & 15)*4;
        float4 v = make_float4(0.f,0.f,0.f,0.f);
        if (m0 + r < M) v = *(const float4*)(A + (size_t)(m0+r)*K + kt + c4);
        unsigned short h0,h1,h2,h3,g0,g1,g2,g3;
        split_bf(v.x,h0,g0); split_bf(v.y,h1,g1);
        split_bf(v.z,h2,g2); split_bf(v.w,h3,g3);
        uint2 ph = { (unsigned)h0 | ((unsigned)h1<<16), (unsigned)h2 | ((unsigned)h3<<16) };
        uint2 pl = { (unsigned)g0 | ((unsigned)g1<<16), (unsigned)g2 | ((unsigned)g3<<16) };
        *(uint2*)&Ah[r*72 + c4] = ph;
        *(uint2*)&Al[r*72 + c4] = pl;
      }
    }
    #pragma unroll
    for (int i=0;i<NT;i++){
      int li = t + i*256;
      int k  = li / (TN/4);
      int n4 = (li % (TN/4))*4;
      float4 v = *(const float4*)(jb.W + (size_t)(kt+k)*N + n0 + n4);
      unsigned short h, g;
      split_bf(v.x,h,g); Bh[(n4+0)*72+k]=h; Bl[(n4+0)*72+k]=g;
      split_bf(v.y,h,g); Bh[(n4+1)*72+k]=h; Bl[(n4+1)*72+k]=g;
      split_bf(v.z,h,g); Bh[(n4+2)*72+k]=h; Bl[(n4+2)*72+k]=g;
      split_bf(v.w,h,g); Bh[(n4+3)*72+k]=h; Bl[(n4+3)*72+k]=g;
    }
    __syncthreads();
    #pragma unroll
    for (int ks=0; ks<2; ks++){
      const int koff = ks*32 + lq*8;
      short8 a_h = *(const short8*)&Ah[(wv*16+lr)*72 + koff];
      short8 a_l;
      if constexpr (!BF16A) a_l = *(const short8*)&Al[(wv*16+lr)*72 + koff];
      #pragma unroll
      for (int nt=0; nt<NT; nt++){
        short8 b_h = *(const short8*)&Bh[(nt*16+lr)*72 + koff];
        short8 b_l = *(const short8*)&Bl[(nt*16+lr)*72 + koff];
        acc[nt] = __builtin_amdgcn_mfma_f32_16x16x32_bf16(a_h, b_h, acc[nt], 0,0,0);
        acc[nt] = __builtin_amdgcn_mfma_f32_16x16x32_bf16(a_h, b_l, acc[nt], 0,0,0);
        if constexpr (!BF16A)
          acc[nt] = __builtin_amdgcn_mfma_f32_16x16x32_bf16(a_l, b_h, acc[nt], 0,0,0);
      }
    }
    __syncthreads();
  }
  float ls[LOGIT ? 4 : 1][LOGIT ? 4 : 1];   // [r][h]
  float ld_[LOGIT ? 4 : 1][LOGIT ? 4 : 1];
  if constexpr (LOGIT){
    #pragma unroll
    for (int r=0;r<4;r++)
      #pragma unroll
      for (int h=0;h<4;h++){ ls[r][h]=0.f; ld_[r][h]=0.f; }
  }
  #pragma unroll
  for (int nt=0; nt<NT; nt++){
    int n = n0 + nt*16 + lr;
    float bv = jb.bias ? jb.bias[n] : 0.f;
    #pragma unroll
    for (int r=0;r<4;r++){
      int m = m0 + wv*16 + lq*4 + r;
      if (m < M){
        float o = acc[nt][r] + bv;
        if (ELU) o = elu_f(o);
        if constexpr (LG){
          if (n < 32)       ((unsigned short*)jb.C)[(size_t)m*32 + n] = f2bf(o);
          else if (n == 32) jb.outA[m] = o;
          else if (n == 33) jb.outB[m] = o;
        } else {
          if (BF16OUT) ((unsigned short*)jb.C)[(size_t)m*N + n] = f2bf(o);
          else         ((float*)jb.C)[(size_t)m*N + n] = o;
        }
        if constexpr (LOGIT){
          #pragma unroll
          for (int h=0;h<4;h++){
            ls[r][h]  = fmaf(o, CwS[h*64 + n], ls[r][h]);
            ld_[r][h] = fmaf(o, CwD[h*64 + n], ld_[r][h]);
          }
        }
      }
    }
  }
  if constexpr (LOGIT){
    // reduce over the 16 lr-lanes (channels), then lane lr==0 writes 4 rows x 4 heads
    #pragma unroll
    for (int r=0;r<4;r++)
      #pragma unroll
      for (int h=0;h<4;h++){
        float a = ls[r][h], d = ld_[r][h];
        #pragma unroll
        for (int off=1; off<16; off<<=1){
          a += __shfl_xor(a, off, 64);
          d += __shfl_xor(d, off, 64);
        }
        ls[r][h]=a; ld_[r][h]=d;
      }
    if (lr == 0){
      #pragma unroll
      for (int r=0;r<4;r++){
        int m = m0 + wv*16 + lq*4 + r;
        if (m < M){
          #pragma unroll
          for (int h=0;h<4;h++){
            jb.outA[(size_t)m*4 + h] = ls[r][h];
            jb.outB[(size_t)m*4 + h] = ld_[r][h];
          }
        }
      }
    }
  }
}

// ---------------- per-head block GEMM: hi1[m, h*64+n] = elu((agg_h @ Ws_h)/den + b) ----
struct HgJob {
  const unsigned short* A; const float* W; const float* den;  // den [M,4]
  const float* bias; unsigned short* out;                      // out bf16 [M,256]
};
__global__ __launch_bounds__(256) void hgemm_kernel(HgJob j0, HgJob j1){
  const HgJob jb = blockIdx.z ? j1 : j0;
  const int head = blockIdx.y;
  const int m0 = blockIdx.x*64;
  __shared__ __align__(16) unsigned short Ah[64*72];
  __shared__ __align__(16) unsigned short Bh[64*72];
  __shared__ __align__(16) unsigned short Bl[64*72];
  const int t = threadIdx.x;
  const int wv = t>>6, l = t&63;
  const int lr = l&15, lq = l>>4;
  floatx4 acc[4];
  #pragma unroll
  for (int i=0;i<4;i++) acc[i] = (floatx4){0.f,0.f,0.f,0.f};
  #pragma unroll
  for (int i=0;i<2;i++){
    int li = t + i*256;
    int r = li >> 3, c8 = (li & 7)*8;
    short8 v = {0,0,0,0,0,0,0,0};
    if (m0 + r < NN) v = *(const short8*)(jb.A + (size_t)(m0+r)*256 + head*64 + c8);
    *(short8*)&Ah[r*72 + c8] = v;
  }
  #pragma unroll
  for (int i=0;i<4;i++){
    int li = t + i*256;
    int k  = li >> 4;
    int n4 = (li & 15)*4;
    float4 v = *(const float4*)(jb.W + (size_t)k*256 + head*64 + n4);
    unsigned short h, g;
    split_bf(v.x,h,g); Bh[(n4+0)*72+k]=h; Bl[(n4+0)*72+k]=g;
    split_bf(v.y,h,g); Bh[(n4+1)*72+k]=h; Bl[(n4+1)*72+k]=g;
    split_bf(v.z,h,g); Bh[(n4+2)*72+k]=h; Bl[(n4+2)*72+k]=g;
    split_bf(v.w,h,g); Bh[(n4+3)*72+k]=h; Bl[(n4+3)*72+k]=g;
  }
  __syncthreads();
  #pragma unroll
  for (int ks=0; ks<2; ks++){
    const int koff = ks*32 + lq*8;
    short8 a_h = *(const short8*)&Ah[(wv*16+lr)*72 + koff];
    #pragma unroll
    for (int nt=0; nt<4; nt++){
      short8 b_h = *(const short8*)&Bh[(nt*16+lr)*72 + koff];
      short8 b_l = *(const short8*)&Bl[(nt*16+lr)*72 + koff];
      acc[nt] = __builtin_amdgcn_mfma_f32_16x16x32_bf16(a_h, b_h, acc[nt], 0,0,0);
      acc[nt] = __builtin_amdgcn_mfma_f32_16x16x32_bf16(a_h, b_l, acc[nt], 0,0,0);
    }
  }
  float inv[4];
  #pragma unroll
  for (int r=0;r<4;r++){
    int m = m0 + wv*16 + lq*4 + r;
    inv[r] = (m < NN) ? 1.f/(jb.den[(size_t)m*4 + head] + 1e-16f) : 0.f;
  }
  #pragma unroll
  for (int nt=0; nt<4; nt++){
    int col = head*64 + nt*16 + lr;
    float bv = jb.bias[col];
    #pragma unroll
    for (int r=0;r<4;r++){
      int m = m0 + wv*16 + lq*4 + r;
      if (m < NN)
        jb.out[(size_t)m*256 + col] = f2bf(elu_f(acc[nt][r]*inv[r] + bv));
    }
  }
}

// ---------------- collapse attention vectors ----------------
struct CollapseJob { const float* W; const float* a; float* out; int K,H,C; };
struct CollapseArgs { CollapseJob j[8]; };
__global__ void collapse_kernel(CollapseArgs args){
  CollapseJob jb = args.j[blockIdx.x];
  int t = threadIdx.x;
  if (t < jb.K * jb.H){
    int k = t / jb.H, h = t % jb.H;
    const float* wr = jb.W + (size_t)k * (jb.H*jb.C) + h*jb.C;
    const float* ar = jb.a + h*jb.C;
    float s = 0.f;
    for (int c=0;c<jb.C;c++) s += wr[c]*ar[c];
    jb.out[h*jb.K + k] = s;   // layout [H,K]
  }
}

// build combined layer-1 weight [256 x 48]: cols 0..31 Ws, 32 cwS, 33 cwD, rest 0
__global__ __launch_bounds__(256) void prep1_kernel(
    const float* __restrict__ WsA, const float* __restrict__ cwSA, const float* __restrict__ cwDA,
    const float* __restrict__ WsB, const float* __restrict__ cwSB, const float* __restrict__ cwDB,
    float* __restrict__ WcA, float* __restrict__ WcB){
  const float* Ws  = blockIdx.x ? WsB  : WsA;
  const float* cwS = blockIdx.x ? cwSB : cwSA;
  const float* cwD = blockIdx.x ? cwDB : cwDA;
  float* Wc = blockIdx.x ? WcB : WcA;
  const int k = threadIdx.x;   // 256 rows
  #pragma unroll
  for (int n=0;n<32;n++) Wc[(size_t)k*48 + n] = Ws[(size_t)k*32 + n];
  Wc[(size_t)k*48 + 32] = cwS[k];
  Wc[(size_t)k*48 + 33] = cwD[k];
  #pragma unroll
  for (int n=34;n<48;n++) Wc[(size_t)k*48 + n] = 0.f;
}

// ---------------- layer-0 pre-aggregation over hu/hi rows ----------------
struct AggPJob {
  const int* offs; const int* ssrc;
  const unsigned short* x;     // bf16 [NN,64]
  const unsigned short* coef;  // bf16 [E,4]
  unsigned short* agg;         // bf16 [NN,256]
  float* den;                  // fp32 [NN,4]
};
__global__ __launch_bounds__(256) void aggpre_kernel(AggPJob ja, AggPJob jbb){
  const AggPJob jb = blockIdx.y ? jbb : ja;
  const int wid = threadIdx.x>>6, lane = threadIdx.x&63;
  const int dst = blockIdx.x*4 + wid;
  if (dst >= NN) return;
  const int b0 = jb.offs[dst], b1 = jb.offs[dst+1];
  const int g  = lane >> 4;        // edge slot 0..3
  const int c4 = (lane & 15)*4;    // channel base
  float acc[4][4];
  float den[4] = {0.f,0.f,0.f,0.f};
  #pragma unroll
  for (int h=0;h<4;h++){ acc[h][0]=0.f; acc[h][1]=0.f; acc[h][2]=0.f; acc[h][3]=0.f; }
  const unsigned ONE2 = 0x3F803F80u;  // packed bf16 (1.0, 1.0)
  int e = b0 + g;
  // unroll 2, paired into v_dot2_f32_bf16: operands stay bf16 (no unpack),
  // 1 instr = both edges' MAC. 8 v_perm interleave the edge pairs.
  for (; e+4 < b1; e += 8){
    int s0 = jb.ssrc[e];
    int s1 = jb.ssrc[e+4];
    uint2 q0 = *(const uint2*)(jb.x + ((size_t)s0<<6) + c4);
    uint2 q1 = *(const uint2*)(jb.x + ((size_t)s1<<6) + c4);
    uint2 w0 = *(const uint2*)(jb.coef + (size_t)e*4);
    uint2 w1 = *(const uint2*)(jb.coef + (size_t)(e+4)*4);
    // (a,b,sel): a supplies bytes 4-7, b supplies bytes 0-3
    unsigned xp0 = __builtin_amdgcn_perm(q1.x, q0.x, 0x05040100u); // (x0[c+0], x1[c+0])
    unsigned xp1 = __builtin_amdgcn_perm(q1.x, q0.x, 0x07060302u); // (x0[c+1], x1[c+1])
    unsigned xp2 = __builtin_amdgcn_perm(q1.y, q0.y, 0x05040100u);
    unsigned xp3 = __builtin_amdgcn_perm(q1.y, q0.y, 0x07060302u);
    unsigned wp0 = __builtin_amdgcn_perm(w1.x, w0.x, 0x05040100u); // (w0[h0], w1[h0])
    unsigned wp1 = __builtin_amdgcn_perm(w1.x, w0.x, 0x07060302u);
    unsigned wp2 = __builtin_amdgcn_perm(w1.y, w0.y, 0x05040100u);
    unsigned wp3 = __builtin_amdgcn_perm(w1.y, w0.y, 0x07060302u);
    acc[0][0]=dot2bf(acc[0][0],wp0,xp0); acc[0][1]=dot2bf(acc[0][1],wp0,xp1);
    acc[0][2]=dot2bf(acc[0][2],wp0,xp2); acc[0][3]=dot2bf(acc[0][3],wp0,xp3);
    acc[1][0]=dot2bf(acc[1][0],wp1,xp0); acc[1][1]=dot2bf(acc[1][1],wp1,xp1);
    acc[1][2]=dot2bf(acc[1][2],wp1,xp2); acc[1][3]=dot2bf(acc[1][3],wp1,xp3);
    acc[2][0]=dot2bf(acc[2][0],wp2,xp0); acc[2][1]=dot2bf(acc[2][1],wp2,xp1);
    acc[2][2]=dot2bf(acc[2][2],wp2,xp2); acc[2][3]=dot2bf(acc[2][3],wp2,xp3);
    acc[3][0]=dot2bf(acc[3][0],wp3,xp0); acc[3][1]=dot2bf(acc[3][1],wp3,xp1);
    acc[3][2]=dot2bf(acc[3][2],wp3,xp2); acc[3][3]=dot2bf(acc[3][3],wp3,xp3);
    den[0]=dot2bf(den[0],wp0,ONE2); den[1]=dot2bf(den[1],wp1,ONE2);
    den[2]=dot2bf(den[2],wp2,ONE2); den[3]=dot2bf(den[3],wp3,ONE2);
  }
  if (e < b1){
    int s = jb.ssrc[e];
    float4 xv = bf4_load(jb.x + ((size_t)s<<6) + c4);
    float4 wv = bf4_load(jb.coef + (size_t)e*4);
    acc[0][0]+=wv.x*xv.x; acc[0][1]+=wv.x*xv.y; acc[0][2]+=wv.x*xv.z; acc[0][3]+=wv.x*xv.w;
    acc[1][0]+=wv.y*xv.x; acc[1][1]+=wv.y*xv.y; acc[1][2]+=wv.y*xv.z; acc[1][3]+=wv.y*xv.w;
    acc[2][0]+=wv.z*xv.x; acc[2][1]+=wv.z*xv.y; acc[2][2]+=wv.z*xv.z; acc[2][3]+=wv.z*xv.w;
    acc[3][0]+=wv.w*xv.x; acc[3][1]+=wv.w*xv.y; acc[3][2]+=wv.w*xv.z; acc[3][3]+=wv.w*xv.w;
    den[0]+=wv.x; den[1]+=wv.y; den[2]+=wv.z; den[3]+=wv.w;
  }
  #pragma unroll
  for (int off=16; off<=32; off<<=1){
    #pragma unroll
    for (int h=0;h<4;h++){
      acc[h][0] += __shfl_xor(acc[h][0], off, 64);
      acc[h][1] += __shfl_xor(acc[h][1], off, 64);
      acc[h][2] += __shfl_xor(acc[h][2], off, 64);
      acc[h][3] += __shfl_xor(acc[h][3], off, 64);
      den[h]    += __shfl_xor(den[h],    off, 64);
    }
  }
  if (lane < 16){
    #pragma unroll
    for (int h=0;h<4;h++){
      float4 o = make_float4(acc[h][0], acc[h][1], acc[h][2], acc[h][3]);
      *(uint2*)(jb.agg + (size_t)dst*256 + h*64 + c4) = bf4_pack(o);
    }
    if (lane == 0)
      *(float4*)(jb.den + (size_t)dst*4) = make_float4(den[0],den[1],den[2],den[3]);
  }
}

// ---------------- layer-1 aggregation (softmax weight fused inline) ----------------
struct Agg1Job {
  const int* offs; const int* ssrc;
  const unsigned short* hs;   // bf16 [NN,32]
  const float* als; const float* ald;  // layer-1 logits
  const float* bias; float* out;
};
__global__ __launch_bounds__(256) void agg1_kernel(Agg1Job ja, Agg1Job jbb){
  const Agg1Job jb = blockIdx.y ? jbb : ja;
  const int wid = threadIdx.x>>6, lane = threadIdx.x&63;
  const int dst = blockIdx.x*4 + wid;
  if (dst >= NN) return;
  const int b0 = jb.offs[dst], b1 = jb.offs[dst+1];
  const float ad = jb.ald[dst];
  const int slot = lane>>3, c4 = (lane&7)*4;
  float4 acc = make_float4(0.f,0.f,0.f,0.f);
  float den = 0.f;
  int e = b0 + slot;
  for (; e+8 < b1; e += 16){
    int s0 = jb.ssrc[e], s1 = jb.ssrc[e+8];
    float a0 = jb.als[s0];
    float a1 = jb.als[s1];
    float4 v0 = bf4_load(jb.hs + ((size_t)s0<<5) + c4);
    float4 v1 = bf4_load(jb.hs + ((size_t)s1<<5) + c4);
    float w0 = __expf(lrelu_f(a0 + ad));
    float w1 = __expf(lrelu_f(a1 + ad));
    acc.x += w0*v0.x + w1*v1.x;
    acc.y += w0*v0.y + w1*v1.y;
    acc.z += w0*v0.z + w1*v1.z;
    acc.w += w0*v0.w + w1*v1.w;
    den += w0 + w1;
  }
  if (e < b1){
    int s = jb.ssrc[e];
    float w = __expf(lrelu_f(jb.als[s] + ad));
    float4 v = bf4_load(jb.hs + ((size_t)s<<5) + c4);
    acc.x += w*v.x; acc.y += w*v.y; acc.z += w*v.z; acc.w += w*v.w;
    den += w;
  }
  #pragma unroll
  for (int off=32; off>=8; off>>=1){
    acc.x += __shfl_xor(acc.x, off, 64);
    acc.y += __shfl_xor(acc.y, off, 64);
    acc.z += __shfl_xor(acc.z, off, 64);
    acc.w += __shfl_xor(acc.w, off, 64);
    den   += __shfl_xor(den,   off, 64);
  }
  if (lane < 8){
    const float inv = 1.f/(den + 1e-16f);
    float4 b = *(const float4*)(jb.bias + c4);
    float4 o = make_float4(acc.x*inv+b.x, acc.y*inv+b.y, acc.z*inv+b.z, acc.w*inv+b.w);
    *(float4*)(jb.out + (size_t)dst*32 + c4) = o;
  }
}

// ---------------- host glue ----------------
extern "C" void kernel_launch(void* const* d_in, const int* in_sizes, int n_in,
                              void* d_out, int out_size, void* d_ws, size_t ws_size,
                              hipStream_t stream)
{
  (void)in_sizes; (void)n_in; (void)out_size; (void)ws_size;
  const float* x_user   = (const float*)d_in[0];
  const float* x_item   = (const float*)d_in[1];
  const int*   e_u2i    = (const int*)  d_in[2];
  const int*   e_i2u    = (const int*)  d_in[3];
  const float* p_user_w = (const float*)d_in[4];
  const float* p_user_b = (const float*)d_in[5];
  const float* p_item_w = (const float*)d_in[6];
  const float* p_item_b = (const float*)d_in[7];
  const float* l0_u2i_ws=(const float*)d_in[8];
  const float* l0_u2i_wd=(const float*)d_in[9];
  const float* l0_u2i_as=(const float*)d_in[10];
  const float* l0_u2i_ad=(const float*)d_in[11];
  const float* l0_u2i_b =(const float*)d_in[12];
  const float* l0_i2u_ws=(const float*)d_in[13];
  const float* l0_i2u_wd=(const float*)d_in[14];
  const float* l0_i2u_as=(const float*)d_in[15];
  const float* l0_i2u_ad=(const float*)d_in[16];
  const float* l0_i2u_b =(const float*)d_in[17];
  const float* l1_u2i_ws=(const float*)d_in[18];
  const float* l1_u2i_wd=(const float*)d_in[19];
  const float* l1_u2i_as=(const float*)d_in[20];
  const float* l1_u2i_ad=(const float*)d_in[21];
  const float* l1_u2i_b =(const float*)d_in[22];
  const float* l1_i2u_ws=(const float*)d_in[23];
  const float* l1_i2u_wd=(const float*)d_in[24];
  const float* l1_i2u_as=(const float*)d_in[25];
  const float* l1_i2u_ad=(const float*)d_in[26];
  const float* l1_i2u_b =(const float*)d_in[27];

  char* base = (char*)d_ws;
  size_t off = 0;
  auto alloc = [&](size_t bytes)->void*{
    void* p = base + off;
    off += (bytes + 255) & ~(size_t)255;
    return p;
  };
  int* offs_u2i = (int*)alloc((size_t)(NN+1)*sizeof(int));
  int* offs_i2u = (int*)alloc((size_t)(NN+1)*sizeof(int));
  int* ssrc_u2i = (int*)alloc((size_t)NE*sizeof(int));
  int* ssrc_i2u = (int*)alloc((size_t)NE*sizeof(int));
  int* ghist    = (int*)alloc((size_t)2*200*sizeof(int));
  int* gbase    = (int*)alloc((size_t)2*200*sizeof(int));
  int* gcur     = (int*)alloc((size_t)2*200*sizeof(int));
  unsigned short* coef0_u2i = (unsigned short*)alloc((size_t)NE*4*sizeof(unsigned short));
  unsigned short* coef0_i2u = (unsigned short*)alloc((size_t)NE*4*sizeof(unsigned short));
  unsigned short* hu = (unsigned short*)alloc((size_t)NN*64*sizeof(unsigned short));
  unsigned short* hi = (unsigned short*)alloc((size_t)NN*64*sizeof(unsigned short));
  unsigned short* agg_u2i = (unsigned short*)alloc((size_t)NN*256*sizeof(unsigned short));
  unsigned short* agg_i2u = (unsigned short*)alloc((size_t)NN*256*sizeof(unsigned short));
  float* den_u2i = (float*)alloc((size_t)NN*4*sizeof(float));
  float* den_i2u = (float*)alloc((size_t)NN*4*sizeof(float));
  unsigned short* hu1 = (unsigned short*)alloc((size_t)NN*256*sizeof(unsigned short));
  unsigned short* hi1 = (unsigned short*)alloc((size_t)NN*256*sizeof(unsigned short));
  unsigned short* hs1_u2i = (unsigned short*)alloc((size_t)NN*32*sizeof(unsigned short));
  unsigned short* hs1_i2u = (unsigned short*)alloc((size_t)NN*32*sizeof(unsigned short));
  float* als0_u2i = (float*)alloc((size_t)NN*4*sizeof(float));
  float* ald0_u2i = (float*)alloc((size_t)NN*4*sizeof(float));
  float* als0_i2u = (float*)alloc((size_t)NN*4*sizeof(float));
  float* ald0_i2u = (float*)alloc((size_t)NN*4*sizeof(float));
  float* als1_u2i = (float*)alloc((size_t)NN*sizeof(float));
  float* ald1_u2i = (float*)alloc((size_t)NN*sizeof(float));
  float* als1_i2u = (float*)alloc((size_t)NN*sizeof(float));
  float* ald1_i2u = (float*)alloc((size_t)NN*sizeof(float));
  float* cw0s_u2i = (float*)alloc(256*sizeof(float));
  float* cw0d_u2i = (float*)alloc(256*sizeof(float));
  float* cw0s_i2u = (float*)alloc(256*sizeof(float));
  float* cw0d_i2u = (float*)alloc(256*sizeof(float));
  float* cw1s_u2i = (float*)alloc(256*sizeof(float));
  float* cw1d_u2i = (float*)alloc(256*sizeof(float));
  float* cw1s_i2u = (float*)alloc(256*sizeof(float));
  float* cw1d_i2u = (float*)alloc(256*sizeof(float));
  float* Wc_u2i   = (float*)alloc((size_t)256*48*sizeof(float));
  float* Wc_i2u   = (float*)alloc((size_t)256*48*sizeof(float));
  // pairs scratch aliases hu1/hi1: consumed by part2 before hgemm writes them
  int2* pairs_u2i = (int2*)hu1;
  int2* pairs_i2u = pairs_u2i + NE;

  const int GM = (NN + 63)/64;

  // ---- bucket sort stage A ----
  hipMemsetAsync(ghist, 0, (size_t)2*200*sizeof(int), stream);
  ghist_kernel<<<dim3(256,2), 256, 0, stream>>>(e_u2i, e_i2u, ghist);
  gscan_kernel<<<1, 256, 0, stream>>>(ghist, gbase, gcur);
  part1_kernel<<<dim3((NE+TILE1-1)/TILE1,2), 256, 0, stream>>>(
      e_u2i, e_i2u, gcur, pairs_u2i, pairs_i2u);

  // ---- collapse attention vectors (needed by proj's fused logits) ----
  CollapseArgs ca;
  ca.j[0] = {l0_u2i_ws, l0_u2i_as, cw0s_u2i, 64, 4, 64};
  ca.j[1] = {l0_u2i_wd, l0_u2i_ad, cw0d_u2i, 64, 4, 64};
  ca.j[2] = {l0_i2u_ws, l0_i2u_as, cw0s_i2u, 64, 4, 64};
  ca.j[3] = {l0_i2u_wd, l0_i2u_ad, cw0d_i2u, 64, 4, 64};
  ca.j[4] = {l1_u2i_ws, l1_u2i_as, cw1s_u2i, 256, 1, 32};
  ca.j[5] = {l1_u2i_wd, l1_u2i_ad, cw1d_u2i, 256, 1, 32};
  ca.j[6] = {l1_i2u_ws, l1_i2u_as, cw1s_i2u, 256, 1, 32};
  ca.j[7] = {l1_i2u_wd, l1_i2u_ad, cw1d_i2u, 256, 1, 32};
  collapse_kernel<<<8, 256, 0, stream>>>(ca);

  // ---- input projections (+bias +ELU) -> bf16, with fused layer-0 logits ----
  // hu row -> als0_u2i (S-side of u2i) and ald0_i2u (D-side of i2u); vice versa.
  mgemm_kernel<4,true,true,false,false,true><<<dim3(GM,1,2), 256, 0, stream>>>(
      MgJob{x_user, p_user_w, p_user_b, hu, als0_u2i, ald0_i2u, cw0s_u2i, cw0d_i2u},
      MgJob{x_item, p_item_w, p_item_b, hi, als0_i2u, ald0_u2i, cw0s_i2u, cw0d_u2i},
      NN, 128, 64);

  // ---- combined layer-1 weights (Ws | cwS | cwD) ----
  prep1_kernel<<<2, 256, 0, stream>>>(
      l1_u2i_ws, cw1s_u2i, cw1d_i2u,
      l1_i2u_ws, cw1s_i2u, cw1d_u2i,
      Wc_u2i, Wc_i2u);

  // ---- bucket sort stage B ----
  part2_kernel<<<dim3(GB,2), 256, 0, stream>>>(
      Part2Job{pairs_u2i, gbase,       als0_u2i, ald0_u2i, ssrc_u2i, offs_u2i, coef0_u2i},
      Part2Job{pairs_i2u, gbase + 200, als0_i2u, ald0_i2u, ssrc_i2u, offs_i2u, coef0_i2u});

  // ---- layer 0: pre-aggregate hu/hi rows (bf16 dot2 MACs, unroll-2) ----
  aggpre_kernel<<<dim3(NN/4,2), 256, 0, stream>>>(
      AggPJob{offs_u2i, ssrc_u2i, hu, coef0_u2i, agg_u2i, den_u2i},
      AggPJob{offs_i2u, ssrc_i2u, hi, coef0_i2u, agg_i2u, den_i2u});

  // ---- layer 0: per-head GEMM + den-divide + bias + ELU -> hi1/hu1 bf16 ----
  hgemm_kernel<<<dim3(GM,4,2), 256, 0, stream>>>(
      HgJob{agg_u2i, l0_u2i_ws, den_u2i, l0_u2i_b, hi1},
      HgJob{agg_i2u, l0_i2u_ws, den_i2u, l0_i2u_b, hu1});

  // ---- layer 1: feature GEMMs with fused logit columns (merged dual launch) ----
  // hu1 @ Wc_u2i -> hs1_u2i (cols 0..31), als1_u2i (col 32), ald1_i2u (col 33)
  mgemm_kernel<3,false,true,true,true,false><<<dim3(GM,1,2), 256, 0, stream>>>(
      MgJob{hu1, Wc_u2i, nullptr, hs1_u2i, als1_u2i, ald1_i2u, nullptr, nullptr},
      MgJob{hi1, Wc_i2u, nullptr, hs1_i2u, als1_i2u, ald1_u2i, nullptr, nullptr},
      NN, 256, 48);

  // ---- layer 1: aggregate (+bias), softmax weights computed inline ----
  float* hu2 = (float*)d_out;                  // first tuple element (users, i2u dst)
  float* hi2 = (float*)d_out + (size_t)NN*32;  // second tuple element (items, u2i dst)
  agg1_kernel<<<dim3(NN/4,2), 256, 0, stream>>>(
      Agg1Job{offs_u2i, ssrc_u2i, hs1_u2i, als1_u2i, ald1_u2i, l1_u2i_b, hi2},
      Agg1Job{offs_i2u, ssrc_i2u, hs1_i2u, als1_i2u, ald1_i2u, l1_i2u_b, hu2});
}

// Round 5
// 398.542 us; speedup vs baseline: 1.2219x; 1.0197x over previous
//
#include <hip/hip_runtime.h>
#include <cstdint>
#include <cstddef>

#define NN 50000
#define NE 800000
#define GB 196        // coarse buckets = ceil(NN/256)
#define TILE1 4096    // edges per part1 block
#define CAP 8192      // max edges per bucket in part2 LDS (mean 4082)

typedef __attribute__((ext_vector_type(8))) short short8;
typedef __attribute__((ext_vector_type(4))) float floatx4;

__device__ __forceinline__ float lrelu_f(float x){ return x >= 0.f ? x : 0.2f*x; }
__device__ __forceinline__ float elu_f(float x){ return x > 0.f ? x : __expf(x) - 1.f; }

__device__ __forceinline__ unsigned short f2bf(float f){
  unsigned int u = __float_as_uint(f);
  u += 0x7FFFu + ((u >> 16) & 1u);
  return (unsigned short)(u >> 16);
}
__device__ __forceinline__ float bf2f(unsigned int us){
  return __uint_as_float(us << 16);
}
__device__ __forceinline__ float4 bf4_load(const unsigned short* p){
  uint2 q = *(const uint2*)p;
  return make_float4(bf2f(q.x & 0xffffu), bf2f(q.x >> 16),
                     bf2f(q.y & 0xffffu), bf2f(q.y >> 16));
}
__device__ __forceinline__ uint2 bf4_pack(float4 o){
  uint2 p;
  p.x = (unsigned)f2bf(o.x) | ((unsigned)f2bf(o.y) << 16);
  p.y = (unsigned)f2bf(o.z) | ((unsigned)f2bf(o.w) << 16);
  return p;
}
__device__ __forceinline__ void split_bf(float a, unsigned short& h, unsigned short& l){
  h = f2bf(a);
  l = f2bf(a - bf2f(h));
}

// v_dot2_f32_bf16: acc += a.bf16[0]*b.bf16[0] + a.bf16[1]*b.bf16[1]
__device__ __forceinline__ float dot2bf(float acc, unsigned a, unsigned b){
  asm("v_dot2_f32_bf16 %0, %1, %2, %0" : "+v"(acc) : "v"(a), "v"(b));
  return acc;
}

// ---------------- two-level bucket sort of edges by dst ----------------
__global__ __launch_bounds__(256) void ghist_kernel(const int* __restrict__ e0,
                                                    const int* __restrict__ e1,
                                                    int* __restrict__ ghist){
  const int ty = blockIdx.y;
  const int* e = ty ? e1 : e0;
  __shared__ int h[GB];
  for (int j=threadIdx.x; j<GB; j+=256) h[j]=0;
  __syncthreads();
  for (int i = blockIdx.x*256 + threadIdx.x; i < NE; i += 256*256)
    atomicAdd(&h[e[NE+i]>>8], 1);
  __syncthreads();
  for (int j=threadIdx.x; j<GB; j+=256) if (h[j]) atomicAdd(&ghist[ty*200+j], h[j]);
}

__global__ __launch_bounds__(256) void gscan_kernel(const int* __restrict__ ghist,
                                                    int* __restrict__ gbase,
                                                    int* __restrict__ gcur){
  __shared__ int wb[4];
  const int t = threadIdx.x, wv = t>>6, l = t&63;
  for (int ty=0; ty<2; ++ty){
    int v = (t < GB) ? ghist[ty*200+t] : 0;
    int sum = v;
    #pragma unroll
    for (int off=1; off<64; off<<=1){
      int x = __shfl_up(sum, off, 64);
      if (l >= off) sum += x;
    }
    if (l == 63) wb[wv] = sum;
    __syncthreads();
    int wbase = 0;
    #pragma unroll
    for (int w=0; w<4; ++w) if (w < wv) wbase += wb[w];
    int excl = wbase + sum - v;
    if (t <= GB) gbase[ty*200+t] = excl;
    if (t <  GB) gcur [ty*200+t] = excl;
    __syncthreads();
  }
}

// partition with LDS staging: global writes are contiguous per-bucket runs
__global__ __launch_bounds__(256) void part1_kernel(const int* __restrict__ e0,
                                                    const int* __restrict__ e1,
                                                    int* __restrict__ gcur,
                                                    int2* __restrict__ p0,
                                                    int2* __restrict__ p1){
  const int ty = blockIdx.y;
  const int* e = ty ? e1 : e0;
  int2* pairs = ty ? p1 : p0;
  __shared__ int cnt[256];
  __shared__ int lstart[256];
  __shared__ int lcur[256];
  __shared__ int curg[GB];
  __shared__ int lsrc[TILE1];
  __shared__ int ldst[TILE1];
  __shared__ int wb[4];
  const int t = threadIdx.x;
  cnt[t] = 0;
  __syncthreads();
  int dreg[16], sreg[16];
  const int base = blockIdx.x*TILE1;
  const int ntile = min(TILE1, NE - base);
  #pragma unroll
  for (int it=0; it<16; ++it){
    int i = base + it*256 + t;
    int d = -1, s = 0;
    if (i < NE){ d = e[NE+i]; s = e[i]; atomicAdd(&cnt[d>>8], 1); }
    dreg[it] = d; sreg[it] = s;
  }
  __syncthreads();
  int c = cnt[t], sum = c;
  #pragma unroll
  for (int off=1; off<64; off<<=1){
    int x = __shfl_up(sum, off, 64);
    if ((t&63) >= off) sum += x;
  }
  if ((t&63) == 63) wb[t>>6] = sum;
  __syncthreads();
  int wbase = 0;
  #pragma unroll
  for (int w=0; w<4; ++w) if (w < (t>>6)) wbase += wb[w];
  int excl = wbase + sum - c;
  lstart[t] = excl;
  lcur[t] = excl;
  if (t < GB && c > 0) curg[t] = atomicAdd(&gcur[ty*200+t], c);
  __syncthreads();
  #pragma unroll
  for (int it=0; it<16; ++it){
    int d = dreg[it];
    if (d >= 0){
      int pos = atomicAdd(&lcur[d>>8], 1);
      lsrc[pos] = sreg[it];
      ldst[pos] = d;
    }
  }
  __syncthreads();
  for (int i=t; i<ntile; i+=256){
    int d = ldst[i];
    int j = d>>8;
    pairs[curg[j] + (i - lstart[j])] = make_int2(lsrc[i], d);
  }
}

// per-bucket LDS bin by dst + CSR offsets + fused layer-0 softmax weights (bf16).
struct Part2Job {
  const int2* pairs; const int* gbase;
  const float* als; const float* ald;   // [NN,4]
  int* ssrc; int* offs; unsigned short* coef;  // coef: [E,4] bf16
};
__global__ __launch_bounds__(256) void part2_kernel(Part2Job j0, Part2Job j1){
  const Part2Job jb = blockIdx.y ? j1 : j0;
  const int b = blockIdx.x;
  const int t = threadIdx.x;
  __shared__ int lcnt[256];
  __shared__ int lcur[256];
  __shared__ int wb[4];
  __shared__ int sorted_src[CAP];
  __shared__ unsigned char sorted_dl[CAP];
  const int gb0 = jb.gbase[b], gb1 = jb.gbase[b+1];
  const int n = gb1 - gb0;
  lcnt[t] = 0;
  __syncthreads();
  for (int i=t; i<n; i+=256)
    atomicAdd(&lcnt[jb.pairs[gb0+i].y - (b<<8)], 1);
  __syncthreads();
  int c = lcnt[t], sum = c;
  #pragma unroll
  for (int off=1; off<64; off<<=1){
    int x = __shfl_up(sum, off, 64);
    if ((t&63) >= off) sum += x;
  }
  if ((t&63) == 63) wb[t>>6] = sum;
  __syncthreads();
  int wbase = 0;
  #pragma unroll
  for (int w=0; w<4; ++w) if (w < (t>>6)) wbase += wb[w];
  int excl = wbase + sum - c;
  lcur[t] = excl;
  int g = (b<<8) + t;
  if (g <= NN) jb.offs[g] = gb0 + excl;
  __syncthreads();
  for (int i=t; i<n; i+=256){
    int2 pr = jb.pairs[gb0+i];
    int dl = pr.y - (b<<8);
    int pos = atomicAdd(&lcur[dl], 1);
    sorted_src[pos] = pr.x;
    sorted_dl[pos] = (unsigned char)dl;
  }
  __syncthreads();
  const float4* als4 = (const float4*)jb.als;
  const float4* ald4 = (const float4*)jb.ald;
  for (int i=t; i<n; i+=256){
    int s  = sorted_src[i];
    int dl = sorted_dl[i];
    float4 a  = als4[s];
    float4 ad = ald4[(b<<8)+dl];
    // no max-shift: |alpha| small at this model scale; softmax shift-invariant.
    float4 w;
    w.x = __expf(lrelu_f(a.x+ad.x));
    w.y = __expf(lrelu_f(a.y+ad.y));
    w.z = __expf(lrelu_f(a.z+ad.z));
    w.w = __expf(lrelu_f(a.w+ad.w));
    ((uint2*)jb.coef)[gb0+i] = bf4_pack(w);
    jb.ssrc[gb0+i] = s;
  }
}

// ---------------- MFMA GEMM: C = act(A[M,K] @ W[K,N] (+bias)) ----------------
// LG: logit-fused variant — GEMM N=48; cols 0..31 -> bf16 C (stride 32),
// col 32 -> fp32 outA[m], col 33 -> fp32 outB[m].
// LOGIT: proj variant (N=64) — additionally computes per-row dual logit dot
// products against cwS/cwD (layout [4][64]) -> outA[m*4+h], outB[m*4+h].
struct MgJob {
  const void* A; const float* W; const float* bias;
  void* C; float* outA; float* outB;
  const float* cwS; const float* cwD;
};
template<int NT, bool ELU, bool BF16OUT, bool BF16A, bool LG, bool LOGIT>
__global__ __launch_bounds__(256) void mgemm_kernel(MgJob j0, MgJob j1,
                                                    int M, int K, int N)
{
  const MgJob jb = blockIdx.z ? j1 : j0;
  constexpr int TN = NT*16;
  __shared__ __align__(16) unsigned short Ah[64*72];
  __shared__ __align__(16) unsigned short Al[BF16A ? 8 : 64*72];
  __shared__ __align__(16) unsigned short Bh[TN*72];
  __shared__ __align__(16) unsigned short Bl[TN*72];
  __shared__ float CwS[LOGIT ? 256 : 1];
  __shared__ float CwD[LOGIT ? 256 : 1];
  const int t = threadIdx.x;
  const int m0 = blockIdx.x*64;
  const int n0 = blockIdx.y*TN;
  const int wv = t>>6, l = t&63;
  const int lr = l&15, lq = l>>4;
  if constexpr (LOGIT){ CwS[t] = jb.cwS[t]; CwD[t] = jb.cwD[t]; }
  floatx4 acc[NT];
  #pragma unroll
  for (int i=0;i<NT;i++) acc[i] = (floatx4){0.f,0.f,0.f,0.f};

  for (int kt=0; kt<K; kt+=64){
    if constexpr (BF16A){
      const unsigned short* A = (const unsigned short*)jb.A;
      #pragma unroll
      for (int i=0;i<2;i++){
        int li = t + i*256;
        int r = li >> 3, c8 = (li & 7)*8;
        short8 v = {0,0,0,0,0,0,0,0};
        if (m0 + r < M) v = *(const short8*)(A + (size_t)(m0+r)*K + kt + c8);
        *(short8*)&Ah[r*72 + c8] = v;
      }
    } else {
      const float* A = (const float*)jb.A;
      #pragma unroll
      for (int i=0;i<4;i++){
        int li = t + i*256;
        int r = li >> 4, c4 = (li & 15)*4;
        float4 v = make_float4(0.f,0.f,0.f,0.f);
        if (m0 + r < M) v = *(const float4*)(A + (size_t)(m0+r)*K + kt + c4);
        unsigned short h0,h1,h2,h3,g0,g1,g2,g3;
        split_bf(v.x,h0,g0); split_bf(v.y,h1,g1);
        split_bf(v.z,h2,g2); split_bf(v.w,h3,g3);
        uint2 ph = { (unsigned)h0 | ((unsigned)h1<<16), (unsigned)h2 | ((unsigned)h3<<16) };
        uint2 pl = { (unsigned)g0 | ((unsigned)g1<<16), (unsigned)g2 | ((unsigned)g3<<16) };
        *(uint2*)&Ah[r*72 + c4] = ph;
        *(uint2*)&Al[r*72 + c4] = pl;
      }
    }
    #pragma unroll
    for (int i=0;i<NT;i++){
      int li = t + i*256;
      int k  = li / (TN/4);
      int n4 = (li % (TN/4))*4;
      float4 v = *(const float4*)(jb.W + (size_t)(kt+k)*N + n0 + n4);
      unsigned short h, g;
      split_bf(v.x,h,g); Bh[(n4+0)*72+k]=h; Bl[(n4+0)*72+k]=g;
      split_bf(v.y,h,g); Bh[(n4+1)*72+k]=h; Bl[(n4+1)*72+k]=g;
      split_bf(v.z,h,g); Bh[(n4+2)*72+k]=h; Bl[(n4+2)*72+k]=g;
      split_bf(v.w,h,g); Bh[(n4+3)*72+k]=h; Bl[(n4+3)*72+k]=g;
    }
    __syncthreads();
    #pragma unroll
    for (int ks=0; ks<2; ks++){
      const int koff = ks*32 + lq*8;
      short8 a_h = *(const short8*)&Ah[(wv*16+lr)*72 + koff];
      short8 a_l;
      if constexpr (!BF16A) a_l = *(const short8*)&Al[(wv*16+lr)*72 + koff];
      #pragma unroll
      for (int nt=0; nt<NT; nt++){
        short8 b_h = *(const short8*)&Bh[(nt*16+lr)*72 + koff];
        short8 b_l = *(const short8*)&Bl[(nt*16+lr)*72 + koff];
        acc[nt] = __builtin_amdgcn_mfma_f32_16x16x32_bf16(a_h, b_h, acc[nt], 0,0,0);
        acc[nt] = __builtin_amdgcn_mfma_f32_16x16x32_bf16(a_h, b_l, acc[nt], 0,0,0);
        if constexpr (!BF16A)
          acc[nt] = __builtin_amdgcn_mfma_f32_16x16x32_bf16(a_l, b_h, acc[nt], 0,0,0);
      }
    }
    __syncthreads();
  }
  float ls[LOGIT ? 4 : 1][LOGIT ? 4 : 1];   // [r][h]
  float ld_[LOGIT ? 4 : 1][LOGIT ? 4 : 1];
  if constexpr (LOGIT){
    #pragma unroll
    for (int r=0;r<4;r++)
      #pragma unroll
      for (int h=0;h<4;h++){ ls[r][h]=0.f; ld_[r][h]=0.f; }
  }
  #pragma unroll
  for (int nt=0; nt<NT; nt++){
    int n = n0 + nt*16 + lr;
    float bv = jb.bias ? jb.bias[n] : 0.f;
    #pragma unroll
    for (int r=0;r<4;r++){
      int m = m0 + wv*16 + lq*4 + r;
      if (m < M){
        float o = acc[nt][r] + bv;
        if (ELU) o = elu_f(o);
        if constexpr (LG){
          if (n < 32)       ((unsigned short*)jb.C)[(size_t)m*32 + n] = f2bf(o);
          else if (n == 32) jb.outA[m] = o;
          else if (n == 33) jb.outB[m] = o;
        } else {
          if (BF16OUT) ((unsigned short*)jb.C)[(size_t)m*N + n] = f2bf(o);
          else         ((float*)jb.C)[(size_t)m*N + n] = o;
        }
        if constexpr (LOGIT){
          #pragma unroll
          for (int h=0;h<4;h++){
            ls[r][h]  = fmaf(o, CwS[h*64 + n], ls[r][h]);
            ld_[r][h] = fmaf(o, CwD[h*64 + n], ld_[r][h]);
          }
        }
      }
    }
  }
  if constexpr (LOGIT){
    // reduce over the 16 lr-lanes (channels), then lane lr==0 writes 4 rows x 4 heads
    #pragma unroll
    for (int r=0;r<4;r++)
      #pragma unroll
      for (int h=0;h<4;h++){
        float a = ls[r][h], d = ld_[r][h];
        #pragma unroll
        for (int off=1; off<16; off<<=1){
          a += __shfl_xor(a, off, 64);
          d += __shfl_xor(d, off, 64);
        }
        ls[r][h]=a; ld_[r][h]=d;
      }
    if (lr == 0){
      #pragma unroll
      for (int r=0;r<4;r++){
        int m = m0 + wv*16 + lq*4 + r;
        if (m < M){
          #pragma unroll
          for (int h=0;h<4;h++){
            jb.outA[(size_t)m*4 + h] = ls[r][h];
            jb.outB[(size_t)m*4 + h] = ld_[r][h];
          }
        }
      }
    }
  }
}

// ---------------- per-head block GEMM: hi1[m, h*64+n] = elu((agg_h @ Ws_h)/den + b) ----
struct HgJob {
  const unsigned short* A; const float* W; const float* den;  // den [M,4]
  const float* bias; unsigned short* out;                      // out bf16 [M,256]
};
__global__ __launch_bounds__(256) void hgemm_kernel(HgJob j0, HgJob j1){
  const HgJob jb = blockIdx.z ? j1 : j0;
  const int head = blockIdx.y;
  const int m0 = blockIdx.x*64;
  __shared__ __align__(16) unsigned short Ah[64*72];
  __shared__ __align__(16) unsigned short Bh[64*72];
  __shared__ __align__(16) unsigned short Bl[64*72];
  const int t = threadIdx.x;
  const int wv = t>>6, l = t&63;
  const int lr = l&15, lq = l>>4;
  floatx4 acc[4];
  #pragma unroll
  for (int i=0;i<4;i++) acc[i] = (floatx4){0.f,0.f,0.f,0.f};
  #pragma unroll
  for (int i=0;i<2;i++){
    int li = t + i*256;
    int r = li >> 3, c8 = (li & 7)*8;
    short8 v = {0,0,0,0,0,0,0,0};
    if (m0 + r < NN) v = *(const short8*)(jb.A + (size_t)(m0+r)*256 + head*64 + c8);
    *(short8*)&Ah[r*72 + c8] = v;
  }
  #pragma unroll
  for (int i=0;i<4;i++){
    int li = t + i*256;
    int k  = li >> 4;
    int n4 = (li & 15)*4;
    float4 v = *(const float4*)(jb.W + (size_t)k*256 + head*64 + n4);
    unsigned short h, g;
    split_bf(v.x,h,g); Bh[(n4+0)*72+k]=h; Bl[(n4+0)*72+k]=g;
    split_bf(v.y,h,g); Bh[(n4+1)*72+k]=h; Bl[(n4+1)*72+k]=g;
    split_bf(v.z,h,g); Bh[(n4+2)*72+k]=h; Bl[(n4+2)*72+k]=g;
    split_bf(v.w,h,g); Bh[(n4+3)*72+k]=h; Bl[(n4+3)*72+k]=g;
  }
  __syncthreads();
  #pragma unroll
  for (int ks=0; ks<2; ks++){
    const int koff = ks*32 + lq*8;
    short8 a_h = *(const short8*)&Ah[(wv*16+lr)*72 + koff];
    #pragma unroll
    for (int nt=0; nt<4; nt++){
      short8 b_h = *(const short8*)&Bh[(nt*16+lr)*72 + koff];
      short8 b_l = *(const short8*)&Bl[(nt*16+lr)*72 + koff];
      acc[nt] = __builtin_amdgcn_mfma_f32_16x16x32_bf16(a_h, b_h, acc[nt], 0,0,0);
      acc[nt] = __builtin_amdgcn_mfma_f32_16x16x32_bf16(a_h, b_l, acc[nt], 0,0,0);
    }
  }
  float inv[4];
  #pragma unroll
  for (int r=0;r<4;r++){
    int m = m0 + wv*16 + lq*4 + r;
    inv[r] = (m < NN) ? 1.f/(jb.den[(size_t)m*4 + head] + 1e-16f) : 0.f;
  }
  #pragma unroll
  for (int nt=0; nt<4; nt++){
    int col = head*64 + nt*16 + lr;
    float bv = jb.bias[col];
    #pragma unroll
    for (int r=0;r<4;r++){
      int m = m0 + wv*16 + lq*4 + r;
      if (m < NN)
        jb.out[(size_t)m*256 + col] = f2bf(elu_f(acc[nt][r]*inv[r] + bv));
    }
  }
}

// ---------------- collapse attention vectors ----------------
struct CollapseJob { const float* W; const float* a; float* out; int K,H,C; };
struct CollapseArgs { CollapseJob j[8]; };
__global__ void collapse_kernel(CollapseArgs args){
  CollapseJob jb = args.j[blockIdx.x];
  int t = threadIdx.x;
  if (t < jb.K * jb.H){
    int k = t / jb.H, h = t % jb.H;
    const float* wr = jb.W + (size_t)k * (jb.H*jb.C) + h*jb.C;
    const float* ar = jb.a + h*jb.C;
    float s = 0.f;
    for (int c=0;c<jb.C;c++) s += wr[c]*ar[c];
    jb.out[h*jb.K + k] = s;   // layout [H,K]
  }
}

// build combined layer-1 weight [256 x 48]: cols 0..31 Ws, 32 cwS, 33 cwD, rest 0
__global__ __launch_bounds__(256) void prep1_kernel(
    const float* __restrict__ WsA, const float* __restrict__ cwSA, const float* __restrict__ cwDA,
    const float* __restrict__ WsB, const float* __restrict__ cwSB, const float* __restrict__ cwDB,
    float* __restrict__ WcA, float* __restrict__ WcB){
  const float* Ws  = blockIdx.x ? WsB  : WsA;
  const float* cwS = blockIdx.x ? cwSB : cwSA;
  const float* cwD = blockIdx.x ? cwDB : cwDA;
  float* Wc = blockIdx.x ? WcB : WcA;
  const int k = threadIdx.x;   // 256 rows
  #pragma unroll
  for (int n=0;n<32;n++) Wc[(size_t)k*48 + n] = Ws[(size_t)k*32 + n];
  Wc[(size_t)k*48 + 32] = cwS[k];
  Wc[(size_t)k*48 + 33] = cwD[k];
  #pragma unroll
  for (int n=34;n<48;n++) Wc[(size_t)k*48 + n] = 0.f;
}

// ---------------- layer-0 pre-aggregation over hu/hi rows ----------------
// 8 dsts per wave, 8 lanes per dst, 8 channels per lane: edge-sum is fully
// within-lane => no cross-lane reduction epilogue (the old 16->1 shuffle
// reduce over 20 accumulators was ~half the kernel's instructions).
struct AggPJob {
  const int* offs; const int* ssrc;
  const unsigned short* x;     // bf16 [NN,64]
  const unsigned short* coef;  // bf16 [E,4]
  unsigned short* agg;         // bf16 [NN,256]
  float* den;                  // fp32 [NN,4]
};
__global__ __launch_bounds__(256) void aggpre_kernel(AggPJob ja, AggPJob jbb){
  const AggPJob jb = blockIdx.y ? jbb : ja;
  const int tid = threadIdx.x;
  const int lane = tid & 63, wid = tid >> 6;
  const int grp = lane >> 3;       // dst group within wave (0..7)
  const int cl  = lane & 7;        // channel lane within group
  const int c8  = cl * 8;          // channel base (8 bf16 = 16B per lane)
  const int dst = blockIdx.x*32 + wid*8 + grp;
  if (dst >= NN) return;
  const int b0 = jb.offs[dst], b1 = jb.offs[dst+1];
  float acc[4][8];
  float den[4] = {0.f,0.f,0.f,0.f};
  #pragma unroll
  for (int h=0;h<4;h++)
    #pragma unroll
    for (int c=0;c<8;c++) acc[h][c]=0.f;
  const unsigned ONE2 = 0x3F803F80u;  // packed bf16 (1.0, 1.0)
  int e = b0;
  // edge-paired dot2: operands stay bf16, sums within-lane only
  for (; e+1 < b1; e += 2){
    int s0 = jb.ssrc[e];
    int s1 = jb.ssrc[e+1];
    uint4 q0 = *(const uint4*)(jb.x + ((size_t)s0<<6) + c8);
    uint4 q1 = *(const uint4*)(jb.x + ((size_t)s1<<6) + c8);
    uint2 w0 = *(const uint2*)(jb.coef + (size_t)e*4);
    uint2 w1 = *(const uint2*)(jb.coef + (size_t)(e+1)*4);
    // (a,b,sel): a supplies bytes 4-7, b supplies bytes 0-3
    unsigned wp[4];
    wp[0] = __builtin_amdgcn_perm(w1.x, w0.x, 0x05040100u);
    wp[1] = __builtin_amdgcn_perm(w1.x, w0.x, 0x07060302u);
    wp[2] = __builtin_amdgcn_perm(w1.y, w0.y, 0x05040100u);
    wp[3] = __builtin_amdgcn_perm(w1.y, w0.y, 0x07060302u);
    unsigned xp[8];
    xp[0] = __builtin_amdgcn_perm(q1.x, q0.x, 0x05040100u);
    xp[1] = __builtin_amdgcn_perm(q1.x, q0.x, 0x07060302u);
    xp[2] = __builtin_amdgcn_perm(q1.y, q0.y, 0x05040100u);
    xp[3] = __builtin_amdgcn_perm(q1.y, q0.y, 0x07060302u);
    xp[4] = __builtin_amdgcn_perm(q1.z, q0.z, 0x05040100u);
    xp[5] = __builtin_amdgcn_perm(q1.z, q0.z, 0x07060302u);
    xp[6] = __builtin_amdgcn_perm(q1.w, q0.w, 0x05040100u);
    xp[7] = __builtin_amdgcn_perm(q1.w, q0.w, 0x07060302u);
    #pragma unroll
    for (int h=0;h<4;h++){
      den[h] = dot2bf(den[h], wp[h], ONE2);
      #pragma unroll
      for (int c=0;c<8;c++) acc[h][c] = dot2bf(acc[h][c], wp[h], xp[c]);
    }
  }
  if (e < b1){  // odd-degree tail: single edge, scalar path
    int s = jb.ssrc[e];
    uint4 q = *(const uint4*)(jb.x + ((size_t)s<<6) + c8);
    uint2 w = *(const uint2*)(jb.coef + (size_t)e*4);
    float wf[4] = { bf2f(w.x & 0xffffu), bf2f(w.x >> 16),
                    bf2f(w.y & 0xffffu), bf2f(w.y >> 16) };
    float xf[8] = { bf2f(q.x & 0xffffu), bf2f(q.x >> 16),
                    bf2f(q.y & 0xffffu), bf2f(q.y >> 16),
                    bf2f(q.z & 0xffffu), bf2f(q.z >> 16),
                    bf2f(q.w & 0xffffu), bf2f(q.w >> 16) };
    #pragma unroll
    for (int h=0;h<4;h++){
      den[h] += wf[h];
      #pragma unroll
      for (int c=0;c<8;c++) acc[h][c] += wf[h]*xf[c];
    }
  }
  // epilogue: pack + store only (no shuffles)
  #pragma unroll
  for (int h=0;h<4;h++){
    uint2 plo = bf4_pack(make_float4(acc[h][0],acc[h][1],acc[h][2],acc[h][3]));
    uint2 phi = bf4_pack(make_float4(acc[h][4],acc[h][5],acc[h][6],acc[h][7]));
    uint4 pk = { plo.x, plo.y, phi.x, phi.y };
    *(uint4*)(jb.agg + (size_t)dst*256 + h*64 + c8) = pk;
  }
  if (cl == 0)
    *(float4*)(jb.den + (size_t)dst*4) = make_float4(den[0],den[1],den[2],den[3]);
}

// ---------------- layer-1 aggregation (softmax weight fused inline) ----------------
struct Agg1Job {
  const int* offs; const int* ssrc;
  const unsigned short* hs;   // bf16 [NN,32]
  const float* als; const float* ald;  // layer-1 logits
  const float* bias; float* out;
};
__global__ __launch_bounds__(256) void agg1_kernel(Agg1Job ja, Agg1Job jbb){
  const Agg1Job jb = blockIdx.y ? jbb : ja;
  const int wid = threadIdx.x>>6, lane = threadIdx.x&63;
  const int dst = blockIdx.x*4 + wid;
  if (dst >= NN) return;
  const int b0 = jb.offs[dst], b1 = jb.offs[dst+1];
  const float ad = jb.ald[dst];
  const int slot = lane>>3, c4 = (lane&7)*4;
  float4 acc = make_float4(0.f,0.f,0.f,0.f);
  float den = 0.f;
  int e = b0 + slot;
  for (; e+8 < b1; e += 16){
    int s0 = jb.ssrc[e], s1 = jb.ssrc[e+8];
    float a0 = jb.als[s0];
    float a1 = jb.als[s1];
    float4 v0 = bf4_load(jb.hs + ((size_t)s0<<5) + c4);
    float4 v1 = bf4_load(jb.hs + ((size_t)s1<<5) + c4);
    float w0 = __expf(lrelu_f(a0 + ad));
    float w1 = __expf(lrelu_f(a1 + ad));
    acc.x += w0*v0.x + w1*v1.x;
    acc.y += w0*v0.y + w1*v1.y;
    acc.z += w0*v0.z + w1*v1.z;
    acc.w += w0*v0.w + w1*v1.w;
    den += w0 + w1;
  }
  if (e < b1){
    int s = jb.ssrc[e];
    float w = __expf(lrelu_f(jb.als[s] + ad));
    float4 v = bf4_load(jb.hs + ((size_t)s<<5) + c4);
    acc.x += w*v.x; acc.y += w*v.y; acc.z += w*v.z; acc.w += w*v.w;
    den += w;
  }
  #pragma unroll
  for (int off=32; off>=8; off>>=1){
    acc.x += __shfl_xor(acc.x, off, 64);
    acc.y += __shfl_xor(acc.y, off, 64);
    acc.z += __shfl_xor(acc.z, off, 64);
    acc.w += __shfl_xor(acc.w, off, 64);
    den   += __shfl_xor(den,   off, 64);
  }
  if (lane < 8){
    const float inv = 1.f/(den + 1e-16f);
    float4 b = *(const float4*)(jb.bias + c4);
    float4 o = make_float4(acc.x*inv+b.x, acc.y*inv+b.y, acc.z*inv+b.z, acc.w*inv+b.w);
    *(float4*)(jb.out + (size_t)dst*32 + c4) = o;
  }
}

// ---------------- host glue ----------------
extern "C" void kernel_launch(void* const* d_in, const int* in_sizes, int n_in,
                              void* d_out, int out_size, void* d_ws, size_t ws_size,
                              hipStream_t stream)
{
  (void)in_sizes; (void)n_in; (void)out_size; (void)ws_size;
  const float* x_user   = (const float*)d_in[0];
  const float* x_item   = (const float*)d_in[1];
  const int*   e_u2i    = (const int*)  d_in[2];
  const int*   e_i2u    = (const int*)  d_in[3];
  const float* p_user_w = (const float*)d_in[4];
  const float* p_user_b = (const float*)d_in[5];
  const float* p_item_w = (const float*)d_in[6];
  const float* p_item_b = (const float*)d_in[7];
  const float* l0_u2i_ws=(const float*)d_in[8];
  const float* l0_u2i_wd=(const float*)d_in[9];
  const float* l0_u2i_as=(const float*)d_in[10];
  const float* l0_u2i_ad=(const float*)d_in[11];
  const float* l0_u2i_b =(const float*)d_in[12];
  const float* l0_i2u_ws=(const float*)d_in[13];
  const float* l0_i2u_wd=(const float*)d_in[14];
  const float* l0_i2u_as=(const float*)d_in[15];
  const float* l0_i2u_ad=(const float*)d_in[16];
  const float* l0_i2u_b =(const float*)d_in[17];
  const float* l1_u2i_ws=(const float*)d_in[18];
  const float* l1_u2i_wd=(const float*)d_in[19];
  const float* l1_u2i_as=(const float*)d_in[20];
  const float* l1_u2i_ad=(const float*)d_in[21];
  const float* l1_u2i_b =(const float*)d_in[22];
  const float* l1_i2u_ws=(const float*)d_in[23];
  const float* l1_i2u_wd=(const float*)d_in[24];
  const float* l1_i2u_as=(const float*)d_in[25];
  const float* l1_i2u_ad=(const float*)d_in[26];
  const float* l1_i2u_b =(const float*)d_in[27];

  char* base = (char*)d_ws;
  size_t off = 0;
  auto alloc = [&](size_t bytes)->void*{
    void* p = base + off;
    off += (bytes + 255) & ~(size_t)255;
    return p;
  };
  int* offs_u2i = (int*)alloc((size_t)(NN+1)*sizeof(int));
  int* offs_i2u = (int*)alloc((size_t)(NN+1)*sizeof(int));
  int* ssrc_u2i = (int*)alloc((size_t)NE*sizeof(int));
  int* ssrc_i2u = (int*)alloc((size_t)NE*sizeof(int));
  int* ghist    = (int*)alloc((size_t)2*200*sizeof(int));
  int* gbase    = (int*)alloc((size_t)2*200*sizeof(int));
  int* gcur     = (int*)alloc((size_t)2*200*sizeof(int));
  unsigned short* coef0_u2i = (unsigned short*)alloc((size_t)NE*4*sizeof(unsigned short));
  unsigned short* coef0_i2u = (unsigned short*)alloc((size_t)NE*4*sizeof(unsigned short));
  unsigned short* hu = (unsigned short*)alloc((size_t)NN*64*sizeof(unsigned short));
  unsigned short* hi = (unsigned short*)alloc((size_t)NN*64*sizeof(unsigned short));
  unsigned short* agg_u2i = (unsigned short*)alloc((size_t)NN*256*sizeof(unsigned short));
  unsigned short* agg_i2u = (unsigned short*)alloc((size_t)NN*256*sizeof(unsigned short));
  float* den_u2i = (float*)alloc((size_t)NN*4*sizeof(float));
  float* den_i2u = (float*)alloc((size_t)NN*4*sizeof(float));
  unsigned short* hu1 = (unsigned short*)alloc((size_t)NN*256*sizeof(unsigned short));
  unsigned short* hi1 = (unsigned short*)alloc((size_t)NN*256*sizeof(unsigned short));
  unsigned short* hs1_u2i = (unsigned short*)alloc((size_t)NN*32*sizeof(unsigned short));
  unsigned short* hs1_i2u = (unsigned short*)alloc((size_t)NN*32*sizeof(unsigned short));
  float* als0_u2i = (float*)alloc((size_t)NN*4*sizeof(float));
  float* ald0_u2i = (float*)alloc((size_t)NN*4*sizeof(float));
  float* als0_i2u = (float*)alloc((size_t)NN*4*sizeof(float));
  float* ald0_i2u = (float*)alloc((size_t)NN*4*sizeof(float));
  float* als1_u2i = (float*)alloc((size_t)NN*sizeof(float));
  float* ald1_u2i = (float*)alloc((size_t)NN*sizeof(float));
  float* als1_i2u = (float*)alloc((size_t)NN*sizeof(float));
  float* ald1_i2u = (float*)alloc((size_t)NN*sizeof(float));
  float* cw0s_u2i = (float*)alloc(256*sizeof(float));
  float* cw0d_u2i = (float*)alloc(256*sizeof(float));
  float* cw0s_i2u = (float*)alloc(256*sizeof(float));
  float* cw0d_i2u = (float*)alloc(256*sizeof(float));
  float* cw1s_u2i = (float*)alloc(256*sizeof(float));
  float* cw1d_u2i = (float*)alloc(256*sizeof(float));
  float* cw1s_i2u = (float*)alloc(256*sizeof(float));
  float* cw1d_i2u = (float*)alloc(256*sizeof(float));
  float* Wc_u2i   = (float*)alloc((size_t)256*48*sizeof(float));
  float* Wc_i2u   = (float*)alloc((size_t)256*48*sizeof(float));
  // pairs scratch aliases hu1/hi1: consumed by part2 before hgemm writes them
  int2* pairs_u2i = (int2*)hu1;
  int2* pairs_i2u = pairs_u2i + NE;

  const int GM = (NN + 63)/64;

  // ---- bucket sort stage A ----
  hipMemsetAsync(ghist, 0, (size_t)2*200*sizeof(int), stream);
  ghist_kernel<<<dim3(256,2), 256, 0, stream>>>(e_u2i, e_i2u, ghist);
  gscan_kernel<<<1, 256, 0, stream>>>(ghist, gbase, gcur);
  part1_kernel<<<dim3((NE+TILE1-1)/TILE1,2), 256, 0, stream>>>(
      e_u2i, e_i2u, gcur, pairs_u2i, pairs_i2u);

  // ---- collapse attention vectors (needed by proj's fused logits) ----
  CollapseArgs ca;
  ca.j[0] = {l0_u2i_ws, l0_u2i_as, cw0s_u2i, 64, 4, 64};
  ca.j[1] = {l0_u2i_wd, l0_u2i_ad, cw0d_u2i, 64, 4, 64};
  ca.j[2] = {l0_i2u_ws, l0_i2u_as, cw0s_i2u, 64, 4, 64};
  ca.j[3] = {l0_i2u_wd, l0_i2u_ad, cw0d_i2u, 64, 4, 64};
  ca.j[4] = {l1_u2i_ws, l1_u2i_as, cw1s_u2i, 256, 1, 32};
  ca.j[5] = {l1_u2i_wd, l1_u2i_ad, cw1d_u2i, 256, 1, 32};
  ca.j[6] = {l1_i2u_ws, l1_i2u_as, cw1s_i2u, 256, 1, 32};
  ca.j[7] = {l1_i2u_wd, l1_i2u_ad, cw1d_i2u, 256, 1, 32};
  collapse_kernel<<<8, 256, 0, stream>>>(ca);

  // ---- input projections (+bias +ELU) -> bf16, with fused layer-0 logits ----
  // hu row -> als0_u2i (S-side of u2i) and ald0_i2u (D-side of i2u); vice versa.
  mgemm_kernel<4,true,true,false,false,true><<<dim3(GM,1,2), 256, 0, stream>>>(
      MgJob{x_user, p_user_w, p_user_b, hu, als0_u2i, ald0_i2u, cw0s_u2i, cw0d_i2u},
      MgJob{x_item, p_item_w, p_item_b, hi, als0_i2u, ald0_u2i, cw0s_i2u, cw0d_u2i},
      NN, 128, 64);

  // ---- combined layer-1 weights (Ws | cwS | cwD) ----
  prep1_kernel<<<2, 256, 0, stream>>>(
      l1_u2i_ws, cw1s_u2i, cw1d_i2u,
      l1_i2u_ws, cw1s_i2u, cw1d_u2i,
      Wc_u2i, Wc_i2u);

  // ---- bucket sort stage B ----
  part2_kernel<<<dim3(GB,2), 256, 0, stream>>>(
      Part2Job{pairs_u2i, gbase,       als0_u2i, ald0_u2i, ssrc_u2i, offs_u2i, coef0_u2i},
      Part2Job{pairs_i2u, gbase + 200, als0_i2u, ald0_i2u, ssrc_i2u, offs_i2u, coef0_i2u});

  // ---- layer 0: pre-aggregate hu/hi rows (8 dst/wave, shuffle-free) ----
  aggpre_kernel<<<dim3((NN+31)/32,2), 256, 0, stream>>>(
      AggPJob{offs_u2i, ssrc_u2i, hu, coef0_u2i, agg_u2i, den_u2i},
      AggPJob{offs_i2u, ssrc_i2u, hi, coef0_i2u, agg_i2u, den_i2u});

  // ---- layer 0: per-head GEMM + den-divide + bias + ELU -> hi1/hu1 bf16 ----
  hgemm_kernel<<<dim3(GM,4,2), 256, 0, stream>>>(
      HgJob{agg_u2i, l0_u2i_ws, den_u2i, l0_u2i_b, hi1},
      HgJob{agg_i2u, l0_i2u_ws, den_i2u, l0_i2u_b, hu1});

  // ---- layer 1: feature GEMMs with fused logit columns (merged dual launch) ----
  // hu1 @ Wc_u2i -> hs1_u2i (cols 0..31), als1_u2i (col 32), ald1_i2u (col 33)
  mgemm_kernel<3,false,true,true,true,false><<<dim3(GM,1,2), 256, 0, stream>>>(
      MgJob{hu1, Wc_u2i, nullptr, hs1_u2i, als1_u2i, ald1_i2u, nullptr, nullptr},
      MgJob{hi1, Wc_i2u, nullptr, hs1_i2u, als1_i2u, ald1_u2i, nullptr, nullptr},
      NN, 256, 48);

  // ---- layer 1: aggregate (+bias), softmax weights computed inline ----
  float* hu2 = (float*)d_out;                  // first tuple element (users, i2u dst)
  float* hi2 = (float*)d_out + (size_t)NN*32;  // second tuple element (items, u2i dst)
  agg1_kernel<<<dim3(NN/4,2), 256, 0, stream>>>(
      Agg1Job{offs_u2i, ssrc_u2i, hs1_u2i, als1_u2i, ald1_u2i, l1_u2i_b, hi2},
      Agg1Job{offs_i2u, ssrc_i2u, hs1_i2u, als1_i2u, ald1_i2u, l1_i2u_b, hu2});
}

// Round 6
// 379.594 us; speedup vs baseline: 1.2829x; 1.0499x over previous
//
#include <hip/hip_runtime.h>
#include <cstdint>
#include <cstddef>

#define NN 50000
#define NE 800000
#define GB 196        // coarse buckets = ceil(NN/256)
#define TILE1 4096    // edges per part1 block
#define CAP 8192      // max edges per bucket in part2 LDS (mean 4082)

typedef __attribute__((ext_vector_type(8))) short short8;
typedef __attribute__((ext_vector_type(4))) float floatx4;

__device__ __forceinline__ float lrelu_f(float x){ return x >= 0.f ? x : 0.2f*x; }
__device__ __forceinline__ float elu_f(float x){ return x > 0.f ? x : __expf(x) - 1.f; }

__device__ __forceinline__ unsigned short f2bf(float f){
  unsigned int u = __float_as_uint(f);
  u += 0x7FFFu + ((u >> 16) & 1u);
  return (unsigned short)(u >> 16);
}
__device__ __forceinline__ float bf2f(unsigned int us){
  return __uint_as_float(us << 16);
}
__device__ __forceinline__ float4 bf4_load(const unsigned short* p){
  uint2 q = *(const uint2*)p;
  return make_float4(bf2f(q.x & 0xffffu), bf2f(q.x >> 16),
                     bf2f(q.y & 0xffffu), bf2f(q.y >> 16));
}
__device__ __forceinline__ uint2 bf4_pack(float4 o){
  uint2 p;
  p.x = (unsigned)f2bf(o.x) | ((unsigned)f2bf(o.y) << 16);
  p.y = (unsigned)f2bf(o.z) | ((unsigned)f2bf(o.w) << 16);
  return p;
}
__device__ __forceinline__ void split_bf(float a, unsigned short& h, unsigned short& l){
  h = f2bf(a);
  l = f2bf(a - bf2f(h));
}

// v_dot2_f32_bf16: acc += a.bf16[0]*b.bf16[0] + a.bf16[1]*b.bf16[1]
__device__ __forceinline__ float dot2bf(float acc, unsigned a, unsigned b){
  asm("v_dot2_f32_bf16 %0, %1, %2, %0" : "+v"(acc) : "v"(a), "v"(b));
  return acc;
}

// ---------------- two-level bucket sort of edges by dst ----------------
__global__ __launch_bounds__(256) void ghist_kernel(const int* __restrict__ e0,
                                                    const int* __restrict__ e1,
                                                    int* __restrict__ ghist){
  const int ty = blockIdx.y;
  const int* e = ty ? e1 : e0;
  __shared__ int h[GB];
  for (int j=threadIdx.x; j<GB; j+=256) h[j]=0;
  __syncthreads();
  for (int i = blockIdx.x*256 + threadIdx.x; i < NE; i += 256*256)
    atomicAdd(&h[e[NE+i]>>8], 1);
  __syncthreads();
  for (int j=threadIdx.x; j<GB; j+=256) if (h[j]) atomicAdd(&ghist[ty*200+j], h[j]);
}

__global__ __launch_bounds__(256) void gscan_kernel(const int* __restrict__ ghist,
                                                    int* __restrict__ gbase,
                                                    int* __restrict__ gcur){
  __shared__ int wb[4];
  const int t = threadIdx.x, wv = t>>6, l = t&63;
  for (int ty=0; ty<2; ++ty){
    int v = (t < GB) ? ghist[ty*200+t] : 0;
    int sum = v;
    #pragma unroll
    for (int off=1; off<64; off<<=1){
      int x = __shfl_up(sum, off, 64);
      if (l >= off) sum += x;
    }
    if (l == 63) wb[wv] = sum;
    __syncthreads();
    int wbase = 0;
    #pragma unroll
    for (int w=0; w<4; ++w) if (w < wv) wbase += wb[w];
    int excl = wbase + sum - v;
    if (t <= GB) gbase[ty*200+t] = excl;
    if (t <  GB) gcur [ty*200+t] = excl;
    __syncthreads();
  }
}

// partition with LDS staging: global writes are contiguous per-bucket runs
__global__ __launch_bounds__(256) void part1_kernel(const int* __restrict__ e0,
                                                    const int* __restrict__ e1,
                                                    int* __restrict__ gcur,
                                                    int2* __restrict__ p0,
                                                    int2* __restrict__ p1){
  const int ty = blockIdx.y;
  const int* e = ty ? e1 : e0;
  int2* pairs = ty ? p1 : p0;
  __shared__ int cnt[256];
  __shared__ int lstart[256];
  __shared__ int lcur[256];
  __shared__ int curg[GB];
  __shared__ int lsrc[TILE1];
  __shared__ int ldst[TILE1];
  __shared__ int wb[4];
  const int t = threadIdx.x;
  cnt[t] = 0;
  __syncthreads();
  int dreg[16], sreg[16];
  const int base = blockIdx.x*TILE1;
  const int ntile = min(TILE1, NE - base);
  #pragma unroll
  for (int it=0; it<16; ++it){
    int i = base + it*256 + t;
    int d = -1, s = 0;
    if (i < NE){ d = e[NE+i]; s = e[i]; atomicAdd(&cnt[d>>8], 1); }
    dreg[it] = d; sreg[it] = s;
  }
  __syncthreads();
  int c = cnt[t], sum = c;
  #pragma unroll
  for (int off=1; off<64; off<<=1){
    int x = __shfl_up(sum, off, 64);
    if ((t&63) >= off) sum += x;
  }
  if ((t&63) == 63) wb[t>>6] = sum;
  __syncthreads();
  int wbase = 0;
  #pragma unroll
  for (int w=0; w<4; ++w) if (w < (t>>6)) wbase += wb[w];
  int excl = wbase + sum - c;
  lstart[t] = excl;
  lcur[t] = excl;
  if (t < GB && c > 0) curg[t] = atomicAdd(&gcur[ty*200+t], c);
  __syncthreads();
  #pragma unroll
  for (int it=0; it<16; ++it){
    int d = dreg[it];
    if (d >= 0){
      int pos = atomicAdd(&lcur[d>>8], 1);
      lsrc[pos] = sreg[it];
      ldst[pos] = d;
    }
  }
  __syncthreads();
  for (int i=t; i<ntile; i+=256){
    int d = ldst[i];
    int j = d>>8;
    pairs[curg[j] + (i - lstart[j])] = make_int2(lsrc[i], d);
  }
}

// per-bucket LDS bin by dst + CSR offsets + fused layer-0 softmax weights (bf16).
struct Part2Job {
  const int2* pairs; const int* gbase;
  const float* als; const float* ald;   // [NN,4]
  int* ssrc; int* offs; unsigned short* coef;  // coef: [E,4] bf16
};
__global__ __launch_bounds__(256) void part2_kernel(Part2Job j0, Part2Job j1){
  const Part2Job jb = blockIdx.y ? j1 : j0;
  const int b = blockIdx.x;
  const int t = threadIdx.x;
  __shared__ int lcnt[256];
  __shared__ int lcur[256];
  __shared__ int wb[4];
  __shared__ int sorted_src[CAP];
  __shared__ unsigned char sorted_dl[CAP];
  const int gb0 = jb.gbase[b], gb1 = jb.gbase[b+1];
  const int n = gb1 - gb0;
  lcnt[t] = 0;
  __syncthreads();
  for (int i=t; i<n; i+=256)
    atomicAdd(&lcnt[jb.pairs[gb0+i].y - (b<<8)], 1);
  __syncthreads();
  int c = lcnt[t], sum = c;
  #pragma unroll
  for (int off=1; off<64; off<<=1){
    int x = __shfl_up(sum, off, 64);
    if ((t&63) >= off) sum += x;
  }
  if ((t&63) == 63) wb[t>>6] = sum;
  __syncthreads();
  int wbase = 0;
  #pragma unroll
  for (int w=0; w<4; ++w) if (w < (t>>6)) wbase += wb[w];
  int excl = wbase + sum - c;
  lcur[t] = excl;
  int g = (b<<8) + t;
  if (g <= NN) jb.offs[g] = gb0 + excl;
  __syncthreads();
  for (int i=t; i<n; i+=256){
    int2 pr = jb.pairs[gb0+i];
    int dl = pr.y - (b<<8);
    int pos = atomicAdd(&lcur[dl], 1);
    sorted_src[pos] = pr.x;
    sorted_dl[pos] = (unsigned char)dl;
  }
  __syncthreads();
  const float4* als4 = (const float4*)jb.als;
  const float4* ald4 = (const float4*)jb.ald;
  for (int i=t; i<n; i+=256){
    int s  = sorted_src[i];
    int dl = sorted_dl[i];
    float4 a  = als4[s];
    float4 ad = ald4[(b<<8)+dl];
    // no max-shift: |alpha| small at this model scale; softmax shift-invariant.
    float4 w;
    w.x = __expf(lrelu_f(a.x+ad.x));
    w.y = __expf(lrelu_f(a.y+ad.y));
    w.z = __expf(lrelu_f(a.z+ad.z));
    w.w = __expf(lrelu_f(a.w+ad.w));
    ((uint2*)jb.coef)[gb0+i] = bf4_pack(w);
    jb.ssrc[gb0+i] = s;
  }
}

// ---------------- MFMA GEMM: C = act(A[M,K] @ W[K,N] (+bias)) ----------------
// LG: logit-fused variant — GEMM N=48; cols 0..31 -> bf16 C (stride 32),
// col 32 -> fp32 outA[m], col 33 -> fp32 outB[m].
// LOGIT: proj variant (N=64) — additionally computes per-row dual logit dot
// products against cwS/cwD (layout [4][64]) -> outA[m*4+h], outB[m*4+h].
// KK is compile-time K: full unroll lets the compiler hoist next-tile global
// loads above the current barrier (software pipelining for free).
struct MgJob {
  const void* A; const float* W; const float* bias;
  void* C; float* outA; float* outB;
  const float* cwS; const float* cwD;
};
template<int NT, int KK, bool ELU, bool BF16OUT, bool BF16A, bool LG, bool LOGIT>
__global__ __launch_bounds__(256) void mgemm_kernel(MgJob j0, MgJob j1,
                                                    int M, int N)
{
  const MgJob jb = blockIdx.z ? j1 : j0;
  constexpr int TN = NT*16;
  __shared__ __align__(16) unsigned short Ah[64*72];
  __shared__ __align__(16) unsigned short Al[BF16A ? 8 : 64*72];
  __shared__ __align__(16) unsigned short Bh[TN*72];
  __shared__ __align__(16) unsigned short Bl[TN*72];
  __shared__ float CwS[LOGIT ? 256 : 1];
  __shared__ float CwD[LOGIT ? 256 : 1];
  const int t = threadIdx.x;
  const int m0 = blockIdx.x*64;
  const int n0 = blockIdx.y*TN;
  const int wv = t>>6, l = t&63;
  const int lr = l&15, lq = l>>4;
  if constexpr (LOGIT){ CwS[t] = jb.cwS[t]; CwD[t] = jb.cwD[t]; }
  floatx4 acc[NT];
  #pragma unroll
  for (int i=0;i<NT;i++) acc[i] = (floatx4){0.f,0.f,0.f,0.f};

  #pragma unroll
  for (int kt=0; kt<KK; kt+=64){
    if constexpr (BF16A){
      const unsigned short* A = (const unsigned short*)jb.A;
      #pragma unroll
      for (int i=0;i<2;i++){
        int li = t + i*256;
        int r = li >> 3, c8 = (li & 7)*8;
        short8 v = {0,0,0,0,0,0,0,0};
        if (m0 + r < M) v = *(const short8*)(A + (size_t)(m0+r)*KK + kt + c8);
        *(short8*)&Ah[r*72 + c8] = v;
      }
    } else {
      const float* A = (const float*)jb.A;
      #pragma unroll
      for (int i=0;i<4;i++){
        int li = t + i*256;
        int r = li >> 4, c4 = (li & 15)*4;
        float4 v = make_float4(0.f,0.f,0.f,0.f);
        if (m0 + r < M) v = *(const float4*)(A + (size_t)(m0+r)*KK + kt + c4);
        unsigned short h0,h1,h2,h3,g0,g1,g2,g3;
        split_bf(v.x,h0,g0); split_bf(v.y,h1,g1);
        split_bf(v.z,h2,g2); split_bf(v.w,h3,g3);
        uint2 ph = { (unsigned)h0 | ((unsigned)h1<<16), (unsigned)h2 | ((unsigned)h3<<16) };
        uint2 pl = { (unsigned)g0 | ((unsigned)g1<<16), (unsigned)g2 | ((unsigned)g3<<16) };
        *(uint2*)&Ah[r*72 + c4] = ph;
        *(uint2*)&Al[r*72 + c4] = pl;
      }
    }
    // B-stage: thread = one n, 4 consecutive k. Global reads coalesced over n;
    // LDS writes are aligned uint2 (k-contiguous) at dword-stride 36 -> 8-way
    // max (was: scalar u16 at 4-row stride -> 32-way on 2 banks, 6.6M conflicts).
    #pragma unroll
    for (int idx = t; idx < TN*16; idx += 256){
      int n  = idx % TN;
      int k4 = (idx / TN) * 4;
      float f0 = jb.W[(size_t)(kt+k4+0)*N + n0 + n];
      float f1 = jb.W[(size_t)(kt+k4+1)*N + n0 + n];
      float f2 = jb.W[(size_t)(kt+k4+2)*N + n0 + n];
      float f3 = jb.W[(size_t)(kt+k4+3)*N + n0 + n];
      unsigned short h0,h1,h2,h3,g0,g1,g2,g3;
      split_bf(f0,h0,g0); split_bf(f1,h1,g1);
      split_bf(f2,h2,g2); split_bf(f3,h3,g3);
      uint2 ph = { (unsigned)h0 | ((unsigned)h1<<16), (unsigned)h2 | ((unsigned)h3<<16) };
      uint2 pl = { (unsigned)g0 | ((unsigned)g1<<16), (unsigned)g2 | ((unsigned)g3<<16) };
      *(uint2*)&Bh[n*72 + k4] = ph;
      *(uint2*)&Bl[n*72 + k4] = pl;
    }
    __syncthreads();
    #pragma unroll
    for (int ks=0; ks<2; ks++){
      const int koff = ks*32 + lq*8;
      short8 a_h = *(const short8*)&Ah[(wv*16+lr)*72 + koff];
      short8 a_l;
      if constexpr (!BF16A) a_l = *(const short8*)&Al[(wv*16+lr)*72 + koff];
      #pragma unroll
      for (int nt=0; nt<NT; nt++){
        short8 b_h = *(const short8*)&Bh[(nt*16+lr)*72 + koff];
        short8 b_l = *(const short8*)&Bl[(nt*16+lr)*72 + koff];
        acc[nt] = __builtin_amdgcn_mfma_f32_16x16x32_bf16(a_h, b_h, acc[nt], 0,0,0);
        acc[nt] = __builtin_amdgcn_mfma_f32_16x16x32_bf16(a_h, b_l, acc[nt], 0,0,0);
        if constexpr (!BF16A)
          acc[nt] = __builtin_amdgcn_mfma_f32_16x16x32_bf16(a_l, b_h, acc[nt], 0,0,0);
      }
    }
    __syncthreads();
  }
  float ls[LOGIT ? 4 : 1][LOGIT ? 4 : 1];   // [r][h]
  float ld_[LOGIT ? 4 : 1][LOGIT ? 4 : 1];
  if constexpr (LOGIT){
    #pragma unroll
    for (int r=0;r<4;r++)
      #pragma unroll
      for (int h=0;h<4;h++){ ls[r][h]=0.f; ld_[r][h]=0.f; }
  }
  #pragma unroll
  for (int nt=0; nt<NT; nt++){
    int n = n0 + nt*16 + lr;
    float bv = jb.bias ? jb.bias[n] : 0.f;
    #pragma unroll
    for (int r=0;r<4;r++){
      int m = m0 + wv*16 + lq*4 + r;
      if (m < M){
        float o = acc[nt][r] + bv;
        if (ELU) o = elu_f(o);
        if constexpr (LG){
          if (n < 32)       ((unsigned short*)jb.C)[(size_t)m*32 + n] = f2bf(o);
          else if (n == 32) jb.outA[m] = o;
          else if (n == 33) jb.outB[m] = o;
        } else {
          if (BF16OUT) ((unsigned short*)jb.C)[(size_t)m*N + n] = f2bf(o);
          else         ((float*)jb.C)[(size_t)m*N + n] = o;
        }
        if constexpr (LOGIT){
          #pragma unroll
          for (int h=0;h<4;h++){
            ls[r][h]  = fmaf(o, CwS[h*64 + n], ls[r][h]);
            ld_[r][h] = fmaf(o, CwD[h*64 + n], ld_[r][h]);
          }
        }
      }
    }
  }
  if constexpr (LOGIT){
    // reduce over the 16 lr-lanes (channels), then lane lr==0 writes 4 rows x 4 heads
    #pragma unroll
    for (int r=0;r<4;r++)
      #pragma unroll
      for (int h=0;h<4;h++){
        float a = ls[r][h], d = ld_[r][h];
        #pragma unroll
        for (int off=1; off<16; off<<=1){
          a += __shfl_xor(a, off, 64);
          d += __shfl_xor(d, off, 64);
        }
        ls[r][h]=a; ld_[r][h]=d;
      }
    if (lr == 0){
      #pragma unroll
      for (int r=0;r<4;r++){
        int m = m0 + wv*16 + lq*4 + r;
        if (m < M){
          #pragma unroll
          for (int h=0;h<4;h++){
            jb.outA[(size_t)m*4 + h] = ls[r][h];
            jb.outB[(size_t)m*4 + h] = ld_[r][h];
          }
        }
      }
    }
  }
}

// ---------------- per-head block GEMM: hi1[m, h*64+n] = elu((agg_h @ Ws_h)/den + b) ----
struct HgJob {
  const unsigned short* A; const float* W; const float* den;  // den [M,4]
  const float* bias; unsigned short* out;                      // out bf16 [M,256]
};
__global__ __launch_bounds__(256) void hgemm_kernel(HgJob j0, HgJob j1){
  const HgJob jb = blockIdx.z ? j1 : j0;
  const int head = blockIdx.y;
  const int m0 = blockIdx.x*64;
  __shared__ __align__(16) unsigned short Ah[64*72];
  __shared__ __align__(16) unsigned short Bh[64*72];
  __shared__ __align__(16) unsigned short Bl[64*72];
  const int t = threadIdx.x;
  const int wv = t>>6, l = t&63;
  const int lr = l&15, lq = l>>4;
  floatx4 acc[4];
  #pragma unroll
  for (int i=0;i<4;i++) acc[i] = (floatx4){0.f,0.f,0.f,0.f};
  #pragma unroll
  for (int i=0;i<2;i++){
    int li = t + i*256;
    int r = li >> 3, c8 = (li & 7)*8;
    short8 v = {0,0,0,0,0,0,0,0};
    if (m0 + r < NN) v = *(const short8*)(jb.A + (size_t)(m0+r)*256 + head*64 + c8);
    *(short8*)&Ah[r*72 + c8] = v;
  }
  // B-stage: thread = one n, 4 consecutive k (conflict-reduced uint2 writes)
  #pragma unroll
  for (int idx = t; idx < 64*16; idx += 256){
    int n  = idx & 63;
    int k4 = (idx >> 6) * 4;
    float f0 = jb.W[(size_t)(k4+0)*256 + head*64 + n];
    float f1 = jb.W[(size_t)(k4+1)*256 + head*64 + n];
    float f2 = jb.W[(size_t)(k4+2)*256 + head*64 + n];
    float f3 = jb.W[(size_t)(k4+3)*256 + head*64 + n];
    unsigned short h0,h1,h2,h3,g0,g1,g2,g3;
    split_bf(f0,h0,g0); split_bf(f1,h1,g1);
    split_bf(f2,h2,g2); split_bf(f3,h3,g3);
    uint2 ph = { (unsigned)h0 | ((unsigned)h1<<16), (unsigned)h2 | ((unsigned)h3<<16) };
    uint2 pl = { (unsigned)g0 | ((unsigned)g1<<16), (unsigned)g2 | ((unsigned)g3<<16) };
    *(uint2*)&Bh[n*72 + k4] = ph;
    *(uint2*)&Bl[n*72 + k4] = pl;
  }
  __syncthreads();
  #pragma unroll
  for (int ks=0; ks<2; ks++){
    const int koff = ks*32 + lq*8;
    short8 a_h = *(const short8*)&Ah[(wv*16+lr)*72 + koff];
    #pragma unroll
    for (int nt=0; nt<4; nt++){
      short8 b_h = *(const short8*)&Bh[(nt*16+lr)*72 + koff];
      short8 b_l = *(const short8*)&Bl[(nt*16+lr)*72 + koff];
      acc[nt] = __builtin_amdgcn_mfma_f32_16x16x32_bf16(a_h, b_h, acc[nt], 0,0,0);
      acc[nt] = __builtin_amdgcn_mfma_f32_16x16x32_bf16(a_h, b_l, acc[nt], 0,0,0);
    }
  }
  float inv[4];
  #pragma unroll
  for (int r=0;r<4;r++){
    int m = m0 + wv*16 + lq*4 + r;
    inv[r] = (m < NN) ? 1.f/(jb.den[(size_t)m*4 + head] + 1e-16f) : 0.f;
  }
  #pragma unroll
  for (int nt=0; nt<4; nt++){
    int col = head*64 + nt*16 + lr;
    float bv = jb.bias[col];
    #pragma unroll
    for (int r=0;r<4;r++){
      int m = m0 + wv*16 + lq*4 + r;
      if (m < NN)
        jb.out[(size_t)m*256 + col] = f2bf(elu_f(acc[nt][r]*inv[r] + bv));
    }
  }
}

// ---------------- collapse attention vectors ----------------
struct CollapseJob { const float* W; const float* a; float* out; int K,H,C; };
struct CollapseArgs { CollapseJob j[8]; };
__global__ void collapse_kernel(CollapseArgs args){
  CollapseJob jb = args.j[blockIdx.x];
  int t = threadIdx.x;
  if (t < jb.K * jb.H){
    int k = t / jb.H, h = t % jb.H;
    const float* wr = jb.W + (size_t)k * (jb.H*jb.C) + h*jb.C;
    const float* ar = jb.a + h*jb.C;
    float s = 0.f;
    for (int c=0;c<jb.C;c++) s += wr[c]*ar[c];
    jb.out[h*jb.K + k] = s;   // layout [H,K]
  }
}

// build combined layer-1 weight [256 x 48]: cols 0..31 Ws, 32 cwS, 33 cwD, rest 0
__global__ __launch_bounds__(256) void prep1_kernel(
    const float* __restrict__ WsA, const float* __restrict__ cwSA, const float* __restrict__ cwDA,
    const float* __restrict__ WsB, const float* __restrict__ cwSB, const float* __restrict__ cwDB,
    float* __restrict__ WcA, float* __restrict__ WcB){
  const float* Ws  = blockIdx.x ? WsB  : WsA;
  const float* cwS = blockIdx.x ? cwSB : cwSA;
  const float* cwD = blockIdx.x ? cwDB : cwDA;
  float* Wc = blockIdx.x ? WcB : WcA;
  const int k = threadIdx.x;   // 256 rows
  #pragma unroll
  for (int n=0;n<32;n++) Wc[(size_t)k*48 + n] = Ws[(size_t)k*32 + n];
  Wc[(size_t)k*48 + 32] = cwS[k];
  Wc[(size_t)k*48 + 33] = cwD[k];
  #pragma unroll
  for (int n=34;n<48;n++) Wc[(size_t)k*48 + n] = 0.f;
}

// ---------------- layer-0 pre-aggregation over hu/hi rows ----------------
// 8 dsts per wave, 8 lanes per dst, 8 channels per lane: edge-sum is fully
// within-lane => no cross-lane reduction epilogue.
struct AggPJob {
  const int* offs; const int* ssrc;
  const unsigned short* x;     // bf16 [NN,64]
  const unsigned short* coef;  // bf16 [E,4]
  unsigned short* agg;         // bf16 [NN,256]
  float* den;                  // fp32 [NN,4]
};
__global__ __launch_bounds__(256) void aggpre_kernel(AggPJob ja, AggPJob jbb){
  const AggPJob jb = blockIdx.y ? jbb : ja;
  const int tid = threadIdx.x;
  const int lane = tid & 63, wid = tid >> 6;
  const int grp = lane >> 3;       // dst group within wave (0..7)
  const int cl  = lane & 7;        // channel lane within group
  const int c8  = cl * 8;          // channel base (8 bf16 = 16B per lane)
  const int dst = blockIdx.x*32 + wid*8 + grp;
  if (dst >= NN) return;
  const int b0 = jb.offs[dst], b1 = jb.offs[dst+1];
  float acc[4][8];
  float den[4] = {0.f,0.f,0.f,0.f};
  #pragma unroll
  for (int h=0;h<4;h++)
    #pragma unroll
    for (int c=0;c<8;c++) acc[h][c]=0.f;
  const unsigned ONE2 = 0x3F803F80u;  // packed bf16 (1.0, 1.0)
  int e = b0;
  // edge-paired dot2: operands stay bf16, sums within-lane only
  for (; e+1 < b1; e += 2){
    int s0 = jb.ssrc[e];
    int s1 = jb.ssrc[e+1];
    uint4 q0 = *(const uint4*)(jb.x + ((size_t)s0<<6) + c8);
    uint4 q1 = *(const uint4*)(jb.x + ((size_t)s1<<6) + c8);
    uint2 w0 = *(const uint2*)(jb.coef + (size_t)e*4);
    uint2 w1 = *(const uint2*)(jb.coef + (size_t)(e+1)*4);
    // (a,b,sel): a supplies bytes 4-7, b supplies bytes 0-3
    unsigned wp[4];
    wp[0] = __builtin_amdgcn_perm(w1.x, w0.x, 0x05040100u);
    wp[1] = __builtin_amdgcn_perm(w1.x, w0.x, 0x07060302u);
    wp[2] = __builtin_amdgcn_perm(w1.y, w0.y, 0x05040100u);
    wp[3] = __builtin_amdgcn_perm(w1.y, w0.y, 0x07060302u);
    unsigned xp[8];
    xp[0] = __builtin_amdgcn_perm(q1.x, q0.x, 0x05040100u);
    xp[1] = __builtin_amdgcn_perm(q1.x, q0.x, 0x07060302u);
    xp[2] = __builtin_amdgcn_perm(q1.y, q0.y, 0x05040100u);
    xp[3] = __builtin_amdgcn_perm(q1.y, q0.y, 0x07060302u);
    xp[4] = __builtin_amdgcn_perm(q1.z, q0.z, 0x05040100u);
    xp[5] = __builtin_amdgcn_perm(q1.z, q0.z, 0x07060302u);
    xp[6] = __builtin_amdgcn_perm(q1.w, q0.w, 0x05040100u);
    xp[7] = __builtin_amdgcn_perm(q1.w, q0.w, 0x07060302u);
    #pragma unroll
    for (int h=0;h<4;h++){
      den[h] = dot2bf(den[h], wp[h], ONE2);
      #pragma unroll
      for (int c=0;c<8;c++) acc[h][c] = dot2bf(acc[h][c], wp[h], xp[c]);
    }
  }
  if (e < b1){  // odd-degree tail: single edge, scalar path
    int s = jb.ssrc[e];
    uint4 q = *(const uint4*)(jb.x + ((size_t)s<<6) + c8);
    uint2 w = *(const uint2*)(jb.coef + (size_t)e*4);
    float wf[4] = { bf2f(w.x & 0xffffu), bf2f(w.x >> 16),
                    bf2f(w.y & 0xffffu), bf2f(w.y >> 16) };
    float xf[8] = { bf2f(q.x & 0xffffu), bf2f(q.x >> 16),
                    bf2f(q.y & 0xffffu), bf2f(q.y >> 16),
                    bf2f(q.z & 0xffffu), bf2f(q.z >> 16),
                    bf2f(q.w & 0xffffu), bf2f(q.w >> 16) };
    #pragma unroll
    for (int h=0;h<4;h++){
      den[h] += wf[h];
      #pragma unroll
      for (int c=0;c<8;c++) acc[h][c] += wf[h]*xf[c];
    }
  }
  // epilogue: pack + store only (no shuffles)
  #pragma unroll
  for (int h=0;h<4;h++){
    uint2 plo = bf4_pack(make_float4(acc[h][0],acc[h][1],acc[h][2],acc[h][3]));
    uint2 phi = bf4_pack(make_float4(acc[h][4],acc[h][5],acc[h][6],acc[h][7]));
    uint4 pk = { plo.x, plo.y, phi.x, phi.y };
    *(uint4*)(jb.agg + (size_t)dst*256 + h*64 + c8) = pk;
  }
  if (cl == 0)
    *(float4*)(jb.den + (size_t)dst*4) = make_float4(den[0],den[1],den[2],den[3]);
}

// ---------------- layer-1 aggregation (softmax weight fused inline) ----------------
struct Agg1Job {
  const int* offs; const int* ssrc;
  const unsigned short* hs;   // bf16 [NN,32]
  const float* als; const float* ald;  // layer-1 logits
  const float* bias; float* out;
};
__global__ __launch_bounds__(256) void agg1_kernel(Agg1Job ja, Agg1Job jbb){
  const Agg1Job jb = blockIdx.y ? jbb : ja;
  const int wid = threadIdx.x>>6, lane = threadIdx.x&63;
  const int dst = blockIdx.x*4 + wid;
  if (dst >= NN) return;
  const int b0 = jb.offs[dst], b1 = jb.offs[dst+1];
  const float ad = jb.ald[dst];
  const int slot = lane>>3, c4 = (lane&7)*4;
  float4 acc = make_float4(0.f,0.f,0.f,0.f);
  float den = 0.f;
  int e = b0 + slot;
  for (; e+8 < b1; e += 16){
    int s0 = jb.ssrc[e], s1 = jb.ssrc[e+8];
    float a0 = jb.als[s0];
    float a1 = jb.als[s1];
    float4 v0 = bf4_load(jb.hs + ((size_t)s0<<5) + c4);
    float4 v1 = bf4_load(jb.hs + ((size_t)s1<<5) + c4);
    float w0 = __expf(lrelu_f(a0 + ad));
    float w1 = __expf(lrelu_f(a1 + ad));
    acc.x += w0*v0.x + w1*v1.x;
    acc.y += w0*v0.y + w1*v1.y;
    acc.z += w0*v0.z + w1*v1.z;
    acc.w += w0*v0.w + w1*v1.w;
    den += w0 + w1;
  }
  if (e < b1){
    int s = jb.ssrc[e];
    float w = __expf(lrelu_f(jb.als[s] + ad));
    float4 v = bf4_load(jb.hs + ((size_t)s<<5) + c4);
    acc.x += w*v.x; acc.y += w*v.y; acc.z += w*v.z; acc.w += w*v.w;
    den += w;
  }
  #pragma unroll
  for (int off=32; off>=8; off>>=1){
    acc.x += __shfl_xor(acc.x, off, 64);
    acc.y += __shfl_xor(acc.y, off, 64);
    acc.z += __shfl_xor(acc.z, off, 64);
    acc.w += __shfl_xor(acc.w, off, 64);
    den   += __shfl_xor(den,   off, 64);
  }
  if (lane < 8){
    const float inv = 1.f/(den + 1e-16f);
    float4 b = *(const float4*)(jb.bias + c4);
    float4 o = make_float4(acc.x*inv+b.x, acc.y*inv+b.y, acc.z*inv+b.z, acc.w*inv+b.w);
    *(float4*)(jb.out + (size_t)dst*32 + c4) = o;
  }
}

// ---------------- host glue ----------------
extern "C" void kernel_launch(void* const* d_in, const int* in_sizes, int n_in,
                              void* d_out, int out_size, void* d_ws, size_t ws_size,
                              hipStream_t stream)
{
  (void)in_sizes; (void)n_in; (void)out_size; (void)ws_size;
  const float* x_user   = (const float*)d_in[0];
  const float* x_item   = (const float*)d_in[1];
  const int*   e_u2i    = (const int*)  d_in[2];
  const int*   e_i2u    = (const int*)  d_in[3];
  const float* p_user_w = (const float*)d_in[4];
  const float* p_user_b = (const float*)d_in[5];
  const float* p_item_w = (const float*)d_in[6];
  const float* p_item_b = (const float*)d_in[7];
  const float* l0_u2i_ws=(const float*)d_in[8];
  const float* l0_u2i_wd=(const float*)d_in[9];
  const float* l0_u2i_as=(const float*)d_in[10];
  const float* l0_u2i_ad=(const float*)d_in[11];
  const float* l0_u2i_b =(const float*)d_in[12];
  const float* l0_i2u_ws=(const float*)d_in[13];
  const float* l0_i2u_wd=(const float*)d_in[14];
  const float* l0_i2u_as=(const float*)d_in[15];
  const float* l0_i2u_ad=(const float*)d_in[16];
  const float* l0_i2u_b =(const float*)d_in[17];
  const float* l1_u2i_ws=(const float*)d_in[18];
  const float* l1_u2i_wd=(const float*)d_in[19];
  const float* l1_u2i_as=(const float*)d_in[20];
  const float* l1_u2i_ad=(const float*)d_in[21];
  const float* l1_u2i_b =(const float*)d_in[22];
  const float* l1_i2u_ws=(const float*)d_in[23];
  const float* l1_i2u_wd=(const float*)d_in[24];
  const float* l1_i2u_as=(const float*)d_in[25];
  const float* l1_i2u_ad=(const float*)d_in[26];
  const float* l1_i2u_b =(const float*)d_in[27];

  char* base = (char*)d_ws;
  size_t off = 0;
  auto alloc = [&](size_t bytes)->void*{
    void* p = base + off;
    off += (bytes + 255) & ~(size_t)255;
    return p;
  };
  int* offs_u2i = (int*)alloc((size_t)(NN+1)*sizeof(int));
  int* offs_i2u = (int*)alloc((size_t)(NN+1)*sizeof(int));
  int* ssrc_u2i = (int*)alloc((size_t)NE*sizeof(int));
  int* ssrc_i2u = (int*)alloc((size_t)NE*sizeof(int));
  int* ghist    = (int*)alloc((size_t)2*200*sizeof(int));
  int* gbase    = (int*)alloc((size_t)2*200*sizeof(int));
  int* gcur     = (int*)alloc((size_t)2*200*sizeof(int));
  unsigned short* coef0_u2i = (unsigned short*)alloc((size_t)NE*4*sizeof(unsigned short));
  unsigned short* coef0_i2u = (unsigned short*)alloc((size_t)NE*4*sizeof(unsigned short));
  unsigned short* hu = (unsigned short*)alloc((size_t)NN*64*sizeof(unsigned short));
  unsigned short* hi = (unsigned short*)alloc((size_t)NN*64*sizeof(unsigned short));
  unsigned short* agg_u2i = (unsigned short*)alloc((size_t)NN*256*sizeof(unsigned short));
  unsigned short* agg_i2u = (unsigned short*)alloc((size_t)NN*256*sizeof(unsigned short));
  float* den_u2i = (float*)alloc((size_t)NN*4*sizeof(float));
  float* den_i2u = (float*)alloc((size_t)NN*4*sizeof(float));
  unsigned short* hu1 = (unsigned short*)alloc((size_t)NN*256*sizeof(unsigned short));
  unsigned short* hi1 = (unsigned short*)alloc((size_t)NN*256*sizeof(unsigned short));
  unsigned short* hs1_u2i = (unsigned short*)alloc((size_t)NN*32*sizeof(unsigned short));
  unsigned short* hs1_i2u = (unsigned short*)alloc((size_t)NN*32*sizeof(unsigned short));
  float* als0_u2i = (float*)alloc((size_t)NN*4*sizeof(float));
  float* ald0_u2i = (float*)alloc((size_t)NN*4*sizeof(float));
  float* als0_i2u = (float*)alloc((size_t)NN*4*sizeof(float));
  float* ald0_i2u = (float*)alloc((size_t)NN*4*sizeof(float));
  float* als1_u2i = (float*)alloc((size_t)NN*sizeof(float));
  float* ald1_u2i = (float*)alloc((size_t)NN*sizeof(float));
  float* als1_i2u = (float*)alloc((size_t)NN*sizeof(float));
  float* ald1_i2u = (float*)alloc((size_t)NN*sizeof(float));
  float* cw0s_u2i = (float*)alloc(256*sizeof(float));
  float* cw0d_u2i = (float*)alloc(256*sizeof(float));
  float* cw0s_i2u = (float*)alloc(256*sizeof(float));
  float* cw0d_i2u = (float*)alloc(256*sizeof(float));
  float* cw1s_u2i = (float*)alloc(256*sizeof(float));
  float* cw1d_u2i = (float*)alloc(256*sizeof(float));
  float* cw1s_i2u = (float*)alloc(256*sizeof(float));
  float* cw1d_i2u = (float*)alloc(256*sizeof(float));
  float* Wc_u2i   = (float*)alloc((size_t)256*48*sizeof(float));
  float* Wc_i2u   = (float*)alloc((size_t)256*48*sizeof(float));
  // pairs scratch aliases hu1/hi1: consumed by part2 before hgemm writes them
  int2* pairs_u2i = (int2*)hu1;
  int2* pairs_i2u = pairs_u2i + NE;

  const int GM = (NN + 63)/64;

  // ---- bucket sort stage A ----
  hipMemsetAsync(ghist, 0, (size_t)2*200*sizeof(int), stream);
  ghist_kernel<<<dim3(256,2), 256, 0, stream>>>(e_u2i, e_i2u, ghist);
  gscan_kernel<<<1, 256, 0, stream>>>(ghist, gbase, gcur);
  part1_kernel<<<dim3((NE+TILE1-1)/TILE1,2), 256, 0, stream>>>(
      e_u2i, e_i2u, gcur, pairs_u2i, pairs_i2u);

  // ---- collapse attention vectors (needed by proj's fused logits) ----
  CollapseArgs ca;
  ca.j[0] = {l0_u2i_ws, l0_u2i_as, cw0s_u2i, 64, 4, 64};
  ca.j[1] = {l0_u2i_wd, l0_u2i_ad, cw0d_u2i, 64, 4, 64};
  ca.j[2] = {l0_i2u_ws, l0_i2u_as, cw0s_i2u, 64, 4, 64};
  ca.j[3] = {l0_i2u_wd, l0_i2u_ad, cw0d_i2u, 64, 4, 64};
  ca.j[4] = {l1_u2i_ws, l1_u2i_as, cw1s_u2i, 256, 1, 32};
  ca.j[5] = {l1_u2i_wd, l1_u2i_ad, cw1d_u2i, 256, 1, 32};
  ca.j[6] = {l1_i2u_ws, l1_i2u_as, cw1s_i2u, 256, 1, 32};
  ca.j[7] = {l1_i2u_wd, l1_i2u_ad, cw1d_i2u, 256, 1, 32};
  collapse_kernel<<<8, 256, 0, stream>>>(ca);

  // ---- input projections (+bias +ELU) -> bf16, with fused layer-0 logits ----
  // hu row -> als0_u2i (S-side of u2i) and ald0_i2u (D-side of i2u); vice versa.
  mgemm_kernel<4,128,true,true,false,false,true><<<dim3(GM,1,2), 256, 0, stream>>>(
      MgJob{x_user, p_user_w, p_user_b, hu, als0_u2i, ald0_i2u, cw0s_u2i, cw0d_i2u},
      MgJob{x_item, p_item_w, p_item_b, hi, als0_i2u, ald0_u2i, cw0s_i2u, cw0d_u2i},
      NN, 64);

  // ---- combined layer-1 weights (Ws | cwS | cwD) ----
  prep1_kernel<<<2, 256, 0, stream>>>(
      l1_u2i_ws, cw1s_u2i, cw1d_i2u,
      l1_i2u_ws, cw1s_i2u, cw1d_u2i,
      Wc_u2i, Wc_i2u);

  // ---- bucket sort stage B ----
  part2_kernel<<<dim3(GB,2), 256, 0, stream>>>(
      Part2Job{pairs_u2i, gbase,       als0_u2i, ald0_u2i, ssrc_u2i, offs_u2i, coef0_u2i},
      Part2Job{pairs_i2u, gbase + 200, als0_i2u, ald0_i2u, ssrc_i2u, offs_i2u, coef0_i2u});

  // ---- layer 0: pre-aggregate hu/hi rows (8 dst/wave, shuffle-free) ----
  aggpre_kernel<<<dim3((NN+31)/32,2), 256, 0, stream>>>(
      AggPJob{offs_u2i, ssrc_u2i, hu, coef0_u2i, agg_u2i, den_u2i},
      AggPJob{offs_i2u, ssrc_i2u, hi, coef0_i2u, agg_i2u, den_i2u});

  // ---- layer 0: per-head GEMM + den-divide + bias + ELU -> hi1/hu1 bf16 ----
  hgemm_kernel<<<dim3(GM,4,2), 256, 0, stream>>>(
      HgJob{agg_u2i, l0_u2i_ws, den_u2i, l0_u2i_b, hi1},
      HgJob{agg_i2u, l0_i2u_ws, den_i2u, l0_i2u_b, hu1});

  // ---- layer 1: feature GEMMs with fused logit columns (merged dual launch) ----
  // hu1 @ Wc_u2i -> hs1_u2i (cols 0..31), als1_u2i (col 32), ald1_i2u (col 33)
  mgemm_kernel<3,256,false,true,true,true,false><<<dim3(GM,1,2), 256, 0, stream>>>(
      MgJob{hu1, Wc_u2i, nullptr, hs1_u2i, als1_u2i, ald1_i2u, nullptr, nullptr},
      MgJob{hi1, Wc_i2u, nullptr, hs1_i2u, als1_i2u, ald1_u2i, nullptr, nullptr},
      NN, 48);

  // ---- layer 1: aggregate (+bias), softmax weights computed inline ----
  float* hu2 = (float*)d_out;                  // first tuple element (users, i2u dst)
  float* hi2 = (float*)d_out + (size_t)NN*32;  // second tuple element (items, u2i dst)
  agg1_kernel<<<dim3(NN/4,2), 256, 0, stream>>>(
      Agg1Job{offs_u2i, ssrc_u2i, hs1_u2i, als1_u2i, ald1_u2i, l1_u2i_b, hi2},
      Agg1Job{offs_i2u, ssrc_i2u, hs1_i2u, als1_i2u, ald1_i2u, l1_i2u_b, hu2});
}